// Round 1
// baseline (2001.605 us; speedup 1.0000x reference)
//
#include <hip/hip_runtime.h>

// resFAN round 7: single-fp16 everywhere (no hi/lo split).  Post-mortem of
// r6 showed conv is LDS-pipe-bound (128KB frag reads/CU-iter vs 460cyc MFMA);
// threshold is 2% of max|ref| -> split precision machinery (2x LDS, 3x MFMA)
// is unnecessary.  Convs now BK=64 dbuf single-stream; vgemm/att/scan 1-pass.
//
// Error budget: fp16 quant 2^-11 per tensor, no amplification (weights std
// 0.01), gamma=0.1 damps attention branch -> final abs err ~1e-5 vs 8e-5 thr.
//
// R0 (this session): identical resubmit — prior bench failed on container
// acquisition (infra), no counters.  Re-establish baseline + rocprof.

#define NPIX 4096

typedef _Float16 f16;
typedef _Float16 f16x8 __attribute__((ext_vector_type(8)));
typedef _Float16 f16x4 __attribute__((ext_vector_type(4)));
typedef float f32x4 __attribute__((ext_vector_type(4)));

__device__ inline void async16(const void* g, void* l) {
  __builtin_amdgcn_global_load_lds(
      (const __attribute__((address_space(1))) unsigned int*)g,
      (__attribute__((address_space(3))) unsigned int*)l, 16, 0, 0);
}

// ---------------- small prep kernels ----------------

__global__ void rf_zero(float* __restrict__ z) { z[threadIdx.x] = 0.f; }

__global__ void rf_s(const float* __restrict__ wB, const float* __restrict__ bA,
                     float* __restrict__ s_out, float* __restrict__ c0_out) {
  int c = threadIdx.x;  // 128 threads
  const float* row = wB + (size_t)c * 1024;
  float acc = 0.f;
  for (int i = 0; i < 1024; ++i) acc += row[i];
  s_out[c] = acc;
  __shared__ float sh[128];
  sh[c] = acc * bA[c];
  __syncthreads();
  for (int off = 64; off > 0; off >>= 1) {
    if (c < off) sh[c] += sh[c + off];
    __syncthreads();
  }
  if (c == 0) c0_out[0] = sh[0];
}

__global__ void rf_u(const float* __restrict__ wA, const float* __restrict__ s,
                     float* __restrict__ u) {
  int i = blockIdx.x * 256 + threadIdx.x;  // 1024 total
  float acc = 0.f;
  for (int c = 0; c < 128; ++c) acc += s[c] * wA[(size_t)c * 1024 + i];
  u[i] = acc;
}

__global__ void rf_fstat(const float* __restrict__ in, float* __restrict__ fstat) {
  int b = blockIdx.x;
  int t = threadIdx.x;
  const float* f = in + ((size_t)b * 1025 + 1024) * NPIX;
  float mx = -1e30f, mn = 1e30f;
  for (int j = t; j < NPIX; j += 256) {
    float v = f[j];
    mx = fmaxf(mx, v);
    mn = fminf(mn, v);
  }
  __shared__ float smx[256], smn[256];
  smx[t] = mx; smn[t] = mn;
  __syncthreads();
  for (int off = 128; off > 0; off >>= 1) {
    if (t < off) {
      smx[t] = fmaxf(smx[t], smx[t + off]);
      smn[t] = fminf(smn[t], smn[t + off]);
    }
    __syncthreads();
  }
  if (t == 0) { fstat[b] = smx[0]; fstat[4 + b] = smn[0]; }
}

__global__ __launch_bounds__(256) void rf_A(const float* __restrict__ in,
                                            const float* __restrict__ u,
                                            const float* __restrict__ c0p,
                                            const float* __restrict__ fst,
                                            float* __restrict__ A, float* __restrict__ M) {
  __shared__ float ul[1024];
  int b = blockIdx.y;
  int n = blockIdx.x * 256 + threadIdx.x;
  for (int s = threadIdx.x; s < 1024; s += 256) ul[s] = u[s];
  __syncthreads();
  const float* xp = in + (size_t)b * 1025 * NPIX + n;
  float acc = c0p[0];
#pragma unroll 8
  for (int i = 0; i < 1024; ++i) acc = fmaf(ul[i], xp[(size_t)i * NPIX], acc);
  A[b * NPIX + n] = acc;
  M[b * NPIX + n] = fmaxf(acc * fst[b], acc * fst[4 + b]);
}

__global__ void rf_Z(const float* __restrict__ in, const float* __restrict__ A,
                     const float* __restrict__ M, float* __restrict__ iZ) {
  int idx = blockIdx.x * 4 + (threadIdx.x >> 6);  // (b,n) pair, 16384 total
  int lane = threadIdx.x & 63;
  int b = idx >> 12;
  const float* f = in + ((size_t)b * 1025 + 1024) * NPIX;
  float a = A[idx], m = M[idx];
  float acc = 0.f;
#pragma unroll 4
  for (int it = 0; it < 64; ++it) acc += __expf(a * f[lane + it * 64] - m);
  for (int off = 32; off > 0; off >>= 1) acc += __shfl_down(acc, off, 64);
  if (lane == 0) iZ[idx] = 1.0f / acc;
}

// ---------------- x transpose: [b][ci][n] f32 -> [b][n][ci] f16, scale 16 ---

__global__ void rf_xsplit(const float* __restrict__ in, f16* __restrict__ xh) {
  __shared__ float tl[64][65];
  int nt = blockIdx.x, ct = blockIdx.y, b = blockIdx.z;
  int n0 = nt * 64, c0 = ct * 64;
  int tid = threadIdx.x;
  for (int s = tid; s < 4096; s += 256) {
    int r = s >> 6, c = s & 63;
    tl[r][c] = in[((size_t)b * 1025 + c0 + r) * NPIX + n0 + c];
  }
  __syncthreads();
  for (int s = tid; s < 512; s += 256) {
    int n = s >> 3, g = s & 7;
    f16x8 hb;
#pragma unroll
    for (int q = 0; q < 8; ++q) hb[q] = (f16)(16.f * tl[g * 8 + q][n]);
    size_t o = ((size_t)b * NPIX + n0 + n) * 1024 + c0 + g * 8;
    *(f16x8*)&xh[o] = hb;
  }
}

// ---------------- wC cast: [1024][1024] f32 -> f16, scale 256 --------------

__global__ void rf_wC1(const float* __restrict__ wC, f16* __restrict__ wh) {
  int base = (blockIdx.x * 256 + threadIdx.x) * 8;
  f16x8 hb;
#pragma unroll
  for (int q = 0; q < 8; ++q) hb[q] = (f16)(256.f * wC[base + q]);
  *(f16x8*)&wh[base] = hb;
}

// ---------------- MFMA v-GEMM (dbuf, single fp16): v = wC @ x + bC --------

__global__ __launch_bounds__(256, 2) void rf_vgemmm(
    const f16* __restrict__ wh, const f16* __restrict__ xh,
    const float* __restrict__ bC, f16* __restrict__ vH) {
  __shared__ f16 sA[2][4096], sB[2][4096];
  const int tid = threadIdx.x;
  const int nb = blockIdx.x * 128, cb = blockIdx.y * 128, b = blockIdx.z;
  const int pA = tid & 127;
  const int wv = tid >> 6, lane = tid & 63;
  const int mrow = lane & 15, quad = lane >> 4;
  const int wm = (wv & 1) * 64, wn = (wv >> 1) * 64;
  const size_t abase = (size_t)(cb + pA) * 1024;
  const size_t bbase = ((size_t)b * NPIX + nb + pA) * 1024;
  f32x4 acc[4][4];
#pragma unroll
  for (int i = 0; i < 4; ++i)
#pragma unroll
    for (int j = 0; j < 4; ++j) acc[i][j] = (f32x4){0.f, 0.f, 0.f, 0.f};

  auto stage = [&](int k0, int pb) {
#pragma unroll
    for (int s = 0; s < 2; ++s) {
      const int cc = ((tid + 256 * s) >> 7) & 3;
      const int lb = ((tid & ~63) + 256 * s) * 8;
      async16(wh + abase + k0 + cc * 8, &sA[pb][lb]);
      async16(xh + bbase + k0 + cc * 8, &sB[pb][lb]);
    }
  };
  stage(0, 0);
  int p = 0;
  for (int k0 = 0; k0 < 1024; k0 += 32) {
    __syncthreads();
    if (k0 + 32 < 1024) stage(k0 + 32, p ^ 1);
    f16x8 fa[4], fb[4];
#pragma unroll
    for (int mi = 0; mi < 4; ++mi)
      fa[mi] = *(const f16x8*)&sA[p][(quad * 128 + wm + mi * 16 + mrow) * 8];
#pragma unroll
    for (int ni = 0; ni < 4; ++ni)
      fb[ni] = *(const f16x8*)&sB[p][(quad * 128 + wn + ni * 16 + mrow) * 8];
#pragma unroll
    for (int mi = 0; mi < 4; ++mi)
#pragma unroll
      for (int ni = 0; ni < 4; ++ni)
        acc[mi][ni] = __builtin_amdgcn_mfma_f32_16x16x32_f16(fa[mi], fb[ni], acc[mi][ni], 0, 0, 0);
    p ^= 1;
  }
  const float inv = 1.0f / 4096.0f;
#pragma unroll
  for (int mi = 0; mi < 4; ++mi) {
#pragma unroll
    for (int rg = 0; rg < 4; ++rg) {
      int c = cb + wm + mi * 16 + quad * 4 + rg;
      float bv = bC[c];
#pragma unroll
      for (int ni = 0; ni < 4; ++ni) {
        int j = nb + wn + ni * 16 + mrow;
        vH[((size_t)b * 1024 + c) * NPIX + j] =
            (f16)(16.f * (acc[mi][ni][rg] * inv + bv));
      }
    }
  }
}

// ---------------- MFMA attention out-GEMM (single fp16) -> y ---------------

__global__ __launch_bounds__(256, 2) void rf_attm(
    const f16* __restrict__ vH,
    const float* __restrict__ Aarr, const float* __restrict__ Marr,
    const float* __restrict__ iZ, const float* __restrict__ in,
    const float* __restrict__ gptr, f16* __restrict__ yH) {
  __shared__ f16 sAh[4096], sPh[4096];
  const int tid = threadIdx.x;
  const int ib = blockIdx.x * 128, cb = blockIdx.y * 128, b = blockIdx.z;
  const int pA = tid & 127;
  const int wv = tid >> 6, lane = tid & 63;
  const int mrow = lane & 15, quad = lane >> 4;
  const int wm = (wv & 1) * 64, wn = (wv >> 1) * 64;
  const size_t vbase = ((size_t)b * 1024 + cb + pA) * NPIX;
  const int ni_ = tid & 127;
  const int kc0 = tid >> 7;  // 0..1
  const float av = Aarr[b * NPIX + ib + ni_];
  const float mv = Marr[b * NPIX + ib + ni_];
  const float zv = iZ[b * NPIX + ib + ni_] * 16.f;
  const float* f = in + ((size_t)b * 1025 + 1024) * NPIX;
  f32x4 acc[4][4];
#pragma unroll
  for (int i = 0; i < 4; ++i)
#pragma unroll
    for (int j = 0; j < 4; ++j) acc[i][j] = (f32x4){0.f, 0.f, 0.f, 0.f};
  for (int j0 = 0; j0 < NPIX; j0 += 32) {
#pragma unroll
    for (int s = 0; s < 2; ++s) {
      const int cc = ((tid + 256 * s) >> 7) & 3;
      const int lb = ((tid & ~63) + 256 * s) * 8;
      async16(vH + vbase + j0 + cc * 8, &sAh[lb]);
    }
#pragma unroll
    for (int it = 0; it < 2; ++it) {
      const int kc = kc0 + 2 * it;
      const float4 fa = *(const float4*)&f[j0 + kc * 8];
      const float4 fb = *(const float4*)&f[j0 + kc * 8 + 4];
      const float fj[8] = {fa.x, fa.y, fa.z, fa.w, fb.x, fb.y, fb.z, fb.w};
      f16x8 ph;
#pragma unroll
      for (int q = 0; q < 8; ++q)
        ph[q] = (f16)(__expf(fmaf(av, fj[q], -mv)) * zv);
      *(f16x8*)&sPh[(kc * 128 + ni_) * 8] = ph;
    }
    __syncthreads();
    f16x8 fa[4], fb[4];
#pragma unroll
    for (int mi = 0; mi < 4; ++mi)
      fa[mi] = *(const f16x8*)&sAh[(quad * 128 + wm + mi * 16 + mrow) * 8];
#pragma unroll
    for (int ni = 0; ni < 4; ++ni)
      fb[ni] = *(const f16x8*)&sPh[(quad * 128 + wn + ni * 16 + mrow) * 8];
#pragma unroll
    for (int mi = 0; mi < 4; ++mi)
#pragma unroll
      for (int ni = 0; ni < 4; ++ni)
        acc[mi][ni] = __builtin_amdgcn_mfma_f32_16x16x32_f16(fa[mi], fb[ni], acc[mi][ni], 0, 0, 0);
    __syncthreads();
  }
  const float g = gptr[0];
  const float inv = 1.0f / 256.0f;
#pragma unroll
  for (int mi = 0; mi < 4; ++mi) {
    const int cbase = cb + wm + mi * 16 + quad * 4;
#pragma unroll
    for (int ni = 0; ni < 4; ++ni) {
      const int i = ib + wn + ni * 16 + mrow;
      f16x4 hv;
#pragma unroll
      for (int rg = 0; rg < 4; ++rg) {
        float xr = in[((size_t)b * 1025 + cbase + rg) * NPIX + i];
        hv[rg] = (f16)(16.f * (g * (acc[mi][ni][rg] * inv) + xr));
      }
      *(f16x4*)&yH[((size_t)b * NPIX + i) * 1024 + cbase] = hv;
    }
  }
}

// ---------------- weight cast prep: [CO][CI][3][3] -> [9][CO][CI] f16 ------

__global__ void rf_wsingle(const float* __restrict__ w, f16* __restrict__ wh,
                           int CO, int CI) {
  int idx = blockIdx.x * 256 + threadIdx.x;  // co*CI + ci
  if (idx >= CO * CI) return;
  int co = idx / CI, ci = idx - co * CI;
#pragma unroll
  for (int t = 0; t < 9; ++t)
    wh[((size_t)t * CO + co) * CI + ci] = (f16)(256.0f * w[(size_t)idx * 9 + t]);
}

// ---------------- MFMA dilated 3x3 conv (dbuf, BK=64, single fp16) ---------

template <int BM, int BN, bool F32OUT>
__global__ __launch_bounds__(256, 2) void rf_mconv(
    const f16* __restrict__ xh, const f16* __restrict__ wh,
    const float* __restrict__ bias, const float* __restrict__ zp,
    f16* __restrict__ oh, float* __restrict__ of, int CI, int CO) {
  constexpr int ROWS = BM / 64;
  constexpr int TPI = 4096 / BM;
  constexpr int NSA = BM / 32;
  constexpr int NSB = BN / 32;
  __shared__ f16 sA[2][BM * 64], sB[2][BN * 64];
  const int tid = threadIdx.x;
  const int blkpx = blockIdx.x;
  const int cob = blockIdx.y * BN;
  const int b = blkpx / TPI;
  const int h0 = (blkpx - b * TPI) * ROWS;

  const int pA = tid & (BM - 1);
  const int rA = pA >> 6, wpx = pA & 63;
  const int pB = tid & (BN - 1);

  const int wv = tid >> 6, lane = tid & 63;
  const int mrow = lane & 15, quad = lane >> 4;
  const int wm = (BN == 128) ? (wv & 1) * 64 : wv * 64;
  const int wn = (BN == 128) ? (wv >> 1) * 64 : 0;

  f32x4 acc[4][4];
#pragma unroll
  for (int i = 0; i < 4; ++i)
#pragma unroll
    for (int j = 0; j < 4; ++j) acc[i][j] = (f32x4){0.f, 0.f, 0.f, 0.f};

  const int KI = CI >> 6;

  const f16* cah; size_t cwb; bool cv;
  auto tapbase = [&](int tt) {
    const int dh = (tt / 3) * 2 - 2, dw = (tt - (tt / 3) * 3) * 2 - 2;
    const int hin = h0 + rA + dh, win = wpx + dw;
    cv = ((unsigned)hin < 64u) && ((unsigned)win < 64u);
    cah = xh + (((size_t)b * 64 + (cv ? hin : 0)) * 64 + (cv ? win : 0)) * CI;
    cwb = ((size_t)tt * CO + cob + pB) * CI;
  };
  auto stage = [&](int kk, int pb) {
    const int ci0 = kk << 6;
#pragma unroll
    for (int s = 0; s < NSA; ++s) {
      const int cc = ((tid + 256 * s) / BM) & 7;
      const int lb = ((tid & ~63) + 256 * s) * 8;
      const f16* sp = cv ? cah + ci0 + cc * 8 : (const f16*)zp;
      async16(sp, &sA[pb][lb]);
    }
#pragma unroll
    for (int s = 0; s < NSB; ++s) {
      const int cc = ((tid + 256 * s) / BN) & 7;
      const int lb = ((tid & ~63) + 256 * s) * 8;
      async16(wh + cwb + ci0 + cc * 8, &sB[pb][lb]);
    }
  };

  tapbase(0);
  stage(0, 0);
  int t = 0, k = 0, p = 0;
  const int total = 9 * KI;
  for (int i = 0; i < total; ++i) {
    __syncthreads();
    int kn = k + 1, tn = t;
    if (kn == KI) { kn = 0; tn = t + 1; }
    if (tn < 9) {
      if (tn != t) tapbase(tn);
      stage(kn, p ^ 1);
    }
#pragma unroll
    for (int kc = 0; kc < 2; ++kc) {
      f16x8 fa[4], fb[4];
#pragma unroll
      for (int mi = 0; mi < 4; ++mi)
        fa[mi] = *(const f16x8*)&sA[p][((kc * 4 + quad) * BM + wm + mi * 16 + mrow) * 8];
#pragma unroll
      for (int ni = 0; ni < 4; ++ni)
        fb[ni] = *(const f16x8*)&sB[p][((kc * 4 + quad) * BN + wn + ni * 16 + mrow) * 8];
#pragma unroll
      for (int mi = 0; mi < 4; ++mi)
#pragma unroll
        for (int ni = 0; ni < 4; ++ni)
          acc[mi][ni] = __builtin_amdgcn_mfma_f32_16x16x32_f16(fa[mi], fb[ni], acc[mi][ni], 0, 0, 0);
    }
    k = kn; t = tn; p ^= 1;
  }
  const float inv = 1.0f / 4096.0f;
  float bvs[4];
#pragma unroll
  for (int ni = 0; ni < 4; ++ni) bvs[ni] = bias[cob + wn + ni * 16 + mrow];
#pragma unroll
  for (int mi = 0; mi < 4; ++mi) {
#pragma unroll
    for (int rg = 0; rg < 4; ++rg) {
      int px = wm + mi * 16 + quad * 4 + rg;
      int hh = h0 + (px >> 6), wwp = px & 63;
#pragma unroll
      for (int ni = 0; ni < 4; ++ni) {
        int co = cob + wn + ni * 16 + mrow;
        float vv = fmaxf(acc[mi][ni][rg] * inv + bvs[ni], 0.f);
        if (F32OUT) {
          of[(((size_t)b * CO + co) * 64 + hh) * 64 + wwp] = vv;
        } else {
          oh[(((size_t)b * 64 + hh) * 64 + wwp) * CO + co] = (f16)(vv * 16.f);
        }
      }
    }
  }
}

// ---------------- scan weight frag prep: w[64][64][9] -> frag order ---------

__global__ void rf_wfrag(const float* __restrict__ w, f16* __restrict__ fh) {
  int gid = blockIdx.x * 256 + threadIdx.x;
  if (gid >= 4608) return;
  int lane = gid & 63;
  int rem = gid >> 6;
  int kc = rem & 1;
  int rem2 = rem >> 1;
  int t = rem2 % 9;
  int w4 = rem2 / 9;
  int co = w4 * 16 + (lane & 15);
  int cib = kc * 32 + (lane >> 4) * 8;
  f16x8 hb;
#pragma unroll
  for (int j = 0; j < 8; ++j)
    hb[j] = (f16)(256.f * w[((size_t)co * 64 + cib + j) * 9 + t]);
  *(f16x8*)&fh[(size_t)gid * 8] = hb;
}

// ---------------- MFMA recurrent scan (single fp16 carry) ------------------

__global__ __launch_bounds__(256, 1) void rf_mscan(
    const float* __restrict__ src, float* __restrict__ dst,
    const f16* __restrict__ fh, const float* __restrict__ bias, int dir) {
  __shared__ f16 ch[72 * 64];
  const int b = blockIdx.x;
  const int tid = threadIdx.x;
  const int wave = tid >> 6, lane = tid & 63;
  const int quad = lane >> 4, l15 = lane & 15;

  f16x8 Ah[9][2];
#pragma unroll
  for (int t = 0; t < 9; ++t)
#pragma unroll
    for (int kc = 0; kc < 2; ++kc)
      Ah[t][kc] = *(const f16x8*)&fh[(((wave * 9 + t) * 2 + kc) * 64 + lane) * 8];
  float bvs[4];
#pragma unroll
  for (int r = 0; r < 4; ++r) bvs[r] = bias[wave * 16 + quad * 4 + r];

  for (int s = tid; s < 2304; s += 256) ((unsigned*)ch)[s] = 0u;
  __syncthreads();

  const size_t sbase = (size_t)b * 64 * 4096;
  const int row0 = (dir > 0) ? 0 : 63;
  {
    int pos0 = tid & 63, cig = tid >> 6;
#pragma unroll
    for (int q = 0; q < 16; ++q) {
      int ci = cig * 16 + q;
      float v = src[sbase + (size_t)ci * 4096 + row0 * 64 + pos0];
      dst[sbase + (size_t)ci * 4096 + row0 * 64 + pos0] = v;
      int rowIdx = pos0 + 4;
      ch[rowIdx * 64 + (((ci >> 3) ^ (rowIdx & 7)) << 3) + (ci & 7)] = (f16)v;
    }
  }
  __syncthreads();

  const float inv = 1.0f / 256.0f;
  for (int s = 1; s < 64; ++s) {
    const int row = (dir > 0) ? s : 63 - s;
    float srow[4][4];
#pragma unroll
    for (int nt = 0; nt < 4; ++nt)
#pragma unroll
      for (int r = 0; r < 4; ++r)
        srow[nt][r] = src[sbase + (size_t)(wave * 16 + quad * 4 + r) * 4096 +
                          row * 64 + nt * 16 + l15];
    f32x4 acc[4];
#pragma unroll
    for (int nt = 0; nt < 4; ++nt) acc[nt] = (f32x4){0.f, 0.f, 0.f, 0.f};
#pragma unroll
    for (int t = 0; t < 9; ++t)
#pragma unroll
      for (int kc = 0; kc < 2; ++kc) {
#pragma unroll
        for (int nt = 0; nt < 4; ++nt) {
          int rowIdx = nt * 16 + l15 + t;
          int gr = kc * 4 + quad;
          f16x8 Bh = *(const f16x8*)&ch[rowIdx * 64 + ((gr ^ (rowIdx & 7)) << 3)];
          acc[nt] = __builtin_amdgcn_mfma_f32_16x16x32_f16(Ah[t][kc], Bh, acc[nt], 0, 0, 0);
        }
      }
    __syncthreads();
#pragma unroll
    for (int nt = 0; nt < 4; ++nt) {
      int pos = nt * 16 + l15;
      int rowIdx = pos + 4;
      f16x4 hv;
#pragma unroll
      for (int r = 0; r < 4; ++r) {
        float v = fmaxf(acc[nt][r] * inv + bvs[r], 0.f) + srow[nt][r];
        dst[sbase + (size_t)(wave * 16 + quad * 4 + r) * 4096 + row * 64 + pos] = v;
        hv[r] = (f16)v;
      }
      int ci0 = wave * 16 + quad * 4;
      *(f16x4*)&ch[rowIdx * 64 + (((ci0 >> 3) ^ (rowIdx & 7)) << 3) + (ci0 & 7)] = hv;
    }
    __syncthreads();
  }
}

// ---------------- transpose last two dims (64x64) per (b,c) ----------------

__global__ void rf_transpose(const float* __restrict__ src, float* __restrict__ dst) {
  int bc = blockIdx.x;  // 256
  __shared__ float tl[64][65];
  int tid = threadIdx.x;
  const float* sp = src + (size_t)bc * 4096;
  float* dp = dst + (size_t)bc * 4096;
  for (int s = tid; s < 4096; s += 256) {
    int h = s >> 6, w = s & 63;
    tl[w][h] = sp[s];
  }
  __syncthreads();
  for (int s = tid; s < 4096; s += 256) dp[s] = tl[s >> 6][s & 63];
}

// ---------------- final 1x1 conv + relu + 8x8 upsample ----------------

__global__ void rf_final(const float* __restrict__ t, const float* __restrict__ ow,
                         const float* __restrict__ ob, float* __restrict__ out) {
  int b = blockIdx.y;
  int s = blockIdx.x * 256 + threadIdx.x;  // 0..4095
  int w = s >> 6, h = s & 63;
  float acc = ob[0];
  for (int c = 0; c < 64; ++c)
    acc += ow[c] * t[(((size_t)b * 64 + c) * 64 + w) * 64 + h];
  acc = fmaxf(acc, 0.f);
  float4 vv = make_float4(acc, acc, acc, acc);
  for (int dy = 0; dy < 8; ++dy) {
    float* dp = out + ((size_t)b * 512 + h * 8 + dy) * 512 + w * 8;
    *(float4*)dp = vv;
    *(float4*)(dp + 4) = vv;
  }
}

// ---------------- launch ----------------

extern "C" void kernel_launch(void* const* d_in, const int* in_sizes, int n_in,
                              void* d_out, int out_size, void* d_ws, size_t ws_size,
                              hipStream_t stream) {
  const float* in    = (const float*)d_in[0];
  const float* wA    = (const float*)d_in[1];
  const float* bA    = (const float*)d_in[2];
  const float* wB    = (const float*)d_in[3];
  const float* wC    = (const float*)d_in[5];
  const float* bC    = (const float*)d_in[6];
  const float* gamma = (const float*)d_in[7];
  const float* bw1 = (const float*)d_in[8];  const float* bb1 = (const float*)d_in[9];
  const float* bw2 = (const float*)d_in[10]; const float* bb2 = (const float*)d_in[11];
  const float* bw3 = (const float*)d_in[12]; const float* bb3 = (const float*)d_in[13];
  const float* bw4 = (const float*)d_in[14]; const float* bb4 = (const float*)d_in[15];
  const float* bw5 = (const float*)d_in[16]; const float* bb5 = (const float*)d_in[17];
  const float* bw6 = (const float*)d_in[18]; const float* bb6 = (const float*)d_in[19];
  const float* du_w = (const float*)d_in[20]; const float* du_b = (const float*)d_in[21];
  const float* lr_w = (const float*)d_in[22]; const float* lr_b = (const float*)d_in[23];
  const float* ow   = (const float*)d_in[24]; const float* ob   = (const float*)d_in[25];
  float* out = (float*)d_out;
  float* ws = (float*)d_ws;

  // phase-1 (attention) buffers; offsets in f32 slots (f16 elems = 2x)
  f16* vH  = (f16*)(ws + 0);          // 16.8M f16 -> [0, 4194304)
  f16* xTh = (f16*)(ws + 4194304);    // [4194304, 8388608)
  f16* wCh = (f16*)(ws + 8388608);    // [8388608, 8912896)
  f16* yH  = (f16*)(ws + 16777216);   // [16777216, 20971520)
  // conv phase
  f16* w1h = (f16*)(ws + 0);          // [0, 2359296)
  f16* c1H = (f16*)(ws + 2359296);    // [2359296, 6553600)
  f16* w3h = (f16*)(ws + 6553600);    // [6553600, 7733248)
  f16* w2h = (f16*)(ws + 16777216);   // [16777216, 17956864)  (yH dead)
  f16* c2H = (f16*)(ws + 17956864);   // [17956864, 22151168)
  f16* w4h = (f16*)(ws + 22151168);   // [22151168, 22740992)
  f16* c4H = (f16*)(ws + 22740992);   // [22740992, 24838144)
  f16* c3H = c1H;
  f16* w5h = (f16*)(ws + 0);          // [0, 147456)       (w1 dead)
  f16* c5H = (f16*)(ws + 147456);     // [147456, 1196032)
  f16* w6h = (f16*)(ws + 1196032);    // [1196032, 1232896)
  float* tin = ws + 1232896;          // [1232896, 2281472)
  float* t0  = ws + 2281472;          // [2281472, 3330048)
  float* t1  = ws + 3330048;          // [3330048, 4378624)
  f16* duFh = (f16*)(ws + 4378624);   // [4378624, 4397056)  (c1/c3 dead)
  f16* lrFh = (f16*)(ws + 4397056);   // [4397056, 4415488)
  float* sm = ws + 33554432;
  float* A_  = sm;
  float* M_  = sm + 16384;
  float* iZ  = sm + 32768;
  float* u_  = sm + 49152;
  float* s_  = sm + 50176;
  float* c0_ = sm + 50304;
  float* fst = sm + 50308;
  float* zp  = sm + 50432;  // 64-float zero page for OOB DMA lanes

  rf_zero<<<1, 64, 0, stream>>>(zp);
  rf_s<<<1, 128, 0, stream>>>(wB, bA, s_, c0_);
  rf_u<<<4, 256, 0, stream>>>(wA, s_, u_);
  rf_fstat<<<4, 256, 0, stream>>>(in, fst);
  rf_A<<<dim3(16, 4), 256, 0, stream>>>(in, u_, c0_, fst, A_, M_);
  rf_Z<<<4096, 256, 0, stream>>>(in, A_, M_, iZ);
  rf_xsplit<<<dim3(64, 16, 4), 256, 0, stream>>>(in, xTh);
  rf_wC1<<<512, 256, 0, stream>>>(wC, wCh);
  rf_vgemmm<<<dim3(32, 8, 4), 256, 0, stream>>>(wCh, xTh, bC, vH);
  rf_attm<<<dim3(32, 8, 4), 256, 0, stream>>>(vH, A_, M_, iZ, in, gamma, yH);

  rf_wsingle<<<2048, 256, 0, stream>>>(bw1, w1h, 512, 1024);
  rf_wsingle<<<1024, 256, 0, stream>>>(bw3, w3h, 512, 512);
  rf_mconv<128, 128, false><<<dim3(128, 4), 256, 0, stream>>>(
      yH, w1h, bb1, zp, c1H, nullptr, 1024, 512);
  rf_wsingle<<<1024, 256, 0, stream>>>(bw2, w2h, 512, 512);
  rf_wsingle<<<512, 256, 0, stream>>>(bw4, w4h, 256, 512);
  rf_wsingle<<<128, 256, 0, stream>>>(bw5, w5h, 128, 256);
  rf_wsingle<<<32, 256, 0, stream>>>(bw6, w6h, 64, 128);
  rf_mconv<128, 128, false><<<dim3(128, 4), 256, 0, stream>>>(
      c1H, w2h, bb2, zp, c2H, nullptr, 512, 512);
  rf_mconv<128, 128, false><<<dim3(128, 4), 256, 0, stream>>>(
      c2H, w3h, bb3, zp, c3H, nullptr, 512, 512);
  rf_mconv<128, 128, false><<<dim3(128, 2), 256, 0, stream>>>(
      c3H, w4h, bb4, zp, c4H, nullptr, 512, 256);
  rf_wfrag<<<18, 256, 0, stream>>>(du_w, duFh);
  rf_wfrag<<<18, 256, 0, stream>>>(lr_w, lrFh);
  rf_mconv<128, 128, false><<<dim3(128, 1), 256, 0, stream>>>(
      c4H, w5h, bb5, zp, c5H, nullptr, 256, 128);
  rf_mconv<256, 64, true><<<dim3(64, 1), 256, 0, stream>>>(
      c5H, w6h, bb6, zp, nullptr, tin, 128, 64);

  rf_mscan<<<4, 256, 0, stream>>>(tin, t0, duFh, du_b, +1);
  rf_mscan<<<4, 256, 0, stream>>>(t0, t1, duFh, du_b, -1);
  rf_transpose<<<256, 256, 0, stream>>>(t1, t0);
  rf_mscan<<<4, 256, 0, stream>>>(t0, t1, lrFh, lr_b, +1);
  rf_mscan<<<4, 256, 0, stream>>>(t1, t0, lrFh, lr_b, -1);
  rf_final<<<dim3(16, 4), 256, 0, stream>>>(t0, ow, ob, out);
}

// Round 2
// 1828.154 us; speedup vs baseline: 1.0949x; 1.0949x over previous
//
#include <hip/hip_runtime.h>

// resFAN round 8 (R1 this session): halo-staged conv.
// r7 counters: conv = 37% of runtime at MfmaUtil 22% / VALUBusy 13% / LDS-conflict 0
// / occupancy 23% (grid-limited 2 blocks/CU) -> latency-bound convoy, and 9x
// redundant A-staging (per-tap re-stage of same pixels).  New rf_mconv stages a
// 6x68-px halo tile once per 32-ci chunk (single-buffered, 28KB) and runs all
// 9 taps from it via shifted ds_read_b128 (px stride 16B keeps alignment);
// weights double-buffered per tap (2x8KB).  A-staging traffic/instr ~9x down,
// per-barrier VMEM in flight 8->2 loads.  LDS 64KB->44KB.
//
// Error budget unchanged: fp16 quant 2^-11 per tensor, scales 16/256, inv 1/4096.

#define NPIX 4096

typedef _Float16 f16;
typedef _Float16 f16x8 __attribute__((ext_vector_type(8)));
typedef _Float16 f16x4 __attribute__((ext_vector_type(4)));
typedef float f32x4 __attribute__((ext_vector_type(4)));

__device__ inline void async16(const void* g, void* l) {
  __builtin_amdgcn_global_load_lds(
      (const __attribute__((address_space(1))) unsigned int*)g,
      (__attribute__((address_space(3))) unsigned int*)l, 16, 0, 0);
}

// ---------------- small prep kernels ----------------

__global__ void rf_zero(float* __restrict__ z) { z[threadIdx.x] = 0.f; }

__global__ void rf_s(const float* __restrict__ wB, const float* __restrict__ bA,
                     float* __restrict__ s_out, float* __restrict__ c0_out) {
  int c = threadIdx.x;  // 128 threads
  const float* row = wB + (size_t)c * 1024;
  float acc = 0.f;
  for (int i = 0; i < 1024; ++i) acc += row[i];
  s_out[c] = acc;
  __shared__ float sh[128];
  sh[c] = acc * bA[c];
  __syncthreads();
  for (int off = 64; off > 0; off >>= 1) {
    if (c < off) sh[c] += sh[c + off];
    __syncthreads();
  }
  if (c == 0) c0_out[0] = sh[0];
}

__global__ void rf_u(const float* __restrict__ wA, const float* __restrict__ s,
                     float* __restrict__ u) {
  int i = blockIdx.x * 256 + threadIdx.x;  // 1024 total
  float acc = 0.f;
  for (int c = 0; c < 128; ++c) acc += s[c] * wA[(size_t)c * 1024 + i];
  u[i] = acc;
}

__global__ void rf_fstat(const float* __restrict__ in, float* __restrict__ fstat) {
  int b = blockIdx.x;
  int t = threadIdx.x;
  const float* f = in + ((size_t)b * 1025 + 1024) * NPIX;
  float mx = -1e30f, mn = 1e30f;
  for (int j = t; j < NPIX; j += 256) {
    float v = f[j];
    mx = fmaxf(mx, v);
    mn = fminf(mn, v);
  }
  __shared__ float smx[256], smn[256];
  smx[t] = mx; smn[t] = mn;
  __syncthreads();
  for (int off = 128; off > 0; off >>= 1) {
    if (t < off) {
      smx[t] = fmaxf(smx[t], smx[t + off]);
      smn[t] = fminf(smn[t], smn[t + off]);
    }
    __syncthreads();
  }
  if (t == 0) { fstat[b] = smx[0]; fstat[4 + b] = smn[0]; }
}

__global__ __launch_bounds__(256) void rf_A(const float* __restrict__ in,
                                            const float* __restrict__ u,
                                            const float* __restrict__ c0p,
                                            const float* __restrict__ fst,
                                            float* __restrict__ A, float* __restrict__ M) {
  __shared__ float ul[1024];
  int b = blockIdx.y;
  int n = blockIdx.x * 256 + threadIdx.x;
  for (int s = threadIdx.x; s < 1024; s += 256) ul[s] = u[s];
  __syncthreads();
  const float* xp = in + (size_t)b * 1025 * NPIX + n;
  float acc = c0p[0];
#pragma unroll 8
  for (int i = 0; i < 1024; ++i) acc = fmaf(ul[i], xp[(size_t)i * NPIX], acc);
  A[b * NPIX + n] = acc;
  M[b * NPIX + n] = fmaxf(acc * fst[b], acc * fst[4 + b]);
}

__global__ void rf_Z(const float* __restrict__ in, const float* __restrict__ A,
                     const float* __restrict__ M, float* __restrict__ iZ) {
  int idx = blockIdx.x * 4 + (threadIdx.x >> 6);  // (b,n) pair, 16384 total
  int lane = threadIdx.x & 63;
  int b = idx >> 12;
  const float* f = in + ((size_t)b * 1025 + 1024) * NPIX;
  float a = A[idx], m = M[idx];
  float acc = 0.f;
#pragma unroll 4
  for (int it = 0; it < 64; ++it) acc += __expf(a * f[lane + it * 64] - m);
  for (int off = 32; off > 0; off >>= 1) acc += __shfl_down(acc, off, 64);
  if (lane == 0) iZ[idx] = 1.0f / acc;
}

// ---------------- x transpose: [b][ci][n] f32 -> [b][n][ci] f16, scale 16 ---

__global__ void rf_xsplit(const float* __restrict__ in, f16* __restrict__ xh) {
  __shared__ float tl[64][65];
  int nt = blockIdx.x, ct = blockIdx.y, b = blockIdx.z;
  int n0 = nt * 64, c0 = ct * 64;
  int tid = threadIdx.x;
  for (int s = tid; s < 4096; s += 256) {
    int r = s >> 6, c = s & 63;
    tl[r][c] = in[((size_t)b * 1025 + c0 + r) * NPIX + n0 + c];
  }
  __syncthreads();
  for (int s = tid; s < 512; s += 256) {
    int n = s >> 3, g = s & 7;
    f16x8 hb;
#pragma unroll
    for (int q = 0; q < 8; ++q) hb[q] = (f16)(16.f * tl[g * 8 + q][n]);
    size_t o = ((size_t)b * NPIX + n0 + n) * 1024 + c0 + g * 8;
    *(f16x8*)&xh[o] = hb;
  }
}

// ---------------- wC cast: [1024][1024] f32 -> f16, scale 256 --------------

__global__ void rf_wC1(const float* __restrict__ wC, f16* __restrict__ wh) {
  int base = (blockIdx.x * 256 + threadIdx.x) * 8;
  f16x8 hb;
#pragma unroll
  for (int q = 0; q < 8; ++q) hb[q] = (f16)(256.f * wC[base + q]);
  *(f16x8*)&wh[base] = hb;
}

// ---------------- MFMA v-GEMM (dbuf, single fp16): v = wC @ x + bC --------

__global__ __launch_bounds__(256, 2) void rf_vgemmm(
    const f16* __restrict__ wh, const f16* __restrict__ xh,
    const float* __restrict__ bC, f16* __restrict__ vH) {
  __shared__ f16 sA[2][4096], sB[2][4096];
  const int tid = threadIdx.x;
  const int nb = blockIdx.x * 128, cb = blockIdx.y * 128, b = blockIdx.z;
  const int pA = tid & 127;
  const int wv = tid >> 6, lane = tid & 63;
  const int mrow = lane & 15, quad = lane >> 4;
  const int wm = (wv & 1) * 64, wn = (wv >> 1) * 64;
  const size_t abase = (size_t)(cb + pA) * 1024;
  const size_t bbase = ((size_t)b * NPIX + nb + pA) * 1024;
  f32x4 acc[4][4];
#pragma unroll
  for (int i = 0; i < 4; ++i)
#pragma unroll
    for (int j = 0; j < 4; ++j) acc[i][j] = (f32x4){0.f, 0.f, 0.f, 0.f};

  auto stage = [&](int k0, int pb) {
#pragma unroll
    for (int s = 0; s < 2; ++s) {
      const int cc = ((tid + 256 * s) >> 7) & 3;
      const int lb = ((tid & ~63) + 256 * s) * 8;
      async16(wh + abase + k0 + cc * 8, &sA[pb][lb]);
      async16(xh + bbase + k0 + cc * 8, &sB[pb][lb]);
    }
  };
  stage(0, 0);
  int p = 0;
  for (int k0 = 0; k0 < 1024; k0 += 32) {
    __syncthreads();
    if (k0 + 32 < 1024) stage(k0 + 32, p ^ 1);
    f16x8 fa[4], fb[4];
#pragma unroll
    for (int mi = 0; mi < 4; ++mi)
      fa[mi] = *(const f16x8*)&sA[p][(quad * 128 + wm + mi * 16 + mrow) * 8];
#pragma unroll
    for (int ni = 0; ni < 4; ++ni)
      fb[ni] = *(const f16x8*)&sB[p][(quad * 128 + wn + ni * 16 + mrow) * 8];
#pragma unroll
    for (int mi = 0; mi < 4; ++mi)
#pragma unroll
      for (int ni = 0; ni < 4; ++ni)
        acc[mi][ni] = __builtin_amdgcn_mfma_f32_16x16x32_f16(fa[mi], fb[ni], acc[mi][ni], 0, 0, 0);
    p ^= 1;
  }
  const float inv = 1.0f / 4096.0f;
#pragma unroll
  for (int mi = 0; mi < 4; ++mi) {
#pragma unroll
    for (int rg = 0; rg < 4; ++rg) {
      int c = cb + wm + mi * 16 + quad * 4 + rg;
      float bv = bC[c];
#pragma unroll
      for (int ni = 0; ni < 4; ++ni) {
        int j = nb + wn + ni * 16 + mrow;
        vH[((size_t)b * 1024 + c) * NPIX + j] =
            (f16)(16.f * (acc[mi][ni][rg] * inv + bv));
      }
    }
  }
}

// ---------------- MFMA attention out-GEMM (single fp16) -> y ---------------

__global__ __launch_bounds__(256, 2) void rf_attm(
    const f16* __restrict__ vH,
    const float* __restrict__ Aarr, const float* __restrict__ Marr,
    const float* __restrict__ iZ, const float* __restrict__ in,
    const float* __restrict__ gptr, f16* __restrict__ yH) {
  __shared__ f16 sAh[4096], sPh[4096];
  const int tid = threadIdx.x;
  const int ib = blockIdx.x * 128, cb = blockIdx.y * 128, b = blockIdx.z;
  const int pA = tid & 127;
  const int wv = tid >> 6, lane = tid & 63;
  const int mrow = lane & 15, quad = lane >> 4;
  const int wm = (wv & 1) * 64, wn = (wv >> 1) * 64;
  const size_t vbase = ((size_t)b * 1024 + cb + pA) * NPIX;
  const int ni_ = tid & 127;
  const int kc0 = tid >> 7;  // 0..1
  const float av = Aarr[b * NPIX + ib + ni_];
  const float mv = Marr[b * NPIX + ib + ni_];
  const float zv = iZ[b * NPIX + ib + ni_] * 16.f;
  const float* f = in + ((size_t)b * 1025 + 1024) * NPIX;
  f32x4 acc[4][4];
#pragma unroll
  for (int i = 0; i < 4; ++i)
#pragma unroll
    for (int j = 0; j < 4; ++j) acc[i][j] = (f32x4){0.f, 0.f, 0.f, 0.f};
  for (int j0 = 0; j0 < NPIX; j0 += 32) {
#pragma unroll
    for (int s = 0; s < 2; ++s) {
      const int cc = ((tid + 256 * s) >> 7) & 3;
      const int lb = ((tid & ~63) + 256 * s) * 8;
      async16(vH + vbase + j0 + cc * 8, &sAh[lb]);
    }
#pragma unroll
    for (int it = 0; it < 2; ++it) {
      const int kc = kc0 + 2 * it;
      const float4 fa = *(const float4*)&f[j0 + kc * 8];
      const float4 fb = *(const float4*)&f[j0 + kc * 8 + 4];
      const float fj[8] = {fa.x, fa.y, fa.z, fa.w, fb.x, fb.y, fb.z, fb.w};
      f16x8 ph;
#pragma unroll
      for (int q = 0; q < 8; ++q)
        ph[q] = (f16)(__expf(fmaf(av, fj[q], -mv)) * zv);
      *(f16x8*)&sPh[(kc * 128 + ni_) * 8] = ph;
    }
    __syncthreads();
    f16x8 fa[4], fb[4];
#pragma unroll
    for (int mi = 0; mi < 4; ++mi)
      fa[mi] = *(const f16x8*)&sAh[(quad * 128 + wm + mi * 16 + mrow) * 8];
#pragma unroll
    for (int ni = 0; ni < 4; ++ni)
      fb[ni] = *(const f16x8*)&sPh[(quad * 128 + wn + ni * 16 + mrow) * 8];
#pragma unroll
    for (int mi = 0; mi < 4; ++mi)
#pragma unroll
      for (int ni = 0; ni < 4; ++ni)
        acc[mi][ni] = __builtin_amdgcn_mfma_f32_16x16x32_f16(fa[mi], fb[ni], acc[mi][ni], 0, 0, 0);
    __syncthreads();
  }
  const float g = gptr[0];
  const float inv = 1.0f / 256.0f;
#pragma unroll
  for (int mi = 0; mi < 4; ++mi) {
    const int cbase = cb + wm + mi * 16 + quad * 4;
#pragma unroll
    for (int ni = 0; ni < 4; ++ni) {
      const int i = ib + wn + ni * 16 + mrow;
      f16x4 hv;
#pragma unroll
      for (int rg = 0; rg < 4; ++rg) {
        float xr = in[((size_t)b * 1025 + cbase + rg) * NPIX + i];
        hv[rg] = (f16)(16.f * (g * (acc[mi][ni][rg] * inv) + xr));
      }
      *(f16x4*)&yH[((size_t)b * NPIX + i) * 1024 + cbase] = hv;
    }
  }
}

// ---------------- weight cast prep: [CO][CI][3][3] -> [9][CO][CI] f16 ------

__global__ void rf_wsingle(const float* __restrict__ w, f16* __restrict__ wh,
                           int CO, int CI) {
  int idx = blockIdx.x * 256 + threadIdx.x;  // co*CI + ci
  if (idx >= CO * CI) return;
  int co = idx / CI, ci = idx - co * CI;
#pragma unroll
  for (int t = 0; t < 9; ++t)
    wh[((size_t)t * CO + co) * CI + ci] = (f16)(256.0f * w[(size_t)idx * 9 + t]);
}

// ---------------- MFMA dilated 3x3 conv (halo-staged A, single fp16) -------
// A: one 32-ci chunk staged as halo tile [HROWS][ks4][col68][8] (single buf);
// all 9 taps read shifted windows from it.  B: per-tap weights, double-buffered.

template <int BM, int BN, bool F32OUT>
__global__ __launch_bounds__(256, 2) void rf_mconv(
    const f16* __restrict__ xh, const f16* __restrict__ wh,
    const float* __restrict__ bias, const float* __restrict__ zp,
    f16* __restrict__ oh, float* __restrict__ of, int CI, int CO) {
  constexpr int ROWS = BM / 64;
  constexpr int TPI = 4096 / BM;
  constexpr int HROWS = ROWS + 4;               // +-2 row halo
  constexpr int CHUNKS = HROWS * 4 * 68;        // 16B chunks in halo tile
  constexpr int NSTG = (CHUNKS + 255) / 256;    // A stage instrs per thread
  constexpr int NSB = BN / 64;                  // B stage instrs per thread
  __shared__ f16 sA[NSTG * 2048];               // [row][ks][col68][8] (+slack)
  __shared__ f16 sB[2][BN * 32];                // [ks4][BN][8]
  const int tid = threadIdx.x;
  const int blkpx = blockIdx.x;
  const int cob = blockIdx.y * BN;
  const int b = blkpx / TPI;
  const int h0 = (blkpx - b * TPI) * ROWS;

  const int pB = tid & (BN - 1);
  const int wv = tid >> 6, lane = tid & 63;
  const int mrow = lane & 15, quad = lane >> 4;
  const int wm = (BN == 128) ? (wv & 1) * 64 : wv * 64;
  const int wn = (BN == 128) ? (wv >> 1) * 64 : 0;
  const int r_out = wm >> 6;
  const int KI = CI >> 5;

  f32x4 acc[4][4];
#pragma unroll
  for (int i = 0; i < 4; ++i)
#pragma unroll
    for (int j = 0; j < 4; ++j) acc[i][j] = (f32x4){0.f, 0.f, 0.f, 0.f};

  // per-lane A staging sources (affine in k: +k*32 f16 when valid)
  const f16* abase[NSTG];
  unsigned vmask = 0;
#pragma unroll
  for (int s = 0; s < NSTG; ++s) {
    int idx = tid + 256 * s;
    int rowks = (idx * 241) >> 14;   // = idx/68, exact for idx <= 2303
    int col = idx - rowks * 68;
    int r = rowks >> 2, ks = rowks & 3;
    int srow = h0 + r - 2, scol = col - 2;
    bool ok = (idx < CHUNKS) && ((unsigned)srow < 64u) && ((unsigned)scol < 64u);
    abase[s] = ok ? xh + (((size_t)b * 64 + srow) * 64 + scol) * CI + ks * 8
                  : (const f16*)zp;
    if (ok) vmask |= (1u << s);
  }
  // per-lane B staging sources
  const f16* wbase[NSB];
#pragma unroll
  for (int s = 0; s < NSB; ++s) {
    int cc = ((tid + 256 * s) / BN) & 3;
    wbase[s] = wh + (size_t)(cob + pB) * CI + cc * 8;
  }
  const size_t tstride = (size_t)CO * CI;

  auto stageA = [&](int k) {
#pragma unroll
    for (int s = 0; s < NSTG; ++s) {
      const f16* sp = abase[s] + (((vmask >> s) & 1u) ? k * 32 : 0);
      async16(sp, &sA[((tid & ~63) + 256 * s) * 8]);
    }
  };
  auto stageB = [&](int t, int k, int pb) {
#pragma unroll
    for (int s = 0; s < NSB; ++s)
      async16(wbase[s] + (size_t)t * tstride + k * 32,
              &sB[pb][((tid & ~63) + 256 * s) * 8]);
  };

  stageA(0);
  stageB(0, 0, 0);
  for (int k = 0; k < KI; ++k) {
#pragma unroll
    for (int t = 0; t < 9; ++t) {
      const int pb = (k + t) & 1;
      __syncthreads();          // drains: B(t,k) (+A(k) at t==0)
      if (t < 8) {
        stageB(t + 1, k, pb ^ 1);
      } else if (k + 1 < KI) {
        stageB(0, k + 1, pb ^ 1);
      }
      const int dh = (t / 3) * 2 - 2, dw = (t - (t / 3) * 3) * 2 - 2;
      f16x8 fa[4], fb[4];
#pragma unroll
      for (int mi = 0; mi < 4; ++mi)
        fa[mi] = *(const f16x8*)&sA[(((r_out + dh + 2) * 4 + quad) * 68 +
                                    mi * 16 + mrow + dw + 2) * 8];
#pragma unroll
      for (int ni = 0; ni < 4; ++ni)
        fb[ni] = *(const f16x8*)&sB[pb][(quad * BN + wn + ni * 16 + mrow) * 8];
#pragma unroll
      for (int mi = 0; mi < 4; ++mi)
#pragma unroll
        for (int ni = 0; ni < 4; ++ni)
          acc[mi][ni] = __builtin_amdgcn_mfma_f32_16x16x32_f16(fa[mi], fb[ni], acc[mi][ni], 0, 0, 0);
    }
    if (k + 1 < KI) {
      __syncthreads();          // all tap reads of A(k) complete
      stageA(k + 1);            // refill halo tile (drained at next t=0 sync)
    }
  }

  const float inv = 1.0f / 4096.0f;
  float bvs[4];
#pragma unroll
  for (int ni = 0; ni < 4; ++ni) bvs[ni] = bias[cob + wn + ni * 16 + mrow];
#pragma unroll
  for (int mi = 0; mi < 4; ++mi) {
#pragma unroll
    for (int rg = 0; rg < 4; ++rg) {
      int px = wm + mi * 16 + quad * 4 + rg;
      int hh = h0 + (px >> 6), wwp = px & 63;
#pragma unroll
      for (int ni = 0; ni < 4; ++ni) {
        int co = cob + wn + ni * 16 + mrow;
        float vv = fmaxf(acc[mi][ni][rg] * inv + bvs[ni], 0.f);
        if (F32OUT) {
          of[(((size_t)b * CO + co) * 64 + hh) * 64 + wwp] = vv;
        } else {
          oh[(((size_t)b * 64 + hh) * 64 + wwp) * CO + co] = (f16)(vv * 16.f);
        }
      }
    }
  }
}

// ---------------- scan weight frag prep: w[64][64][9] -> frag order ---------

__global__ void rf_wfrag(const float* __restrict__ w, f16* __restrict__ fh) {
  int gid = blockIdx.x * 256 + threadIdx.x;
  if (gid >= 4608) return;
  int lane = gid & 63;
  int rem = gid >> 6;
  int kc = rem & 1;
  int rem2 = rem >> 1;
  int t = rem2 % 9;
  int w4 = rem2 / 9;
  int co = w4 * 16 + (lane & 15);
  int cib = kc * 32 + (lane >> 4) * 8;
  f16x8 hb;
#pragma unroll
  for (int j = 0; j < 8; ++j)
    hb[j] = (f16)(256.f * w[((size_t)co * 64 + cib + j) * 9 + t]);
  *(f16x8*)&fh[(size_t)gid * 8] = hb;
}

// ---------------- MFMA recurrent scan (single fp16 carry) ------------------

__global__ __launch_bounds__(256, 1) void rf_mscan(
    const float* __restrict__ src, float* __restrict__ dst,
    const f16* __restrict__ fh, const float* __restrict__ bias, int dir) {
  __shared__ f16 ch[72 * 64];
  const int b = blockIdx.x;
  const int tid = threadIdx.x;
  const int wave = tid >> 6, lane = tid & 63;
  const int quad = lane >> 4, l15 = lane & 15;

  f16x8 Ah[9][2];
#pragma unroll
  for (int t = 0; t < 9; ++t)
#pragma unroll
    for (int kc = 0; kc < 2; ++kc)
      Ah[t][kc] = *(const f16x8*)&fh[(((wave * 9 + t) * 2 + kc) * 64 + lane) * 8];
  float bvs[4];
#pragma unroll
  for (int r = 0; r < 4; ++r) bvs[r] = bias[wave * 16 + quad * 4 + r];

  for (int s = tid; s < 2304; s += 256) ((unsigned*)ch)[s] = 0u;
  __syncthreads();

  const size_t sbase = (size_t)b * 64 * 4096;
  const int row0 = (dir > 0) ? 0 : 63;
  {
    int pos0 = tid & 63, cig = tid >> 6;
#pragma unroll
    for (int q = 0; q < 16; ++q) {
      int ci = cig * 16 + q;
      float v = src[sbase + (size_t)ci * 4096 + row0 * 64 + pos0];
      dst[sbase + (size_t)ci * 4096 + row0 * 64 + pos0] = v;
      int rowIdx = pos0 + 4;
      ch[rowIdx * 64 + (((ci >> 3) ^ (rowIdx & 7)) << 3) + (ci & 7)] = (f16)v;
    }
  }
  __syncthreads();

  const float inv = 1.0f / 256.0f;
  for (int s = 1; s < 64; ++s) {
    const int row = (dir > 0) ? s : 63 - s;
    float srow[4][4];
#pragma unroll
    for (int nt = 0; nt < 4; ++nt)
#pragma unroll
      for (int r = 0; r < 4; ++r)
        srow[nt][r] = src[sbase + (size_t)(wave * 16 + quad * 4 + r) * 4096 +
                          row * 64 + nt * 16 + l15];
    f32x4 acc[4];
#pragma unroll
    for (int nt = 0; nt < 4; ++nt) acc[nt] = (f32x4){0.f, 0.f, 0.f, 0.f};
#pragma unroll
    for (int t = 0; t < 9; ++t)
#pragma unroll
      for (int kc = 0; kc < 2; ++kc) {
#pragma unroll
        for (int nt = 0; nt < 4; ++nt) {
          int rowIdx = nt * 16 + l15 + t;
          int gr = kc * 4 + quad;
          f16x8 Bh = *(const f16x8*)&ch[rowIdx * 64 + ((gr ^ (rowIdx & 7)) << 3)];
          acc[nt] = __builtin_amdgcn_mfma_f32_16x16x32_f16(Ah[t][kc], Bh, acc[nt], 0, 0, 0);
        }
      }
    __syncthreads();
#pragma unroll
    for (int nt = 0; nt < 4; ++nt) {
      int pos = nt * 16 + l15;
      int rowIdx = pos + 4;
      f16x4 hv;
#pragma unroll
      for (int r = 0; r < 4; ++r) {
        float v = fmaxf(acc[nt][r] * inv + bvs[r], 0.f) + srow[nt][r];
        dst[sbase + (size_t)(wave * 16 + quad * 4 + r) * 4096 + row * 64 + pos] = v;
        hv[r] = (f16)v;
      }
      int ci0 = wave * 16 + quad * 4;
      *(f16x4*)&ch[rowIdx * 64 + (((ci0 >> 3) ^ (rowIdx & 7)) << 3) + (ci0 & 7)] = hv;
    }
    __syncthreads();
  }
}

// ---------------- transpose last two dims (64x64) per (b,c) ----------------

__global__ void rf_transpose(const float* __restrict__ src, float* __restrict__ dst) {
  int bc = blockIdx.x;  // 256
  __shared__ float tl[64][65];
  int tid = threadIdx.x;
  const float* sp = src + (size_t)bc * 4096;
  float* dp = dst + (size_t)bc * 4096;
  for (int s = tid; s < 4096; s += 256) {
    int h = s >> 6, w = s & 63;
    tl[w][h] = sp[s];
  }
  __syncthreads();
  for (int s = tid; s < 4096; s += 256) dp[s] = tl[s >> 6][s & 63];
}

// ---------------- final 1x1 conv + relu + 8x8 upsample ----------------

__global__ void rf_final(const float* __restrict__ t, const float* __restrict__ ow,
                         const float* __restrict__ ob, float* __restrict__ out) {
  int b = blockIdx.y;
  int s = blockIdx.x * 256 + threadIdx.x;  // 0..4095
  int w = s >> 6, h = s & 63;
  float acc = ob[0];
  for (int c = 0; c < 64; ++c)
    acc += ow[c] * t[(((size_t)b * 64 + c) * 64 + w) * 64 + h];
  acc = fmaxf(acc, 0.f);
  float4 vv = make_float4(acc, acc, acc, acc);
  for (int dy = 0; dy < 8; ++dy) {
    float* dp = out + ((size_t)b * 512 + h * 8 + dy) * 512 + w * 8;
    *(float4*)dp = vv;
    *(float4*)(dp + 4) = vv;
  }
}

// ---------------- launch ----------------

extern "C" void kernel_launch(void* const* d_in, const int* in_sizes, int n_in,
                              void* d_out, int out_size, void* d_ws, size_t ws_size,
                              hipStream_t stream) {
  const float* in    = (const float*)d_in[0];
  const float* wA    = (const float*)d_in[1];
  const float* bA    = (const float*)d_in[2];
  const float* wB    = (const float*)d_in[3];
  const float* wC    = (const float*)d_in[5];
  const float* bC    = (const float*)d_in[6];
  const float* gamma = (const float*)d_in[7];
  const float* bw1 = (const float*)d_in[8];  const float* bb1 = (const float*)d_in[9];
  const float* bw2 = (const float*)d_in[10]; const float* bb2 = (const float*)d_in[11];
  const float* bw3 = (const float*)d_in[12]; const float* bb3 = (const float*)d_in[13];
  const float* bw4 = (const float*)d_in[14]; const float* bb4 = (const float*)d_in[15];
  const float* bw5 = (const float*)d_in[16]; const float* bb5 = (const float*)d_in[17];
  const float* bw6 = (const float*)d_in[18]; const float* bb6 = (const float*)d_in[19];
  const float* du_w = (const float*)d_in[20]; const float* du_b = (const float*)d_in[21];
  const float* lr_w = (const float*)d_in[22]; const float* lr_b = (const float*)d_in[23];
  const float* ow   = (const float*)d_in[24]; const float* ob   = (const float*)d_in[25];
  float* out = (float*)d_out;
  float* ws = (float*)d_ws;

  // phase-1 (attention) buffers; offsets in f32 slots (f16 elems = 2x)
  f16* vH  = (f16*)(ws + 0);          // 16.8M f16 -> [0, 4194304)
  f16* xTh = (f16*)(ws + 4194304);    // [4194304, 8388608)
  f16* wCh = (f16*)(ws + 8388608);    // [8388608, 8912896)
  f16* yH  = (f16*)(ws + 16777216);   // [16777216, 20971520)
  // conv phase
  f16* w1h = (f16*)(ws + 0);          // [0, 2359296)
  f16* c1H = (f16*)(ws + 2359296);    // [2359296, 6553600)
  f16* w3h = (f16*)(ws + 6553600);    // [6553600, 7733248)
  f16* w2h = (f16*)(ws + 16777216);   // [16777216, 17956864)  (yH dead)
  f16* c2H = (f16*)(ws + 17956864);   // [17956864, 22151168)
  f16* w4h = (f16*)(ws + 22151168);   // [22151168, 22740992)
  f16* c4H = (f16*)(ws + 22740992);   // [22740992, 24838144)
  f16* c3H = c1H;
  f16* w5h = (f16*)(ws + 0);          // [0, 147456)       (w1 dead)
  f16* c5H = (f16*)(ws + 147456);     // [147456, 1196032)
  f16* w6h = (f16*)(ws + 1196032);    // [1196032, 1232896)
  float* tin = ws + 1232896;          // [1232896, 2281472)
  float* t0  = ws + 2281472;          // [2281472, 3330048)
  float* t1  = ws + 3330048;          // [3330048, 4378624)
  f16* duFh = (f16*)(ws + 4378624);   // [4378624, 4397056)  (c1/c3 dead)
  f16* lrFh = (f16*)(ws + 4397056);   // [4397056, 4415488)
  float* sm = ws + 33554432;
  float* A_  = sm;
  float* M_  = sm + 16384;
  float* iZ  = sm + 32768;
  float* u_  = sm + 49152;
  float* s_  = sm + 50176;
  float* c0_ = sm + 50304;
  float* fst = sm + 50308;
  float* zp  = sm + 50432;  // 64-float zero page for OOB DMA lanes

  rf_zero<<<1, 64, 0, stream>>>(zp);
  rf_s<<<1, 128, 0, stream>>>(wB, bA, s_, c0_);
  rf_u<<<4, 256, 0, stream>>>(wA, s_, u_);
  rf_fstat<<<4, 256, 0, stream>>>(in, fst);
  rf_A<<<dim3(16, 4), 256, 0, stream>>>(in, u_, c0_, fst, A_, M_);
  rf_Z<<<4096, 256, 0, stream>>>(in, A_, M_, iZ);
  rf_xsplit<<<dim3(64, 16, 4), 256, 0, stream>>>(in, xTh);
  rf_wC1<<<512, 256, 0, stream>>>(wC, wCh);
  rf_vgemmm<<<dim3(32, 8, 4), 256, 0, stream>>>(wCh, xTh, bC, vH);
  rf_attm<<<dim3(32, 8, 4), 256, 0, stream>>>(vH, A_, M_, iZ, in, gamma, yH);

  rf_wsingle<<<2048, 256, 0, stream>>>(bw1, w1h, 512, 1024);
  rf_wsingle<<<1024, 256, 0, stream>>>(bw3, w3h, 512, 512);
  rf_mconv<128, 128, false><<<dim3(128, 4), 256, 0, stream>>>(
      yH, w1h, bb1, zp, c1H, nullptr, 1024, 512);
  rf_wsingle<<<1024, 256, 0, stream>>>(bw2, w2h, 512, 512);
  rf_wsingle<<<512, 256, 0, stream>>>(bw4, w4h, 256, 512);
  rf_wsingle<<<128, 256, 0, stream>>>(bw5, w5h, 128, 256);
  rf_wsingle<<<32, 256, 0, stream>>>(bw6, w6h, 64, 128);
  rf_mconv<128, 128, false><<<dim3(128, 4), 256, 0, stream>>>(
      c1H, w2h, bb2, zp, c2H, nullptr, 512, 512);
  rf_mconv<128, 128, false><<<dim3(128, 4), 256, 0, stream>>>(
      c2H, w3h, bb3, zp, c3H, nullptr, 512, 512);
  rf_mconv<128, 128, false><<<dim3(128, 2), 256, 0, stream>>>(
      c3H, w4h, bb4, zp, c4H, nullptr, 512, 256);
  rf_wfrag<<<18, 256, 0, stream>>>(du_w, duFh);
  rf_wfrag<<<18, 256, 0, stream>>>(lr_w, lrFh);
  rf_mconv<128, 128, false><<<dim3(128, 1), 256, 0, stream>>>(
      c4H, w5h, bb5, zp, c5H, nullptr, 256, 128);
  rf_mconv<256, 64, true><<<dim3(64, 1), 256, 0, stream>>>(
      c5H, w6h, bb6, zp, nullptr, tin, 128, 64);

  rf_mscan<<<4, 256, 0, stream>>>(tin, t0, duFh, du_b, +1);
  rf_mscan<<<4, 256, 0, stream>>>(t0, t1, duFh, du_b, -1);
  rf_transpose<<<256, 256, 0, stream>>>(t1, t0);
  rf_mscan<<<4, 256, 0, stream>>>(t0, t1, lrFh, lr_b, +1);
  rf_mscan<<<4, 256, 0, stream>>>(t1, t0, lrFh, lr_b, -1);
  rf_final<<<dim3(16, 4), 256, 0, stream>>>(t0, ow, ob, out);
}

// Round 3
// 1715.109 us; speedup vs baseline: 1.1670x; 1.0659x over previous
//
#include <hip/hip_runtime.h>

// resFAN round 9 (R2 this session): barrier-free tap loop.
// R1 post-mortem: halo staging halved FETCH (161->85MB) but (a) col-68 layout
// put quad-stride at 1088B = 64 mod 128 -> 9.4M LDS bank conflicts, and
// (b) the per-tap __syncthreads carries a compiler vmcnt(0) drain of the
// just-issued B global_load_lds -> every tap pays full load latency (~2000
// cyc/phase vs ~640 floor).  Fix: B weights pre-shuffled to MFMA-fragment
// order (rf_wfragc) and loaded straight to registers (coalesced 1KB/wave,
// L2-hot, no barrier); A halo double-buffered with col padded to 72
// (stride 1152 = 0 mod 128) -> ONE barrier per 32-ci chunk, 9 taps run on
// pure ds_read+MFMA.
//
// Error budget unchanged: fp16 quant 2^-11, scales 16/256, inv 1/4096.

#define NPIX 4096

typedef _Float16 f16;
typedef _Float16 f16x8 __attribute__((ext_vector_type(8)));
typedef _Float16 f16x4 __attribute__((ext_vector_type(4)));
typedef float f32x4 __attribute__((ext_vector_type(4)));

__device__ inline void async16(const void* g, void* l) {
  __builtin_amdgcn_global_load_lds(
      (const __attribute__((address_space(1))) unsigned int*)g,
      (__attribute__((address_space(3))) unsigned int*)l, 16, 0, 0);
}

// ---------------- small prep kernels ----------------

__global__ void rf_zero(float* __restrict__ z) { z[threadIdx.x] = 0.f; }

__global__ void rf_s(const float* __restrict__ wB, const float* __restrict__ bA,
                     float* __restrict__ s_out, float* __restrict__ c0_out) {
  int c = threadIdx.x;  // 128 threads
  const float* row = wB + (size_t)c * 1024;
  float acc = 0.f;
  for (int i = 0; i < 1024; ++i) acc += row[i];
  s_out[c] = acc;
  __shared__ float sh[128];
  sh[c] = acc * bA[c];
  __syncthreads();
  for (int off = 64; off > 0; off >>= 1) {
    if (c < off) sh[c] += sh[c + off];
    __syncthreads();
  }
  if (c == 0) c0_out[0] = sh[0];
}

__global__ void rf_u(const float* __restrict__ wA, const float* __restrict__ s,
                     float* __restrict__ u) {
  int i = blockIdx.x * 256 + threadIdx.x;  // 1024 total
  float acc = 0.f;
  for (int c = 0; c < 128; ++c) acc += s[c] * wA[(size_t)c * 1024 + i];
  u[i] = acc;
}

__global__ void rf_fstat(const float* __restrict__ in, float* __restrict__ fstat) {
  int b = blockIdx.x;
  int t = threadIdx.x;
  const float* f = in + ((size_t)b * 1025 + 1024) * NPIX;
  float mx = -1e30f, mn = 1e30f;
  for (int j = t; j < NPIX; j += 256) {
    float v = f[j];
    mx = fmaxf(mx, v);
    mn = fminf(mn, v);
  }
  __shared__ float smx[256], smn[256];
  smx[t] = mx; smn[t] = mn;
  __syncthreads();
  for (int off = 128; off > 0; off >>= 1) {
    if (t < off) {
      smx[t] = fmaxf(smx[t], smx[t + off]);
      smn[t] = fminf(smn[t], smn[t + off]);
    }
    __syncthreads();
  }
  if (t == 0) { fstat[b] = smx[0]; fstat[4 + b] = smn[0]; }
}

__global__ __launch_bounds__(256) void rf_A(const float* __restrict__ in,
                                            const float* __restrict__ u,
                                            const float* __restrict__ c0p,
                                            const float* __restrict__ fst,
                                            float* __restrict__ A, float* __restrict__ M) {
  __shared__ float ul[1024];
  int b = blockIdx.y;
  int n = blockIdx.x * 256 + threadIdx.x;
  for (int s = threadIdx.x; s < 1024; s += 256) ul[s] = u[s];
  __syncthreads();
  const float* xp = in + (size_t)b * 1025 * NPIX + n;
  float acc = c0p[0];
#pragma unroll 8
  for (int i = 0; i < 1024; ++i) acc = fmaf(ul[i], xp[(size_t)i * NPIX], acc);
  A[b * NPIX + n] = acc;
  M[b * NPIX + n] = fmaxf(acc * fst[b], acc * fst[4 + b]);
}

__global__ void rf_Z(const float* __restrict__ in, const float* __restrict__ A,
                     const float* __restrict__ M, float* __restrict__ iZ) {
  int idx = blockIdx.x * 4 + (threadIdx.x >> 6);  // (b,n) pair, 16384 total
  int lane = threadIdx.x & 63;
  int b = idx >> 12;
  const float* f = in + ((size_t)b * 1025 + 1024) * NPIX;
  float a = A[idx], m = M[idx];
  float acc = 0.f;
#pragma unroll 4
  for (int it = 0; it < 64; ++it) acc += __expf(a * f[lane + it * 64] - m);
  for (int off = 32; off > 0; off >>= 1) acc += __shfl_down(acc, off, 64);
  if (lane == 0) iZ[idx] = 1.0f / acc;
}

// ---------------- x transpose: [b][ci][n] f32 -> [b][n][ci] f16, scale 16 ---

__global__ void rf_xsplit(const float* __restrict__ in, f16* __restrict__ xh) {
  __shared__ float tl[64][65];
  int nt = blockIdx.x, ct = blockIdx.y, b = blockIdx.z;
  int n0 = nt * 64, c0 = ct * 64;
  int tid = threadIdx.x;
  for (int s = tid; s < 4096; s += 256) {
    int r = s >> 6, c = s & 63;
    tl[r][c] = in[((size_t)b * 1025 + c0 + r) * NPIX + n0 + c];
  }
  __syncthreads();
  for (int s = tid; s < 512; s += 256) {
    int n = s >> 3, g = s & 7;
    f16x8 hb;
#pragma unroll
    for (int q = 0; q < 8; ++q) hb[q] = (f16)(16.f * tl[g * 8 + q][n]);
    size_t o = ((size_t)b * NPIX + n0 + n) * 1024 + c0 + g * 8;
    *(f16x8*)&xh[o] = hb;
  }
}

// ---------------- wC cast: [1024][1024] f32 -> f16, scale 256 --------------

__global__ void rf_wC1(const float* __restrict__ wC, f16* __restrict__ wh) {
  int base = (blockIdx.x * 256 + threadIdx.x) * 8;
  f16x8 hb;
#pragma unroll
  for (int q = 0; q < 8; ++q) hb[q] = (f16)(256.f * wC[base + q]);
  *(f16x8*)&wh[base] = hb;
}

// ---------------- MFMA v-GEMM (dbuf, single fp16): v = wC @ x + bC --------

__global__ __launch_bounds__(256, 2) void rf_vgemmm(
    const f16* __restrict__ wh, const f16* __restrict__ xh,
    const float* __restrict__ bC, f16* __restrict__ vH) {
  __shared__ f16 sA[2][4096], sB[2][4096];
  const int tid = threadIdx.x;
  const int nb = blockIdx.x * 128, cb = blockIdx.y * 128, b = blockIdx.z;
  const int pA = tid & 127;
  const int wv = tid >> 6, lane = tid & 63;
  const int mrow = lane & 15, quad = lane >> 4;
  const int wm = (wv & 1) * 64, wn = (wv >> 1) * 64;
  const size_t abase = (size_t)(cb + pA) * 1024;
  const size_t bbase = ((size_t)b * NPIX + nb + pA) * 1024;
  f32x4 acc[4][4];
#pragma unroll
  for (int i = 0; i < 4; ++i)
#pragma unroll
    for (int j = 0; j < 4; ++j) acc[i][j] = (f32x4){0.f, 0.f, 0.f, 0.f};

  auto stage = [&](int k0, int pb) {
#pragma unroll
    for (int s = 0; s < 2; ++s) {
      const int cc = ((tid + 256 * s) >> 7) & 3;
      const int lb = ((tid & ~63) + 256 * s) * 8;
      async16(wh + abase + k0 + cc * 8, &sA[pb][lb]);
      async16(xh + bbase + k0 + cc * 8, &sB[pb][lb]);
    }
  };
  stage(0, 0);
  int p = 0;
  for (int k0 = 0; k0 < 1024; k0 += 32) {
    __syncthreads();
    if (k0 + 32 < 1024) stage(k0 + 32, p ^ 1);
    f16x8 fa[4], fb[4];
#pragma unroll
    for (int mi = 0; mi < 4; ++mi)
      fa[mi] = *(const f16x8*)&sA[p][(quad * 128 + wm + mi * 16 + mrow) * 8];
#pragma unroll
    for (int ni = 0; ni < 4; ++ni)
      fb[ni] = *(const f16x8*)&sB[p][(quad * 128 + wn + ni * 16 + mrow) * 8];
#pragma unroll
    for (int mi = 0; mi < 4; ++mi)
#pragma unroll
      for (int ni = 0; ni < 4; ++ni)
        acc[mi][ni] = __builtin_amdgcn_mfma_f32_16x16x32_f16(fa[mi], fb[ni], acc[mi][ni], 0, 0, 0);
    p ^= 1;
  }
  const float inv = 1.0f / 4096.0f;
#pragma unroll
  for (int mi = 0; mi < 4; ++mi) {
#pragma unroll
    for (int rg = 0; rg < 4; ++rg) {
      int c = cb + wm + mi * 16 + quad * 4 + rg;
      float bv = bC[c];
#pragma unroll
      for (int ni = 0; ni < 4; ++ni) {
        int j = nb + wn + ni * 16 + mrow;
        vH[((size_t)b * 1024 + c) * NPIX + j] =
            (f16)(16.f * (acc[mi][ni][rg] * inv + bv));
      }
    }
  }
}

// ---------------- MFMA attention out-GEMM (single fp16) -> y ---------------

__global__ __launch_bounds__(256, 2) void rf_attm(
    const f16* __restrict__ vH,
    const float* __restrict__ Aarr, const float* __restrict__ Marr,
    const float* __restrict__ iZ, const float* __restrict__ in,
    const float* __restrict__ gptr, f16* __restrict__ yH) {
  __shared__ f16 sAh[4096], sPh[4096];
  const int tid = threadIdx.x;
  const int ib = blockIdx.x * 128, cb = blockIdx.y * 128, b = blockIdx.z;
  const int pA = tid & 127;
  const int wv = tid >> 6, lane = tid & 63;
  const int mrow = lane & 15, quad = lane >> 4;
  const int wm = (wv & 1) * 64, wn = (wv >> 1) * 64;
  const size_t vbase = ((size_t)b * 1024 + cb + pA) * NPIX;
  const int ni_ = tid & 127;
  const int kc0 = tid >> 7;  // 0..1
  const float av = Aarr[b * NPIX + ib + ni_];
  const float mv = Marr[b * NPIX + ib + ni_];
  const float zv = iZ[b * NPIX + ib + ni_] * 16.f;
  const float* f = in + ((size_t)b * 1025 + 1024) * NPIX;
  f32x4 acc[4][4];
#pragma unroll
  for (int i = 0; i < 4; ++i)
#pragma unroll
    for (int j = 0; j < 4; ++j) acc[i][j] = (f32x4){0.f, 0.f, 0.f, 0.f};
  for (int j0 = 0; j0 < NPIX; j0 += 32) {
#pragma unroll
    for (int s = 0; s < 2; ++s) {
      const int cc = ((tid + 256 * s) >> 7) & 3;
      const int lb = ((tid & ~63) + 256 * s) * 8;
      async16(vH + vbase + j0 + cc * 8, &sAh[lb]);
    }
#pragma unroll
    for (int it = 0; it < 2; ++it) {
      const int kc = kc0 + 2 * it;
      const float4 fa = *(const float4*)&f[j0 + kc * 8];
      const float4 fb = *(const float4*)&f[j0 + kc * 8 + 4];
      const float fj[8] = {fa.x, fa.y, fa.z, fa.w, fb.x, fb.y, fb.z, fb.w};
      f16x8 ph;
#pragma unroll
      for (int q = 0; q < 8; ++q)
        ph[q] = (f16)(__expf(fmaf(av, fj[q], -mv)) * zv);
      *(f16x8*)&sPh[(kc * 128 + ni_) * 8] = ph;
    }
    __syncthreads();
    f16x8 fa[4], fb[4];
#pragma unroll
    for (int mi = 0; mi < 4; ++mi)
      fa[mi] = *(const f16x8*)&sAh[(quad * 128 + wm + mi * 16 + mrow) * 8];
#pragma unroll
    for (int ni = 0; ni < 4; ++ni)
      fb[ni] = *(const f16x8*)&sPh[(quad * 128 + wn + ni * 16 + mrow) * 8];
#pragma unroll
    for (int mi = 0; mi < 4; ++mi)
#pragma unroll
      for (int ni = 0; ni < 4; ++ni)
        acc[mi][ni] = __builtin_amdgcn_mfma_f32_16x16x32_f16(fa[mi], fb[ni], acc[mi][ni], 0, 0, 0);
    __syncthreads();
  }
  const float g = gptr[0];
  const float inv = 1.0f / 256.0f;
#pragma unroll
  for (int mi = 0; mi < 4; ++mi) {
    const int cbase = cb + wm + mi * 16 + quad * 4;
#pragma unroll
    for (int ni = 0; ni < 4; ++ni) {
      const int i = ib + wn + ni * 16 + mrow;
      f16x4 hv;
#pragma unroll
      for (int rg = 0; rg < 4; ++rg) {
        float xr = in[((size_t)b * 1025 + cbase + rg) * NPIX + i];
        hv[rg] = (f16)(16.f * (g * (acc[mi][ni][rg] * inv) + xr));
      }
      *(f16x4*)&yH[((size_t)b * NPIX + i) * 1024 + cbase] = hv;
    }
  }
}

// ---------------- conv weight prep: [CO][CI][3][3] -> MFMA-fragment order --
// F[((t*KI + k)*C16 + c16)*64 + lane][8]:  co = c16*16 + (lane&15),
// ci = k*32 + (lane>>4)*8 + j.  One coalesced 1KB wave-load per fb fragment.

__global__ void rf_wfragc(const float* __restrict__ w, f16* __restrict__ F,
                          int CI, int CO) {
  int gid = blockIdx.x * 256 + threadIdx.x;
  const int C16 = CO >> 4, KI = CI >> 5;
  const int total = 9 * KI * C16 * 64;
  if (gid >= total) return;
  int lane = gid & 63;
  int rest = gid >> 6;
  int c16 = rest % C16;
  int rest2 = rest / C16;
  int k = rest2 % KI;
  int t = rest2 / KI;
  int co = c16 * 16 + (lane & 15);
  int ci = k * 32 + (lane >> 4) * 8;
  f16x8 hb;
#pragma unroll
  for (int j = 0; j < 8; ++j)
    hb[j] = (f16)(256.0f * w[((size_t)co * CI + ci + j) * 9 + t]);
  *(f16x8*)&F[(size_t)gid * 8] = hb;
}

// ---------------- MFMA dilated 3x3 conv (halo dbuf A, register B) ----------
// A: 32-ci halo tile [HROWS][ks4][col72][8] double-buffered (col pad 72 ->
// quad stride 1152B = 0 mod 128, conflict-free).  B: register fragments from
// fragment-ordered F (coalesced, L2-hot, compiler-pipelined).  ONE barrier/k.

template <int BM, int BN, bool F32OUT>
__global__ __launch_bounds__(256, 2) void rf_mconv(
    const f16* __restrict__ xh, const f16* __restrict__ F,
    const float* __restrict__ bias, const float* __restrict__ zp,
    f16* __restrict__ oh, float* __restrict__ of, int CI, int CO) {
  constexpr int ROWS = BM / 64;
  constexpr int TPI = 4096 / BM;
  constexpr int HROWS = ROWS + 4;               // +-2 row halo
  constexpr int COLP = 72;                      // 68 used + pad to 72
  constexpr int CHUNKS = HROWS * 4 * COLP;      // 16B chunks in halo tile
  constexpr int NSTG = (CHUNKS + 255) / 256;    // A stage instrs per thread
  __shared__ f16 sA[2][NSTG * 2048];
  const int tid = threadIdx.x;
  const int blkpx = blockIdx.x;
  const int cob = blockIdx.y * BN;
  const int b = blkpx / TPI;
  const int h0 = (blkpx - b * TPI) * ROWS;

  const int wv = tid >> 6, lane = tid & 63;
  const int mrow = lane & 15, quad = lane >> 4;
  const int wm = (BN == 128) ? (wv & 1) * 64 : wv * 64;
  const int wn = (BN == 128) ? (wv >> 1) * 64 : 0;
  const int r_out = wm >> 6;
  const int KI = CI >> 5;
  const int C16 = CO >> 4;
  const int cb16 = (cob + wn) >> 4;

  f32x4 acc[4][4];
#pragma unroll
  for (int i = 0; i < 4; ++i)
#pragma unroll
    for (int j = 0; j < 4; ++j) acc[i][j] = (f32x4){0.f, 0.f, 0.f, 0.f};

  // per-lane A staging sources (affine in k: +k*32 f16 when valid)
  const f16* abase[NSTG];
  unsigned vmask = 0;
#pragma unroll
  for (int s = 0; s < NSTG; ++s) {
    int idx = tid + 256 * s;
    int rowks = idx / COLP;
    int col = idx - rowks * COLP;
    int r = rowks >> 2, ks = rowks & 3;
    int srow = h0 + r - 2, scol = col - 2;
    bool ok = (idx < CHUNKS) && ((unsigned)srow < 64u) && ((unsigned)scol < 64u);
    abase[s] = ok ? xh + (((size_t)b * 64 + srow) * 64 + scol) * CI + ks * 8
                  : (const f16*)zp;
    if (ok) vmask |= (1u << s);
  }
  auto stageA = [&](int k, int pb) {
#pragma unroll
    for (int s = 0; s < NSTG; ++s) {
      const f16* sp = abase[s] + (((vmask >> s) & 1u) ? k * 32 : 0);
      async16(sp, &sA[pb][((tid & ~63) + 256 * s) * 8]);
    }
  };

  // per-lane B fragment base (fragment-ordered F)
  const f16* Fb = F + ((size_t)cb16 * 64 + lane) * 8;

  stageA(0, 0);
  int p = 0;
  for (int k = 0; k < KI; ++k) {
    __syncthreads();                    // A(k) writes drained & visible
    if (k + 1 < KI) stageA(k + 1, p ^ 1);
#pragma unroll
    for (int t = 0; t < 9; ++t) {
      const int dh = (t / 3) * 2 - 2, dw = (t - (t / 3) * 3) * 2 - 2;
      f16x8 fb[4];
#pragma unroll
      for (int ni = 0; ni < 4; ++ni)
        fb[ni] = *(const f16x8*)(Fb + ((size_t)(t * KI + k) * C16 + ni) * 512);
      f16x8 fa[4];
#pragma unroll
      for (int mi = 0; mi < 4; ++mi)
        fa[mi] = *(const f16x8*)&sA[p][(((r_out + dh + 2) * 4 + quad) * COLP +
                                       mi * 16 + mrow + dw + 2) * 8];
#pragma unroll
      for (int mi = 0; mi < 4; ++mi)
#pragma unroll
        for (int ni = 0; ni < 4; ++ni)
          acc[mi][ni] = __builtin_amdgcn_mfma_f32_16x16x32_f16(fa[mi], fb[ni], acc[mi][ni], 0, 0, 0);
    }
    p ^= 1;
  }

  const float inv = 1.0f / 4096.0f;
  float bvs[4];
#pragma unroll
  for (int ni = 0; ni < 4; ++ni) bvs[ni] = bias[cob + wn + ni * 16 + mrow];
#pragma unroll
  for (int mi = 0; mi < 4; ++mi) {
#pragma unroll
    for (int rg = 0; rg < 4; ++rg) {
      int px = wm + mi * 16 + quad * 4 + rg;
      int hh = h0 + (px >> 6), wwp = px & 63;
#pragma unroll
      for (int ni = 0; ni < 4; ++ni) {
        int co = cob + wn + ni * 16 + mrow;
        float vv = fmaxf(acc[mi][ni][rg] * inv + bvs[ni], 0.f);
        if (F32OUT) {
          of[(((size_t)b * CO + co) * 64 + hh) * 64 + wwp] = vv;
        } else {
          oh[(((size_t)b * 64 + hh) * 64 + wwp) * CO + co] = (f16)(vv * 16.f);
        }
      }
    }
  }
}

// ---------------- scan weight frag prep: w[64][64][9] -> frag order ---------

__global__ void rf_wfrag(const float* __restrict__ w, f16* __restrict__ fh) {
  int gid = blockIdx.x * 256 + threadIdx.x;
  if (gid >= 4608) return;
  int lane = gid & 63;
  int rem = gid >> 6;
  int kc = rem & 1;
  int rem2 = rem >> 1;
  int t = rem2 % 9;
  int w4 = rem2 / 9;
  int co = w4 * 16 + (lane & 15);
  int cib = kc * 32 + (lane >> 4) * 8;
  f16x8 hb;
#pragma unroll
  for (int j = 0; j < 8; ++j)
    hb[j] = (f16)(256.f * w[((size_t)co * 64 + cib + j) * 9 + t]);
  *(f16x8*)&fh[(size_t)gid * 8] = hb;
}

// ---------------- MFMA recurrent scan (single fp16 carry) ------------------

__global__ __launch_bounds__(256, 1) void rf_mscan(
    const float* __restrict__ src, float* __restrict__ dst,
    const f16* __restrict__ fh, const float* __restrict__ bias, int dir) {
  __shared__ f16 ch[72 * 64];
  const int b = blockIdx.x;
  const int tid = threadIdx.x;
  const int wave = tid >> 6, lane = tid & 63;
  const int quad = lane >> 4, l15 = lane & 15;

  f16x8 Ah[9][2];
#pragma unroll
  for (int t = 0; t < 9; ++t)
#pragma unroll
    for (int kc = 0; kc < 2; ++kc)
      Ah[t][kc] = *(const f16x8*)&fh[(((wave * 9 + t) * 2 + kc) * 64 + lane) * 8];
  float bvs[4];
#pragma unroll
  for (int r = 0; r < 4; ++r) bvs[r] = bias[wave * 16 + quad * 4 + r];

  for (int s = tid; s < 2304; s += 256) ((unsigned*)ch)[s] = 0u;
  __syncthreads();

  const size_t sbase = (size_t)b * 64 * 4096;
  const int row0 = (dir > 0) ? 0 : 63;
  {
    int pos0 = tid & 63, cig = tid >> 6;
#pragma unroll
    for (int q = 0; q < 16; ++q) {
      int ci = cig * 16 + q;
      float v = src[sbase + (size_t)ci * 4096 + row0 * 64 + pos0];
      dst[sbase + (size_t)ci * 4096 + row0 * 64 + pos0] = v;
      int rowIdx = pos0 + 4;
      ch[rowIdx * 64 + (((ci >> 3) ^ (rowIdx & 7)) << 3) + (ci & 7)] = (f16)v;
    }
  }
  __syncthreads();

  const float inv = 1.0f / 256.0f;
  for (int s = 1; s < 64; ++s) {
    const int row = (dir > 0) ? s : 63 - s;
    float srow[4][4];
#pragma unroll
    for (int nt = 0; nt < 4; ++nt)
#pragma unroll
      for (int r = 0; r < 4; ++r)
        srow[nt][r] = src[sbase + (size_t)(wave * 16 + quad * 4 + r) * 4096 +
                          row * 64 + nt * 16 + l15];
    f32x4 acc[4];
#pragma unroll
    for (int nt = 0; nt < 4; ++nt) acc[nt] = (f32x4){0.f, 0.f, 0.f, 0.f};
#pragma unroll
    for (int t = 0; t < 9; ++t)
#pragma unroll
      for (int kc = 0; kc < 2; ++kc) {
#pragma unroll
        for (int nt = 0; nt < 4; ++nt) {
          int rowIdx = nt * 16 + l15 + t;
          int gr = kc * 4 + quad;
          f16x8 Bh = *(const f16x8*)&ch[rowIdx * 64 + ((gr ^ (rowIdx & 7)) << 3)];
          acc[nt] = __builtin_amdgcn_mfma_f32_16x16x32_f16(Ah[t][kc], Bh, acc[nt], 0, 0, 0);
        }
      }
    __syncthreads();
#pragma unroll
    for (int nt = 0; nt < 4; ++nt) {
      int pos = nt * 16 + l15;
      int rowIdx = pos + 4;
      f16x4 hv;
#pragma unroll
      for (int r = 0; r < 4; ++r) {
        float v = fmaxf(acc[nt][r] * inv + bvs[r], 0.f) + srow[nt][r];
        dst[sbase + (size_t)(wave * 16 + quad * 4 + r) * 4096 + row * 64 + pos] = v;
        hv[r] = (f16)v;
      }
      int ci0 = wave * 16 + quad * 4;
      *(f16x4*)&ch[rowIdx * 64 + (((ci0 >> 3) ^ (rowIdx & 7)) << 3) + (ci0 & 7)] = hv;
    }
    __syncthreads();
  }
}

// ---------------- transpose last two dims (64x64) per (b,c) ----------------

__global__ void rf_transpose(const float* __restrict__ src, float* __restrict__ dst) {
  int bc = blockIdx.x;  // 256
  __shared__ float tl[64][65];
  int tid = threadIdx.x;
  const float* sp = src + (size_t)bc * 4096;
  float* dp = dst + (size_t)bc * 4096;
  for (int s = tid; s < 4096; s += 256) {
    int h = s >> 6, w = s & 63;
    tl[w][h] = sp[s];
  }
  __syncthreads();
  for (int s = tid; s < 4096; s += 256) dp[s] = tl[s >> 6][s & 63];
}

// ---------------- final 1x1 conv + relu + 8x8 upsample ----------------

__global__ void rf_final(const float* __restrict__ t, const float* __restrict__ ow,
                         const float* __restrict__ ob, float* __restrict__ out) {
  int b = blockIdx.y;
  int s = blockIdx.x * 256 + threadIdx.x;  // 0..4095
  int w = s >> 6, h = s & 63;
  float acc = ob[0];
  for (int c = 0; c < 64; ++c)
    acc += ow[c] * t[(((size_t)b * 64 + c) * 64 + w) * 64 + h];
  acc = fmaxf(acc, 0.f);
  float4 vv = make_float4(acc, acc, acc, acc);
  for (int dy = 0; dy < 8; ++dy) {
    float* dp = out + ((size_t)b * 512 + h * 8 + dy) * 512 + w * 8;
    *(float4*)dp = vv;
    *(float4*)(dp + 4) = vv;
  }
}

// ---------------- launch ----------------

extern "C" void kernel_launch(void* const* d_in, const int* in_sizes, int n_in,
                              void* d_out, int out_size, void* d_ws, size_t ws_size,
                              hipStream_t stream) {
  const float* in    = (const float*)d_in[0];
  const float* wA    = (const float*)d_in[1];
  const float* bA    = (const float*)d_in[2];
  const float* wB    = (const float*)d_in[3];
  const float* wC    = (const float*)d_in[5];
  const float* bC    = (const float*)d_in[6];
  const float* gamma = (const float*)d_in[7];
  const float* bw1 = (const float*)d_in[8];  const float* bb1 = (const float*)d_in[9];
  const float* bw2 = (const float*)d_in[10]; const float* bb2 = (const float*)d_in[11];
  const float* bw3 = (const float*)d_in[12]; const float* bb3 = (const float*)d_in[13];
  const float* bw4 = (const float*)d_in[14]; const float* bb4 = (const float*)d_in[15];
  const float* bw5 = (const float*)d_in[16]; const float* bb5 = (const float*)d_in[17];
  const float* bw6 = (const float*)d_in[18]; const float* bb6 = (const float*)d_in[19];
  const float* du_w = (const float*)d_in[20]; const float* du_b = (const float*)d_in[21];
  const float* lr_w = (const float*)d_in[22]; const float* lr_b = (const float*)d_in[23];
  const float* ow   = (const float*)d_in[24]; const float* ob   = (const float*)d_in[25];
  float* out = (float*)d_out;
  float* ws = (float*)d_ws;

  // phase-1 (attention) buffers; offsets in f32 slots (f16 elems = 2x)
  f16* vH  = (f16*)(ws + 0);          // 16.8M f16 -> [0, 4194304)
  f16* xTh = (f16*)(ws + 4194304);    // [4194304, 8388608)
  f16* wCh = (f16*)(ws + 8388608);    // [8388608, 8912896)
  f16* yH  = (f16*)(ws + 16777216);   // [16777216, 20971520)
  // conv phase (F buffers = same sizes as old wsingle buffers)
  f16* w1h = (f16*)(ws + 0);          // [0, 2359296)
  f16* c1H = (f16*)(ws + 2359296);    // [2359296, 6553600)
  f16* w3h = (f16*)(ws + 6553600);    // [6553600, 7733248)
  f16* w2h = (f16*)(ws + 16777216);   // [16777216, 17956864)  (yH dead)
  f16* c2H = (f16*)(ws + 17956864);   // [17956864, 22151168)
  f16* w4h = (f16*)(ws + 22151168);   // [22151168, 22740992)
  f16* c4H = (f16*)(ws + 22740992);   // [22740992, 24838144)
  f16* c3H = c1H;
  f16* w5h = (f16*)(ws + 0);          // [0, 147456)       (w1 dead)
  f16* c5H = (f16*)(ws + 147456);     // [147456, 1196032)
  f16* w6h = (f16*)(ws + 1196032);    // [1196032, 1232896)
  float* tin = ws + 1232896;          // [1232896, 2281472)
  float* t0  = ws + 2281472;          // [2281472, 3330048)
  float* t1  = ws + 3330048;          // [3330048, 4378624)
  f16* duFh = (f16*)(ws + 4378624);   // [4378624, 4397056)  (c1/c3 dead)
  f16* lrFh = (f16*)(ws + 4397056);   // [4397056, 4415488)
  float* sm = ws + 33554432;
  float* A_  = sm;
  float* M_  = sm + 16384;
  float* iZ  = sm + 32768;
  float* u_  = sm + 49152;
  float* s_  = sm + 50176;
  float* c0_ = sm + 50304;
  float* fst = sm + 50308;
  float* zp  = sm + 50432;  // 64-float zero page for OOB DMA lanes

  rf_zero<<<1, 64, 0, stream>>>(zp);
  rf_s<<<1, 128, 0, stream>>>(wB, bA, s_, c0_);
  rf_u<<<4, 256, 0, stream>>>(wA, s_, u_);
  rf_fstat<<<4, 256, 0, stream>>>(in, fst);
  rf_A<<<dim3(16, 4), 256, 0, stream>>>(in, u_, c0_, fst, A_, M_);
  rf_Z<<<4096, 256, 0, stream>>>(in, A_, M_, iZ);
  rf_xsplit<<<dim3(64, 16, 4), 256, 0, stream>>>(in, xTh);
  rf_wC1<<<512, 256, 0, stream>>>(wC, wCh);
  rf_vgemmm<<<dim3(32, 8, 4), 256, 0, stream>>>(wCh, xTh, bC, vH);
  rf_attm<<<dim3(32, 8, 4), 256, 0, stream>>>(vH, A_, M_, iZ, in, gamma, yH);

  // fragment-ordered conv weights (sizes identical to old wsingle buffers)
  rf_wfragc<<<2304, 256, 0, stream>>>(bw1, w1h, 1024, 512);
  rf_wfragc<<<1152, 256, 0, stream>>>(bw3, w3h, 512, 512);
  rf_mconv<128, 128, false><<<dim3(128, 4), 256, 0, stream>>>(
      yH, w1h, bb1, zp, c1H, nullptr, 1024, 512);
  rf_wfragc<<<1152, 256, 0, stream>>>(bw2, w2h, 512, 512);
  rf_wfragc<<<576, 256, 0, stream>>>(bw4, w4h, 512, 256);
  rf_wfragc<<<144, 256, 0, stream>>>(bw5, w5h, 256, 128);
  rf_wfragc<<<36, 256, 0, stream>>>(bw6, w6h, 128, 64);
  rf_mconv<128, 128, false><<<dim3(128, 4), 256, 0, stream>>>(
      c1H, w2h, bb2, zp, c2H, nullptr, 512, 512);
  rf_mconv<128, 128, false><<<dim3(128, 4), 256, 0, stream>>>(
      c2H, w3h, bb3, zp, c3H, nullptr, 512, 512);
  rf_mconv<128, 128, false><<<dim3(128, 2), 256, 0, stream>>>(
      c3H, w4h, bb4, zp, c4H, nullptr, 512, 256);
  rf_wfrag<<<18, 256, 0, stream>>>(du_w, duFh);
  rf_wfrag<<<18, 256, 0, stream>>>(lr_w, lrFh);
  rf_mconv<128, 128, false><<<dim3(128, 1), 256, 0, stream>>>(
      c4H, w5h, bb5, zp, c5H, nullptr, 256, 128);
  rf_mconv<256, 64, true><<<dim3(64, 1), 256, 0, stream>>>(
      c5H, w6h, bb6, zp, nullptr, tin, 128, 64);

  rf_mscan<<<4, 256, 0, stream>>>(tin, t0, duFh, du_b, +1);
  rf_mscan<<<4, 256, 0, stream>>>(t0, t1, duFh, du_b, -1);
  rf_transpose<<<256, 256, 0, stream>>>(t1, t0);
  rf_mscan<<<4, 256, 0, stream>>>(t0, t1, lrFh, lr_b, +1);
  rf_mscan<<<4, 256, 0, stream>>>(t1, t0, lrFh, lr_b, -1);
  rf_final<<<dim3(16, 4), 256, 0, stream>>>(t0, ow, ob, out);
}

// Round 4
// 1702.343 us; speedup vs baseline: 1.1758x; 1.0075x over previous
//
#include <hip/hip_runtime.h>

// resFAN round 10 (R3 this session): attm restructure.
// R2 counters: rf_attm top kernel (242us): MfmaUtil 25%, VALUBusy 46% -> the
// P(i,j)=exp tile is recomputed by all 8 cb-blocks and double-barriered per
// 32-j step.  New rf_attm: 128i x 256c blocks (grid y 8->4, halves P work),
// dbuf sAh/sPh with ONE barrier per step (frag reads ordered before sPh
// writes), exp2f instead of expf, iZ normalization hoisted to epilogue
// (raw P<=1 in f16: relative error unchanged, dynamics better).
// Convs (R2): halo dbuf A + register B frags, one barrier per 32-ci chunk.
//
// Error budget unchanged: fp16 quant 2^-11, scales 16/256.

#define NPIX 4096

typedef _Float16 f16;
typedef _Float16 f16x8 __attribute__((ext_vector_type(8)));
typedef _Float16 f16x4 __attribute__((ext_vector_type(4)));
typedef float f32x4 __attribute__((ext_vector_type(4)));

__device__ inline void async16(const void* g, void* l) {
  __builtin_amdgcn_global_load_lds(
      (const __attribute__((address_space(1))) unsigned int*)g,
      (__attribute__((address_space(3))) unsigned int*)l, 16, 0, 0);
}

// ---------------- small prep kernels ----------------

__global__ void rf_zero(float* __restrict__ z) { z[threadIdx.x] = 0.f; }

__global__ void rf_s(const float* __restrict__ wB, const float* __restrict__ bA,
                     float* __restrict__ s_out, float* __restrict__ c0_out) {
  int c = threadIdx.x;  // 128 threads
  const float* row = wB + (size_t)c * 1024;
  float acc = 0.f;
  for (int i = 0; i < 1024; ++i) acc += row[i];
  s_out[c] = acc;
  __shared__ float sh[128];
  sh[c] = acc * bA[c];
  __syncthreads();
  for (int off = 64; off > 0; off >>= 1) {
    if (c < off) sh[c] += sh[c + off];
    __syncthreads();
  }
  if (c == 0) c0_out[0] = sh[0];
}

__global__ void rf_u(const float* __restrict__ wA, const float* __restrict__ s,
                     float* __restrict__ u) {
  int i = blockIdx.x * 256 + threadIdx.x;  // 1024 total
  float acc = 0.f;
  for (int c = 0; c < 128; ++c) acc += s[c] * wA[(size_t)c * 1024 + i];
  u[i] = acc;
}

__global__ void rf_fstat(const float* __restrict__ in, float* __restrict__ fstat) {
  int b = blockIdx.x;
  int t = threadIdx.x;
  const float* f = in + ((size_t)b * 1025 + 1024) * NPIX;
  float mx = -1e30f, mn = 1e30f;
  for (int j = t; j < NPIX; j += 256) {
    float v = f[j];
    mx = fmaxf(mx, v);
    mn = fminf(mn, v);
  }
  __shared__ float smx[256], smn[256];
  smx[t] = mx; smn[t] = mn;
  __syncthreads();
  for (int off = 128; off > 0; off >>= 1) {
    if (t < off) {
      smx[t] = fmaxf(smx[t], smx[t + off]);
      smn[t] = fminf(smn[t], smn[t + off]);
    }
    __syncthreads();
  }
  if (t == 0) { fstat[b] = smx[0]; fstat[4 + b] = smn[0]; }
}

__global__ __launch_bounds__(256) void rf_A(const float* __restrict__ in,
                                            const float* __restrict__ u,
                                            const float* __restrict__ c0p,
                                            const float* __restrict__ fst,
                                            float* __restrict__ A, float* __restrict__ M) {
  __shared__ float ul[1024];
  int b = blockIdx.y;
  int n = blockIdx.x * 256 + threadIdx.x;
  for (int s = threadIdx.x; s < 1024; s += 256) ul[s] = u[s];
  __syncthreads();
  const float* xp = in + (size_t)b * 1025 * NPIX + n;
  float acc = c0p[0];
#pragma unroll 8
  for (int i = 0; i < 1024; ++i) acc = fmaf(ul[i], xp[(size_t)i * NPIX], acc);
  A[b * NPIX + n] = acc;
  M[b * NPIX + n] = fmaxf(acc * fst[b], acc * fst[4 + b]);
}

__global__ void rf_Z(const float* __restrict__ in, const float* __restrict__ A,
                     const float* __restrict__ M, float* __restrict__ iZ) {
  int idx = blockIdx.x * 4 + (threadIdx.x >> 6);  // (b,n) pair, 16384 total
  int lane = threadIdx.x & 63;
  int b = idx >> 12;
  const float* f = in + ((size_t)b * 1025 + 1024) * NPIX;
  float a = A[idx], m = M[idx];
  float acc = 0.f;
#pragma unroll 4
  for (int it = 0; it < 64; ++it) acc += __expf(a * f[lane + it * 64] - m);
  for (int off = 32; off > 0; off >>= 1) acc += __shfl_down(acc, off, 64);
  if (lane == 0) iZ[idx] = 1.0f / acc;
}

// ---------------- x transpose: [b][ci][n] f32 -> [b][n][ci] f16, scale 16 ---

__global__ void rf_xsplit(const float* __restrict__ in, f16* __restrict__ xh) {
  __shared__ float tl[64][65];
  int nt = blockIdx.x, ct = blockIdx.y, b = blockIdx.z;
  int n0 = nt * 64, c0 = ct * 64;
  int tid = threadIdx.x;
  for (int s = tid; s < 4096; s += 256) {
    int r = s >> 6, c = s & 63;
    tl[r][c] = in[((size_t)b * 1025 + c0 + r) * NPIX + n0 + c];
  }
  __syncthreads();
  for (int s = tid; s < 512; s += 256) {
    int n = s >> 3, g = s & 7;
    f16x8 hb;
#pragma unroll
    for (int q = 0; q < 8; ++q) hb[q] = (f16)(16.f * tl[g * 8 + q][n]);
    size_t o = ((size_t)b * NPIX + n0 + n) * 1024 + c0 + g * 8;
    *(f16x8*)&xh[o] = hb;
  }
}

// ---------------- wC cast: [1024][1024] f32 -> f16, scale 256 --------------

__global__ void rf_wC1(const float* __restrict__ wC, f16* __restrict__ wh) {
  int base = (blockIdx.x * 256 + threadIdx.x) * 8;
  f16x8 hb;
#pragma unroll
  for (int q = 0; q < 8; ++q) hb[q] = (f16)(256.f * wC[base + q]);
  *(f16x8*)&wh[base] = hb;
}

// ---------------- MFMA v-GEMM (dbuf, single fp16): v = wC @ x + bC --------

__global__ __launch_bounds__(256, 2) void rf_vgemmm(
    const f16* __restrict__ wh, const f16* __restrict__ xh,
    const float* __restrict__ bC, f16* __restrict__ vH) {
  __shared__ f16 sA[2][4096], sB[2][4096];
  const int tid = threadIdx.x;
  const int nb = blockIdx.x * 128, cb = blockIdx.y * 128, b = blockIdx.z;
  const int pA = tid & 127;
  const int wv = tid >> 6, lane = tid & 63;
  const int mrow = lane & 15, quad = lane >> 4;
  const int wm = (wv & 1) * 64, wn = (wv >> 1) * 64;
  const size_t abase = (size_t)(cb + pA) * 1024;
  const size_t bbase = ((size_t)b * NPIX + nb + pA) * 1024;
  f32x4 acc[4][4];
#pragma unroll
  for (int i = 0; i < 4; ++i)
#pragma unroll
    for (int j = 0; j < 4; ++j) acc[i][j] = (f32x4){0.f, 0.f, 0.f, 0.f};

  auto stage = [&](int k0, int pb) {
#pragma unroll
    for (int s = 0; s < 2; ++s) {
      const int cc = ((tid + 256 * s) >> 7) & 3;
      const int lb = ((tid & ~63) + 256 * s) * 8;
      async16(wh + abase + k0 + cc * 8, &sA[pb][lb]);
      async16(xh + bbase + k0 + cc * 8, &sB[pb][lb]);
    }
  };
  stage(0, 0);
  int p = 0;
  for (int k0 = 0; k0 < 1024; k0 += 32) {
    __syncthreads();
    if (k0 + 32 < 1024) stage(k0 + 32, p ^ 1);
    f16x8 fa[4], fb[4];
#pragma unroll
    for (int mi = 0; mi < 4; ++mi)
      fa[mi] = *(const f16x8*)&sA[p][(quad * 128 + wm + mi * 16 + mrow) * 8];
#pragma unroll
    for (int ni = 0; ni < 4; ++ni)
      fb[ni] = *(const f16x8*)&sB[p][(quad * 128 + wn + ni * 16 + mrow) * 8];
#pragma unroll
    for (int mi = 0; mi < 4; ++mi)
#pragma unroll
      for (int ni = 0; ni < 4; ++ni)
        acc[mi][ni] = __builtin_amdgcn_mfma_f32_16x16x32_f16(fa[mi], fb[ni], acc[mi][ni], 0, 0, 0);
    p ^= 1;
  }
  const float inv = 1.0f / 4096.0f;
#pragma unroll
  for (int mi = 0; mi < 4; ++mi) {
#pragma unroll
    for (int rg = 0; rg < 4; ++rg) {
      int c = cb + wm + mi * 16 + quad * 4 + rg;
      float bv = bC[c];
#pragma unroll
      for (int ni = 0; ni < 4; ++ni) {
        int j = nb + wn + ni * 16 + mrow;
        vH[((size_t)b * 1024 + c) * NPIX + j] =
            (f16)(16.f * (acc[mi][ni][rg] * inv + bv));
      }
    }
  }
}

// ---------------- MFMA attention out-GEMM (256c blocks, 1-barrier dbuf) ----

__global__ __launch_bounds__(256, 2) void rf_attm(
    const f16* __restrict__ vH,
    const float* __restrict__ Aarr, const float* __restrict__ Marr,
    const float* __restrict__ iZ, const float* __restrict__ in,
    const float* __restrict__ gptr, f16* __restrict__ yH) {
  __shared__ f16 sAh[2][8192];   // [jgrp4][c256][8]
  __shared__ f16 sPh[2][4096];   // [joct4][i128][8]
  const int tid = threadIdx.x;
  const int ib = blockIdx.x * 128, cb = blockIdx.y * 256, b = blockIdx.z;
  const int wv = tid >> 6, lane = tid & 63;
  const int mrow = lane & 15, quad = lane >> 4;
  const int wm = wv * 64;                 // wave's 64-c slice of 256
  const int ni_ = tid & 127;
  const int kc0 = tid >> 7;               // 0..1
  const float av2 = Aarr[b * NPIX + ib + ni_] * 1.44269504f;
  const float mv2 = Marr[b * NPIX + ib + ni_] * 1.44269504f;
  const float* f = in + ((size_t)b * 1025 + 1024) * NPIX;
  const f16* vrow = vH + ((size_t)b * 1024 + cb + tid) * NPIX;

  f32x4 acc[4][8];
#pragma unroll
  for (int i = 0; i < 4; ++i)
#pragma unroll
    for (int j = 0; j < 8; ++j) acc[i][j] = (f32x4){0.f, 0.f, 0.f, 0.f};

  auto stage = [&](int j0, int pb) {
#pragma unroll
    for (int s = 0; s < 4; ++s)
      async16(vrow + j0 + s * 8, &sAh[pb][(s * 256 + tid) * 8]);
  };
  auto doP = [&](int j0, int pb) {
#pragma unroll
    for (int it = 0; it < 2; ++it) {
      const int kc = kc0 + 2 * it;
      const float4 fa4 = *(const float4*)&f[j0 + kc * 8];
      const float4 fb4 = *(const float4*)&f[j0 + kc * 8 + 4];
      const float fj[8] = {fa4.x, fa4.y, fa4.z, fa4.w, fb4.x, fb4.y, fb4.z, fb4.w};
      f16x8 ph;
#pragma unroll
      for (int q = 0; q < 8; ++q)
        ph[q] = (f16)exp2f(fmaf(av2, fj[q], -mv2));
      *(f16x8*)&sPh[pb][(kc * 128 + ni_) * 8] = ph;
    }
  };

  stage(0, 0);
  doP(0, 0);
  int p = 0;
  for (int k = 0; k < 128; ++k) {
    __syncthreads();               // buf p tile + P complete & visible
    f16x8 fa[4], fb[8];
#pragma unroll
    for (int mi = 0; mi < 4; ++mi)
      fa[mi] = *(const f16x8*)&sAh[p][(quad * 256 + wm + mi * 16 + mrow) * 8];
#pragma unroll
    for (int ni = 0; ni < 8; ++ni)
      fb[ni] = *(const f16x8*)&sPh[p][(quad * 128 + ni * 16 + mrow) * 8];
    if (k < 127) {
      stage((k + 1) * 32, p ^ 1);  // async DMA, drained at next barrier
      doP((k + 1) * 32, p ^ 1);    // VALU overlaps MFMA issue
    }
#pragma unroll
    for (int mi = 0; mi < 4; ++mi)
#pragma unroll
      for (int ni = 0; ni < 8; ++ni)
        acc[mi][ni] = __builtin_amdgcn_mfma_f32_16x16x32_f16(fa[mi], fb[ni], acc[mi][ni], 0, 0, 0);
    p ^= 1;
  }

  const float g = gptr[0];
  const float inv16 = 1.0f / 16.0f;
  float zvi[8];
#pragma unroll
  for (int ni = 0; ni < 8; ++ni)
    zvi[ni] = iZ[b * NPIX + ib + ni * 16 + mrow] * inv16;
#pragma unroll
  for (int mi = 0; mi < 4; ++mi) {
    const int cbase = cb + wm + mi * 16 + quad * 4;
#pragma unroll
    for (int ni = 0; ni < 8; ++ni) {
      const int i = ib + ni * 16 + mrow;
      f16x4 hv;
#pragma unroll
      for (int rg = 0; rg < 4; ++rg) {
        float xr = in[((size_t)b * 1025 + cbase + rg) * NPIX + i];
        hv[rg] = (f16)(16.f * (g * (acc[mi][ni][rg] * zvi[ni]) + xr));
      }
      *(f16x4*)&yH[((size_t)b * NPIX + i) * 1024 + cbase] = hv;
    }
  }
}

// ---------------- conv weight prep: [CO][CI][3][3] -> MFMA-fragment order --

__global__ void rf_wfragc(const float* __restrict__ w, f16* __restrict__ F,
                          int CI, int CO) {
  int gid = blockIdx.x * 256 + threadIdx.x;
  const int C16 = CO >> 4, KI = CI >> 5;
  const int total = 9 * KI * C16 * 64;
  if (gid >= total) return;
  int lane = gid & 63;
  int rest = gid >> 6;
  int c16 = rest % C16;
  int rest2 = rest / C16;
  int k = rest2 % KI;
  int t = rest2 / KI;
  int co = c16 * 16 + (lane & 15);
  int ci = k * 32 + (lane >> 4) * 8;
  f16x8 hb;
#pragma unroll
  for (int j = 0; j < 8; ++j)
    hb[j] = (f16)(256.0f * w[((size_t)co * CI + ci + j) * 9 + t]);
  *(f16x8*)&F[(size_t)gid * 8] = hb;
}

// ---------------- MFMA dilated 3x3 conv (halo dbuf A, register B) ----------

template <int BM, int BN, bool F32OUT>
__global__ __launch_bounds__(256, 2) void rf_mconv(
    const f16* __restrict__ xh, const f16* __restrict__ F,
    const float* __restrict__ bias, const float* __restrict__ zp,
    f16* __restrict__ oh, float* __restrict__ of, int CI, int CO) {
  constexpr int ROWS = BM / 64;
  constexpr int TPI = 4096 / BM;
  constexpr int HROWS = ROWS + 4;               // +-2 row halo
  constexpr int COLP = 72;                      // 68 used + pad to 72
  constexpr int CHUNKS = HROWS * 4 * COLP;      // 16B chunks in halo tile
  constexpr int NSTG = (CHUNKS + 255) / 256;    // A stage instrs per thread
  __shared__ f16 sA[2][NSTG * 2048];
  const int tid = threadIdx.x;
  const int blkpx = blockIdx.x;
  const int cob = blockIdx.y * BN;
  const int b = blkpx / TPI;
  const int h0 = (blkpx - b * TPI) * ROWS;

  const int wv = tid >> 6, lane = tid & 63;
  const int mrow = lane & 15, quad = lane >> 4;
  const int wm = (BN == 128) ? (wv & 1) * 64 : wv * 64;
  const int wn = (BN == 128) ? (wv >> 1) * 64 : 0;
  const int r_out = wm >> 6;
  const int KI = CI >> 5;
  const int C16 = CO >> 4;
  const int cb16 = (cob + wn) >> 4;

  f32x4 acc[4][4];
#pragma unroll
  for (int i = 0; i < 4; ++i)
#pragma unroll
    for (int j = 0; j < 4; ++j) acc[i][j] = (f32x4){0.f, 0.f, 0.f, 0.f};

  // per-lane A staging sources (affine in k: +k*32 f16 when valid)
  const f16* abase[NSTG];
  unsigned vmask = 0;
#pragma unroll
  for (int s = 0; s < NSTG; ++s) {
    int idx = tid + 256 * s;
    int rowks = idx / COLP;
    int col = idx - rowks * COLP;
    int r = rowks >> 2, ks = rowks & 3;
    int srow = h0 + r - 2, scol = col - 2;
    bool ok = (idx < CHUNKS) && ((unsigned)srow < 64u) && ((unsigned)scol < 64u);
    abase[s] = ok ? xh + (((size_t)b * 64 + srow) * 64 + scol) * CI + ks * 8
                  : (const f16*)zp;
    if (ok) vmask |= (1u << s);
  }
  auto stageA = [&](int k, int pb) {
#pragma unroll
    for (int s = 0; s < NSTG; ++s) {
      const f16* sp = abase[s] + (((vmask >> s) & 1u) ? k * 32 : 0);
      async16(sp, &sA[pb][((tid & ~63) + 256 * s) * 8]);
    }
  };

  // per-lane B fragment base (fragment-ordered F)
  const f16* Fb = F + ((size_t)cb16 * 64 + lane) * 8;

  stageA(0, 0);
  int p = 0;
  for (int k = 0; k < KI; ++k) {
    __syncthreads();                    // A(k) writes drained & visible
    if (k + 1 < KI) stageA(k + 1, p ^ 1);
#pragma unroll
    for (int t = 0; t < 9; ++t) {
      const int dh = (t / 3) * 2 - 2, dw = (t - (t / 3) * 3) * 2 - 2;
      f16x8 fb[4];
#pragma unroll
      for (int ni = 0; ni < 4; ++ni)
        fb[ni] = *(const f16x8*)(Fb + ((size_t)(t * KI + k) * C16 + ni) * 512);
      f16x8 fa[4];
#pragma unroll
      for (int mi = 0; mi < 4; ++mi)
        fa[mi] = *(const f16x8*)&sA[p][(((r_out + dh + 2) * 4 + quad) * COLP +
                                       mi * 16 + mrow + dw + 2) * 8];
#pragma unroll
      for (int mi = 0; mi < 4; ++mi)
#pragma unroll
        for (int ni = 0; ni < 4; ++ni)
          acc[mi][ni] = __builtin_amdgcn_mfma_f32_16x16x32_f16(fa[mi], fb[ni], acc[mi][ni], 0, 0, 0);
    }
    p ^= 1;
  }

  const float inv = 1.0f / 4096.0f;
  float bvs[4];
#pragma unroll
  for (int ni = 0; ni < 4; ++ni) bvs[ni] = bias[cob + wn + ni * 16 + mrow];
#pragma unroll
  for (int mi = 0; mi < 4; ++mi) {
#pragma unroll
    for (int rg = 0; rg < 4; ++rg) {
      int px = wm + mi * 16 + quad * 4 + rg;
      int hh = h0 + (px >> 6), wwp = px & 63;
#pragma unroll
      for (int ni = 0; ni < 4; ++ni) {
        int co = cob + wn + ni * 16 + mrow;
        float vv = fmaxf(acc[mi][ni][rg] * inv + bvs[ni], 0.f);
        if (F32OUT) {
          of[(((size_t)b * CO + co) * 64 + hh) * 64 + wwp] = vv;
        } else {
          oh[(((size_t)b * 64 + hh) * 64 + wwp) * CO + co] = (f16)(vv * 16.f);
        }
      }
    }
  }
}

// ---------------- scan weight frag prep: w[64][64][9] -> frag order ---------

__global__ void rf_wfrag(const float* __restrict__ w, f16* __restrict__ fh) {
  int gid = blockIdx.x * 256 + threadIdx.x;
  if (gid >= 4608) return;
  int lane = gid & 63;
  int rem = gid >> 6;
  int kc = rem & 1;
  int rem2 = rem >> 1;
  int t = rem2 % 9;
  int w4 = rem2 / 9;
  int co = w4 * 16 + (lane & 15);
  int cib = kc * 32 + (lane >> 4) * 8;
  f16x8 hb;
#pragma unroll
  for (int j = 0; j < 8; ++j)
    hb[j] = (f16)(256.f * w[((size_t)co * 64 + cib + j) * 9 + t]);
  *(f16x8*)&fh[(size_t)gid * 8] = hb;
}

// ---------------- MFMA recurrent scan (single fp16 carry) ------------------

__global__ __launch_bounds__(256, 1) void rf_mscan(
    const float* __restrict__ src, float* __restrict__ dst,
    const f16* __restrict__ fh, const float* __restrict__ bias, int dir) {
  __shared__ f16 ch[72 * 64];
  const int b = blockIdx.x;
  const int tid = threadIdx.x;
  const int wave = tid >> 6, lane = tid & 63;
  const int quad = lane >> 4, l15 = lane & 15;

  f16x8 Ah[9][2];
#pragma unroll
  for (int t = 0; t < 9; ++t)
#pragma unroll
    for (int kc = 0; kc < 2; ++kc)
      Ah[t][kc] = *(const f16x8*)&fh[(((wave * 9 + t) * 2 + kc) * 64 + lane) * 8];
  float bvs[4];
#pragma unroll
  for (int r = 0; r < 4; ++r) bvs[r] = bias[wave * 16 + quad * 4 + r];

  for (int s = tid; s < 2304; s += 256) ((unsigned*)ch)[s] = 0u;
  __syncthreads();

  const size_t sbase = (size_t)b * 64 * 4096;
  const int row0 = (dir > 0) ? 0 : 63;
  {
    int pos0 = tid & 63, cig = tid >> 6;
#pragma unroll
    for (int q = 0; q < 16; ++q) {
      int ci = cig * 16 + q;
      float v = src[sbase + (size_t)ci * 4096 + row0 * 64 + pos0];
      dst[sbase + (size_t)ci * 4096 + row0 * 64 + pos0] = v;
      int rowIdx = pos0 + 4;
      ch[rowIdx * 64 + (((ci >> 3) ^ (rowIdx & 7)) << 3) + (ci & 7)] = (f16)v;
    }
  }
  __syncthreads();

  const float inv = 1.0f / 256.0f;
  for (int s = 1; s < 64; ++s) {
    const int row = (dir > 0) ? s : 63 - s;
    float srow[4][4];
#pragma unroll
    for (int nt = 0; nt < 4; ++nt)
#pragma unroll
      for (int r = 0; r < 4; ++r)
        srow[nt][r] = src[sbase + (size_t)(wave * 16 + quad * 4 + r) * 4096 +
                          row * 64 + nt * 16 + l15];
    f32x4 acc[4];
#pragma unroll
    for (int nt = 0; nt < 4; ++nt) acc[nt] = (f32x4){0.f, 0.f, 0.f, 0.f};
#pragma unroll
    for (int t = 0; t < 9; ++t)
#pragma unroll
      for (int kc = 0; kc < 2; ++kc) {
#pragma unroll
        for (int nt = 0; nt < 4; ++nt) {
          int rowIdx = nt * 16 + l15 + t;
          int gr = kc * 4 + quad;
          f16x8 Bh = *(const f16x8*)&ch[rowIdx * 64 + ((gr ^ (rowIdx & 7)) << 3)];
          acc[nt] = __builtin_amdgcn_mfma_f32_16x16x32_f16(Ah[t][kc], Bh, acc[nt], 0, 0, 0);
        }
      }
    __syncthreads();
#pragma unroll
    for (int nt = 0; nt < 4; ++nt) {
      int pos = nt * 16 + l15;
      int rowIdx = pos + 4;
      f16x4 hv;
#pragma unroll
      for (int r = 0; r < 4; ++r) {
        float v = fmaxf(acc[nt][r] * inv + bvs[r], 0.f) + srow[nt][r];
        dst[sbase + (size_t)(wave * 16 + quad * 4 + r) * 4096 + row * 64 + pos] = v;
        hv[r] = (f16)v;
      }
      int ci0 = wave * 16 + quad * 4;
      *(f16x4*)&ch[rowIdx * 64 + (((ci0 >> 3) ^ (rowIdx & 7)) << 3) + (ci0 & 7)] = hv;
    }
    __syncthreads();
  }
}

// ---------------- transpose last two dims (64x64) per (b,c) ----------------

__global__ void rf_transpose(const float* __restrict__ src, float* __restrict__ dst) {
  int bc = blockIdx.x;  // 256
  __shared__ float tl[64][65];
  int tid = threadIdx.x;
  const float* sp = src + (size_t)bc * 4096;
  float* dp = dst + (size_t)bc * 4096;
  for (int s = tid; s < 4096; s += 256) {
    int h = s >> 6, w = s & 63;
    tl[w][h] = sp[s];
  }
  __syncthreads();
  for (int s = tid; s < 4096; s += 256) dp[s] = tl[s >> 6][s & 63];
}

// ---------------- final 1x1 conv + relu + 8x8 upsample ----------------

__global__ void rf_final(const float* __restrict__ t, const float* __restrict__ ow,
                         const float* __restrict__ ob, float* __restrict__ out) {
  int b = blockIdx.y;
  int s = blockIdx.x * 256 + threadIdx.x;  // 0..4095
  int w = s >> 6, h = s & 63;
  float acc = ob[0];
  for (int c = 0; c < 64; ++c)
    acc += ow[c] * t[(((size_t)b * 64 + c) * 64 + w) * 64 + h];
  acc = fmaxf(acc, 0.f);
  float4 vv = make_float4(acc, acc, acc, acc);
  for (int dy = 0; dy < 8; ++dy) {
    float* dp = out + ((size_t)b * 512 + h * 8 + dy) * 512 + w * 8;
    *(float4*)dp = vv;
    *(float4*)(dp + 4) = vv;
  }
}

// ---------------- launch ----------------

extern "C" void kernel_launch(void* const* d_in, const int* in_sizes, int n_in,
                              void* d_out, int out_size, void* d_ws, size_t ws_size,
                              hipStream_t stream) {
  const float* in    = (const float*)d_in[0];
  const float* wA    = (const float*)d_in[1];
  const float* bA    = (const float*)d_in[2];
  const float* wB    = (const float*)d_in[3];
  const float* wC    = (const float*)d_in[5];
  const float* bC    = (const float*)d_in[6];
  const float* gamma = (const float*)d_in[7];
  const float* bw1 = (const float*)d_in[8];  const float* bb1 = (const float*)d_in[9];
  const float* bw2 = (const float*)d_in[10]; const float* bb2 = (const float*)d_in[11];
  const float* bw3 = (const float*)d_in[12]; const float* bb3 = (const float*)d_in[13];
  const float* bw4 = (const float*)d_in[14]; const float* bb4 = (const float*)d_in[15];
  const float* bw5 = (const float*)d_in[16]; const float* bb5 = (const float*)d_in[17];
  const float* bw6 = (const float*)d_in[18]; const float* bb6 = (const float*)d_in[19];
  const float* du_w = (const float*)d_in[20]; const float* du_b = (const float*)d_in[21];
  const float* lr_w = (const float*)d_in[22]; const float* lr_b = (const float*)d_in[23];
  const float* ow   = (const float*)d_in[24]; const float* ob   = (const float*)d_in[25];
  float* out = (float*)d_out;
  float* ws = (float*)d_ws;

  // phase-1 (attention) buffers; offsets in f32 slots (f16 elems = 2x)
  f16* vH  = (f16*)(ws + 0);          // 16.8M f16 -> [0, 4194304)
  f16* xTh = (f16*)(ws + 4194304);    // [4194304, 8388608)
  f16* wCh = (f16*)(ws + 8388608);    // [8388608, 8912896)
  f16* yH  = (f16*)(ws + 16777216);   // [16777216, 20971520)
  // conv phase (F buffers = same sizes as old wsingle buffers)
  f16* w1h = (f16*)(ws + 0);          // [0, 2359296)
  f16* c1H = (f16*)(ws + 2359296);    // [2359296, 6553600)
  f16* w3h = (f16*)(ws + 6553600);    // [6553600, 7733248)
  f16* w2h = (f16*)(ws + 16777216);   // [16777216, 17956864)  (yH dead)
  f16* c2H = (f16*)(ws + 17956864);   // [17956864, 22151168)
  f16* w4h = (f16*)(ws + 22151168);   // [22151168, 22740992)
  f16* c4H = (f16*)(ws + 22740992);   // [22740992, 24838144)
  f16* c3H = c1H;
  f16* w5h = (f16*)(ws + 0);          // [0, 147456)       (w1 dead)
  f16* c5H = (f16*)(ws + 147456);     // [147456, 1196032)
  f16* w6h = (f16*)(ws + 1196032);    // [1196032, 1232896)
  float* tin = ws + 1232896;          // [1232896, 2281472)
  float* t0  = ws + 2281472;          // [2281472, 3330048)
  float* t1  = ws + 3330048;          // [3330048, 4378624)
  f16* duFh = (f16*)(ws + 4378624);   // [4378624, 4397056)  (c1/c3 dead)
  f16* lrFh = (f16*)(ws + 4397056);   // [4397056, 4415488)
  float* sm = ws + 33554432;
  float* A_  = sm;
  float* M_  = sm + 16384;
  float* iZ  = sm + 32768;
  float* u_  = sm + 49152;
  float* s_  = sm + 50176;
  float* c0_ = sm + 50304;
  float* fst = sm + 50308;
  float* zp  = sm + 50432;  // 64-float zero page for OOB DMA lanes

  rf_zero<<<1, 64, 0, stream>>>(zp);
  rf_s<<<1, 128, 0, stream>>>(wB, bA, s_, c0_);
  rf_u<<<4, 256, 0, stream>>>(wA, s_, u_);
  rf_fstat<<<4, 256, 0, stream>>>(in, fst);
  rf_A<<<dim3(16, 4), 256, 0, stream>>>(in, u_, c0_, fst, A_, M_);
  rf_Z<<<4096, 256, 0, stream>>>(in, A_, M_, iZ);
  rf_xsplit<<<dim3(64, 16, 4), 256, 0, stream>>>(in, xTh);
  rf_wC1<<<512, 256, 0, stream>>>(wC, wCh);
  rf_vgemmm<<<dim3(32, 8, 4), 256, 0, stream>>>(wCh, xTh, bC, vH);
  rf_attm<<<dim3(32, 4, 4), 256, 0, stream>>>(vH, A_, M_, iZ, in, gamma, yH);

  // fragment-ordered conv weights (sizes identical to old wsingle buffers)
  rf_wfragc<<<2304, 256, 0, stream>>>(bw1, w1h, 1024, 512);
  rf_wfragc<<<1152, 256, 0, stream>>>(bw3, w3h, 512, 512);
  rf_mconv<128, 128, false><<<dim3(128, 4), 256, 0, stream>>>(
      yH, w1h, bb1, zp, c1H, nullptr, 1024, 512);
  rf_wfragc<<<1152, 256, 0, stream>>>(bw2, w2h, 512, 512);
  rf_wfragc<<<576, 256, 0, stream>>>(bw4, w4h, 512, 256);
  rf_wfragc<<<144, 256, 0, stream>>>(bw5, w5h, 256, 128);
  rf_wfragc<<<36, 256, 0, stream>>>(bw6, w6h, 128, 64);
  rf_mconv<128, 128, false><<<dim3(128, 4), 256, 0, stream>>>(
      c1H, w2h, bb2, zp, c2H, nullptr, 512, 512);
  rf_mconv<128, 128, false><<<dim3(128, 4), 256, 0, stream>>>(
      c2H, w3h, bb3, zp, c3H, nullptr, 512, 512);
  rf_mconv<128, 128, false><<<dim3(128, 2), 256, 0, stream>>>(
      c3H, w4h, bb4, zp, c4H, nullptr, 512, 256);
  rf_wfrag<<<18, 256, 0, stream>>>(du_w, duFh);
  rf_wfrag<<<18, 256, 0, stream>>>(lr_w, lrFh);
  rf_mconv<128, 128, false><<<dim3(128, 1), 256, 0, stream>>>(
      c4H, w5h, bb5, zp, c5H, nullptr, 256, 128);
  rf_mconv<256, 64, true><<<dim3(64, 1), 256, 0, stream>>>(
      c5H, w6h, bb6, zp, nullptr, tin, 128, 64);

  rf_mscan<<<4, 256, 0, stream>>>(tin, t0, duFh, du_b, +1);
  rf_mscan<<<4, 256, 0, stream>>>(t0, t1, duFh, du_b, -1);
  rf_transpose<<<256, 256, 0, stream>>>(t1, t0);
  rf_mscan<<<4, 256, 0, stream>>>(t0, t1, lrFh, lr_b, +1);
  rf_mscan<<<4, 256, 0, stream>>>(t1, t0, lrFh, lr_b, -1);
  rf_final<<<dim3(16, 4), 256, 0, stream>>>(t0, ow, ob, out);
}

// Round 5
// 1682.657 us; speedup vs baseline: 1.1896x; 1.0117x over previous
//
#include <hip/hip_runtime.h>

// resFAN round 11 (R4 this session): counted-vmcnt attm (T3/T4 port).
// R3 post-mortem: doP's global f-loads after stage() forced an effective
// vmcnt(0) drain mid-step + another at __syncthreads -> every step paid
// exposed DMA latency twice (MfmaUtil stuck 26%).  Fix per m201/m218 recipe:
// f row preloaded to LDS (doP = lgkm-only broadcasts), sAh triple-buffered
// with stage(k+2) issued each step, and __syncthreads replaced by
// s_waitcnt vmcnt(4) lgkmcnt(0) + raw s_barrier (never drain to 0 in loop).
// LDS 80KB/block = 2 blocks/CU exact fit.
//
// Error budget unchanged: fp16 quant 2^-11, scales 16/256; fl is exact f32.

#define NPIX 4096

typedef _Float16 f16;
typedef _Float16 f16x8 __attribute__((ext_vector_type(8)));
typedef _Float16 f16x4 __attribute__((ext_vector_type(4)));
typedef float f32x4 __attribute__((ext_vector_type(4)));

__device__ inline void async16(const void* g, void* l) {
  __builtin_amdgcn_global_load_lds(
      (const __attribute__((address_space(1))) unsigned int*)g,
      (__attribute__((address_space(3))) unsigned int*)l, 16, 0, 0);
}

// ---------------- small prep kernels ----------------

__global__ void rf_zero(float* __restrict__ z) { z[threadIdx.x] = 0.f; }

__global__ void rf_s(const float* __restrict__ wB, const float* __restrict__ bA,
                     float* __restrict__ s_out, float* __restrict__ c0_out) {
  int c = threadIdx.x;  // 128 threads
  const float* row = wB + (size_t)c * 1024;
  float acc = 0.f;
  for (int i = 0; i < 1024; ++i) acc += row[i];
  s_out[c] = acc;
  __shared__ float sh[128];
  sh[c] = acc * bA[c];
  __syncthreads();
  for (int off = 64; off > 0; off >>= 1) {
    if (c < off) sh[c] += sh[c + off];
    __syncthreads();
  }
  if (c == 0) c0_out[0] = sh[0];
}

__global__ void rf_u(const float* __restrict__ wA, const float* __restrict__ s,
                     float* __restrict__ u) {
  int i = blockIdx.x * 256 + threadIdx.x;  // 1024 total
  float acc = 0.f;
  for (int c = 0; c < 128; ++c) acc += s[c] * wA[(size_t)c * 1024 + i];
  u[i] = acc;
}

__global__ void rf_fstat(const float* __restrict__ in, float* __restrict__ fstat) {
  int b = blockIdx.x;
  int t = threadIdx.x;
  const float* f = in + ((size_t)b * 1025 + 1024) * NPIX;
  float mx = -1e30f, mn = 1e30f;
  for (int j = t; j < NPIX; j += 256) {
    float v = f[j];
    mx = fmaxf(mx, v);
    mn = fminf(mn, v);
  }
  __shared__ float smx[256], smn[256];
  smx[t] = mx; smn[t] = mn;
  __syncthreads();
  for (int off = 128; off > 0; off >>= 1) {
    if (t < off) {
      smx[t] = fmaxf(smx[t], smx[t + off]);
      smn[t] = fminf(smn[t], smn[t + off]);
    }
    __syncthreads();
  }
  if (t == 0) { fstat[b] = smx[0]; fstat[4 + b] = smn[0]; }
}

__global__ __launch_bounds__(256) void rf_A(const float* __restrict__ in,
                                            const float* __restrict__ u,
                                            const float* __restrict__ c0p,
                                            const float* __restrict__ fst,
                                            float* __restrict__ A, float* __restrict__ M) {
  __shared__ float ul[1024];
  int b = blockIdx.y;
  int n = blockIdx.x * 256 + threadIdx.x;
  for (int s = threadIdx.x; s < 1024; s += 256) ul[s] = u[s];
  __syncthreads();
  const float* xp = in + (size_t)b * 1025 * NPIX + n;
  float acc = c0p[0];
#pragma unroll 8
  for (int i = 0; i < 1024; ++i) acc = fmaf(ul[i], xp[(size_t)i * NPIX], acc);
  A[b * NPIX + n] = acc;
  M[b * NPIX + n] = fmaxf(acc * fst[b], acc * fst[4 + b]);
}

__global__ void rf_Z(const float* __restrict__ in, const float* __restrict__ A,
                     const float* __restrict__ M, float* __restrict__ iZ) {
  int idx = blockIdx.x * 4 + (threadIdx.x >> 6);  // (b,n) pair, 16384 total
  int lane = threadIdx.x & 63;
  int b = idx >> 12;
  const float* f = in + ((size_t)b * 1025 + 1024) * NPIX;
  float a = A[idx], m = M[idx];
  float acc = 0.f;
#pragma unroll 4
  for (int it = 0; it < 64; ++it) acc += __expf(a * f[lane + it * 64] - m);
  for (int off = 32; off > 0; off >>= 1) acc += __shfl_down(acc, off, 64);
  if (lane == 0) iZ[idx] = 1.0f / acc;
}

// ---------------- x transpose: [b][ci][n] f32 -> [b][n][ci] f16, scale 16 ---

__global__ void rf_xsplit(const float* __restrict__ in, f16* __restrict__ xh) {
  __shared__ float tl[64][65];
  int nt = blockIdx.x, ct = blockIdx.y, b = blockIdx.z;
  int n0 = nt * 64, c0 = ct * 64;
  int tid = threadIdx.x;
  for (int s = tid; s < 4096; s += 256) {
    int r = s >> 6, c = s & 63;
    tl[r][c] = in[((size_t)b * 1025 + c0 + r) * NPIX + n0 + c];
  }
  __syncthreads();
  for (int s = tid; s < 512; s += 256) {
    int n = s >> 3, g = s & 7;
    f16x8 hb;
#pragma unroll
    for (int q = 0; q < 8; ++q) hb[q] = (f16)(16.f * tl[g * 8 + q][n]);
    size_t o = ((size_t)b * NPIX + n0 + n) * 1024 + c0 + g * 8;
    *(f16x8*)&xh[o] = hb;
  }
}

// ---------------- wC cast: [1024][1024] f32 -> f16, scale 256 --------------

__global__ void rf_wC1(const float* __restrict__ wC, f16* __restrict__ wh) {
  int base = (blockIdx.x * 256 + threadIdx.x) * 8;
  f16x8 hb;
#pragma unroll
  for (int q = 0; q < 8; ++q) hb[q] = (f16)(256.f * wC[base + q]);
  *(f16x8*)&wh[base] = hb;
}

// ---------------- MFMA v-GEMM (dbuf, single fp16): v = wC @ x + bC --------

__global__ __launch_bounds__(256, 2) void rf_vgemmm(
    const f16* __restrict__ wh, const f16* __restrict__ xh,
    const float* __restrict__ bC, f16* __restrict__ vH) {
  __shared__ f16 sA[2][4096], sB[2][4096];
  const int tid = threadIdx.x;
  const int nb = blockIdx.x * 128, cb = blockIdx.y * 128, b = blockIdx.z;
  const int pA = tid & 127;
  const int wv = tid >> 6, lane = tid & 63;
  const int mrow = lane & 15, quad = lane >> 4;
  const int wm = (wv & 1) * 64, wn = (wv >> 1) * 64;
  const size_t abase = (size_t)(cb + pA) * 1024;
  const size_t bbase = ((size_t)b * NPIX + nb + pA) * 1024;
  f32x4 acc[4][4];
#pragma unroll
  for (int i = 0; i < 4; ++i)
#pragma unroll
    for (int j = 0; j < 4; ++j) acc[i][j] = (f32x4){0.f, 0.f, 0.f, 0.f};

  auto stage = [&](int k0, int pb) {
#pragma unroll
    for (int s = 0; s < 2; ++s) {
      const int cc = ((tid + 256 * s) >> 7) & 3;
      const int lb = ((tid & ~63) + 256 * s) * 8;
      async16(wh + abase + k0 + cc * 8, &sA[pb][lb]);
      async16(xh + bbase + k0 + cc * 8, &sB[pb][lb]);
    }
  };
  stage(0, 0);
  int p = 0;
  for (int k0 = 0; k0 < 1024; k0 += 32) {
    __syncthreads();
    if (k0 + 32 < 1024) stage(k0 + 32, p ^ 1);
    f16x8 fa[4], fb[4];
#pragma unroll
    for (int mi = 0; mi < 4; ++mi)
      fa[mi] = *(const f16x8*)&sA[p][(quad * 128 + wm + mi * 16 + mrow) * 8];
#pragma unroll
    for (int ni = 0; ni < 4; ++ni)
      fb[ni] = *(const f16x8*)&sB[p][(quad * 128 + wn + ni * 16 + mrow) * 8];
#pragma unroll
    for (int mi = 0; mi < 4; ++mi)
#pragma unroll
      for (int ni = 0; ni < 4; ++ni)
        acc[mi][ni] = __builtin_amdgcn_mfma_f32_16x16x32_f16(fa[mi], fb[ni], acc[mi][ni], 0, 0, 0);
    p ^= 1;
  }
  const float inv = 1.0f / 4096.0f;
#pragma unroll
  for (int mi = 0; mi < 4; ++mi) {
#pragma unroll
    for (int rg = 0; rg < 4; ++rg) {
      int c = cb + wm + mi * 16 + quad * 4 + rg;
      float bv = bC[c];
#pragma unroll
      for (int ni = 0; ni < 4; ++ni) {
        int j = nb + wn + ni * 16 + mrow;
        vH[((size_t)b * 1024 + c) * NPIX + j] =
            (f16)(16.f * (acc[mi][ni][rg] * inv + bv));
      }
    }
  }
}

// ---------------- MFMA attention out-GEMM (counted-vmcnt pipeline) ---------

__global__ __launch_bounds__(256, 2) void rf_attm(
    const f16* __restrict__ vH,
    const float* __restrict__ Aarr, const float* __restrict__ Marr,
    const float* __restrict__ iZ, const float* __restrict__ in,
    const float* __restrict__ gptr, f16* __restrict__ yH) {
  __shared__ f16 sAh[3][8192];   // [buf][jgrp4][c256][8]  16KB each
  __shared__ f16 sPh[2][4096];   // [buf][kc4][i128][8]     8KB each
  __shared__ float fl[4096];     // f row, 16KB
  const int tid = threadIdx.x;
  const int ib = blockIdx.x * 128, cb = blockIdx.y * 256, b = blockIdx.z;
  const int wv = tid >> 6, lane = tid & 63;
  const int mrow = lane & 15, quad = lane >> 4;
  const int wm = wv * 64;                 // wave's 64-c slice of 256
  const int ni_ = tid & 127;
  const int kc0 = tid >> 7;               // 0..1
  const float av2 = Aarr[b * NPIX + ib + ni_] * 1.44269504f;
  const float mv2 = Marr[b * NPIX + ib + ni_] * 1.44269504f;
  const float* f = in + ((size_t)b * 1025 + 1024) * NPIX;
  const f16* vrow = vH + ((size_t)b * 1024 + cb + tid) * NPIX;

  f32x4 acc[4][8];
#pragma unroll
  for (int i = 0; i < 4; ++i)
#pragma unroll
    for (int j = 0; j < 8; ++j) acc[i][j] = (f32x4){0.f, 0.f, 0.f, 0.f};

  auto stage = [&](int j0, int pb) {
#pragma unroll
    for (int s = 0; s < 4; ++s)
      async16(vrow + j0 + s * 8, &sAh[pb][(s * 256 + tid) * 8]);
  };
  auto doP = [&](int j0, int pb) {
#pragma unroll
    for (int it = 0; it < 2; ++it) {
      const int kc = kc0 + 2 * it;
      const float4 fa4 = *(const float4*)&fl[j0 + kc * 8];
      const float4 fb4 = *(const float4*)&fl[j0 + kc * 8 + 4];
      const float fj[8] = {fa4.x, fa4.y, fa4.z, fa4.w, fb4.x, fb4.y, fb4.z, fb4.w};
      f16x8 ph;
#pragma unroll
      for (int q = 0; q < 8; ++q)
        ph[q] = (f16)exp2f(fmaf(av2, fj[q], -mv2));
      *(f16x8*)&sPh[pb][(kc * 128 + ni_) * 8] = ph;
    }
  };

  // prologue: f row -> LDS, A0, then P0 while A1 flies
#pragma unroll
  for (int s = 0; s < 4; ++s)
    async16(f + (tid + 256 * s) * 4, &fl[((tid & ~63) + 256 * s) * 4]);
  stage(0, 0);
  asm volatile("s_waitcnt vmcnt(0)" ::: "memory");
  __builtin_amdgcn_s_barrier();
  doP(0, 0);
  stage(32, 1);
  asm volatile("s_waitcnt lgkmcnt(0)" ::: "memory");
  __builtin_amdgcn_s_barrier();

  for (int k = 0; k < 126; ++k) {
    const int pa = k % 3;
    const int pp = k & 1;
    f16x8 fa[4], fb[8];
#pragma unroll
    for (int mi = 0; mi < 4; ++mi)
      fa[mi] = *(const f16x8*)&sAh[pa][(quad * 256 + wm + mi * 16 + mrow) * 8];
#pragma unroll
    for (int ni = 0; ni < 8; ++ni)
      fb[ni] = *(const f16x8*)&sPh[pp][(quad * 128 + ni * 16 + mrow) * 8];
    stage((k + 2) * 32, (k + 2) % 3);   // lands by end of step k+1
    doP((k + 1) * 32, pp ^ 1);          // lgkm-only, overlaps MFMA
#pragma unroll
    for (int mi = 0; mi < 4; ++mi)
#pragma unroll
      for (int ni = 0; ni < 8; ++ni)
        acc[mi][ni] = __builtin_amdgcn_mfma_f32_16x16x32_f16(fa[mi], fb[ni], acc[mi][ni], 0, 0, 0);
    asm volatile("s_waitcnt vmcnt(4) lgkmcnt(0)" ::: "memory");
    __builtin_amdgcn_s_barrier();
  }
  {  // k = 126: pa=0, pp=0; last doP, drain all DMAs
    f16x8 fa[4], fb[8];
#pragma unroll
    for (int mi = 0; mi < 4; ++mi)
      fa[mi] = *(const f16x8*)&sAh[0][(quad * 256 + wm + mi * 16 + mrow) * 8];
#pragma unroll
    for (int ni = 0; ni < 8; ++ni)
      fb[ni] = *(const f16x8*)&sPh[0][(quad * 128 + ni * 16 + mrow) * 8];
    doP(127 * 32, 1);
#pragma unroll
    for (int mi = 0; mi < 4; ++mi)
#pragma unroll
      for (int ni = 0; ni < 8; ++ni)
        acc[mi][ni] = __builtin_amdgcn_mfma_f32_16x16x32_f16(fa[mi], fb[ni], acc[mi][ni], 0, 0, 0);
    asm volatile("s_waitcnt vmcnt(0) lgkmcnt(0)" ::: "memory");
    __builtin_amdgcn_s_barrier();
  }
  {  // k = 127: pa=1, pp=1
    f16x8 fa[4], fb[8];
#pragma unroll
    for (int mi = 0; mi < 4; ++mi)
      fa[mi] = *(const f16x8*)&sAh[1][(quad * 256 + wm + mi * 16 + mrow) * 8];
#pragma unroll
    for (int ni = 0; ni < 8; ++ni)
      fb[ni] = *(const f16x8*)&sPh[1][(quad * 128 + ni * 16 + mrow) * 8];
#pragma unroll
    for (int mi = 0; mi < 4; ++mi)
#pragma unroll
      for (int ni = 0; ni < 8; ++ni)
        acc[mi][ni] = __builtin_amdgcn_mfma_f32_16x16x32_f16(fa[mi], fb[ni], acc[mi][ni], 0, 0, 0);
  }

  const float g = gptr[0];
  const float inv16 = 1.0f / 16.0f;
  float zvi[8];
#pragma unroll
  for (int ni = 0; ni < 8; ++ni)
    zvi[ni] = iZ[b * NPIX + ib + ni * 16 + mrow] * inv16;
#pragma unroll
  for (int mi = 0; mi < 4; ++mi) {
    const int cbase = cb + wm + mi * 16 + quad * 4;
#pragma unroll
    for (int ni = 0; ni < 8; ++ni) {
      const int i = ib + ni * 16 + mrow;
      f16x4 hv;
#pragma unroll
      for (int rg = 0; rg < 4; ++rg) {
        float xr = in[((size_t)b * 1025 + cbase + rg) * NPIX + i];
        hv[rg] = (f16)(16.f * (g * (acc[mi][ni][rg] * zvi[ni]) + xr));
      }
      *(f16x4*)&yH[((size_t)b * NPIX + i) * 1024 + cbase] = hv;
    }
  }
}

// ---------------- conv weight prep: [CO][CI][3][3] -> MFMA-fragment order --

__global__ void rf_wfragc(const float* __restrict__ w, f16* __restrict__ F,
                          int CI, int CO) {
  int gid = blockIdx.x * 256 + threadIdx.x;
  const int C16 = CO >> 4, KI = CI >> 5;
  const int total = 9 * KI * C16 * 64;
  if (gid >= total) return;
  int lane = gid & 63;
  int rest = gid >> 6;
  int c16 = rest % C16;
  int rest2 = rest / C16;
  int k = rest2 % KI;
  int t = rest2 / KI;
  int co = c16 * 16 + (lane & 15);
  int ci = k * 32 + (lane >> 4) * 8;
  f16x8 hb;
#pragma unroll
  for (int j = 0; j < 8; ++j)
    hb[j] = (f16)(256.0f * w[((size_t)co * CI + ci + j) * 9 + t]);
  *(f16x8*)&F[(size_t)gid * 8] = hb;
}

// ---------------- MFMA dilated 3x3 conv (halo dbuf A, register B) ----------

template <int BM, int BN, bool F32OUT>
__global__ __launch_bounds__(256, 2) void rf_mconv(
    const f16* __restrict__ xh, const f16* __restrict__ F,
    const float* __restrict__ bias, const float* __restrict__ zp,
    f16* __restrict__ oh, float* __restrict__ of, int CI, int CO) {
  constexpr int ROWS = BM / 64;
  constexpr int TPI = 4096 / BM;
  constexpr int HROWS = ROWS + 4;               // +-2 row halo
  constexpr int COLP = 72;                      // 68 used + pad to 72
  constexpr int CHUNKS = HROWS * 4 * COLP;      // 16B chunks in halo tile
  constexpr int NSTG = (CHUNKS + 255) / 256;    // A stage instrs per thread
  __shared__ f16 sA[2][NSTG * 2048];
  const int tid = threadIdx.x;
  const int blkpx = blockIdx.x;
  const int cob = blockIdx.y * BN;
  const int b = blkpx / TPI;
  const int h0 = (blkpx - b * TPI) * ROWS;

  const int wv = tid >> 6, lane = tid & 63;
  const int mrow = lane & 15, quad = lane >> 4;
  const int wm = (BN == 128) ? (wv & 1) * 64 : wv * 64;
  const int wn = (BN == 128) ? (wv >> 1) * 64 : 0;
  const int r_out = wm >> 6;
  const int KI = CI >> 5;
  const int C16 = CO >> 4;
  const int cb16 = (cob + wn) >> 4;

  f32x4 acc[4][4];
#pragma unroll
  for (int i = 0; i < 4; ++i)
#pragma unroll
    for (int j = 0; j < 4; ++j) acc[i][j] = (f32x4){0.f, 0.f, 0.f, 0.f};

  // per-lane A staging sources (affine in k: +k*32 f16 when valid)
  const f16* abase[NSTG];
  unsigned vmask = 0;
#pragma unroll
  for (int s = 0; s < NSTG; ++s) {
    int idx = tid + 256 * s;
    int rowks = idx / COLP;
    int col = idx - rowks * COLP;
    int r = rowks >> 2, ks = rowks & 3;
    int srow = h0 + r - 2, scol = col - 2;
    bool ok = (idx < CHUNKS) && ((unsigned)srow < 64u) && ((unsigned)scol < 64u);
    abase[s] = ok ? xh + (((size_t)b * 64 + srow) * 64 + scol) * CI + ks * 8
                  : (const f16*)zp;
    if (ok) vmask |= (1u << s);
  }
  auto stageA = [&](int k, int pb) {
#pragma unroll
    for (int s = 0; s < NSTG; ++s) {
      const f16* sp = abase[s] + (((vmask >> s) & 1u) ? k * 32 : 0);
      async16(sp, &sA[pb][((tid & ~63) + 256 * s) * 8]);
    }
  };

  // per-lane B fragment base (fragment-ordered F)
  const f16* Fb = F + ((size_t)cb16 * 64 + lane) * 8;

  stageA(0, 0);
  int p = 0;
  for (int k = 0; k < KI; ++k) {
    __syncthreads();                    // A(k) writes drained & visible
    if (k + 1 < KI) stageA(k + 1, p ^ 1);
#pragma unroll
    for (int t = 0; t < 9; ++t) {
      const int dh = (t / 3) * 2 - 2, dw = (t - (t / 3) * 3) * 2 - 2;
      f16x8 fb[4];
#pragma unroll
      for (int ni = 0; ni < 4; ++ni)
        fb[ni] = *(const f16x8*)(Fb + ((size_t)(t * KI + k) * C16 + ni) * 512);
      f16x8 fa[4];
#pragma unroll
      for (int mi = 0; mi < 4; ++mi)
        fa[mi] = *(const f16x8*)&sA[p][(((r_out + dh + 2) * 4 + quad) * COLP +
                                       mi * 16 + mrow + dw + 2) * 8];
#pragma unroll
      for (int mi = 0; mi < 4; ++mi)
#pragma unroll
        for (int ni = 0; ni < 4; ++ni)
          acc[mi][ni] = __builtin_amdgcn_mfma_f32_16x16x32_f16(fa[mi], fb[ni], acc[mi][ni], 0, 0, 0);
    }
    p ^= 1;
  }

  const float inv = 1.0f / 4096.0f;
  float bvs[4];
#pragma unroll
  for (int ni = 0; ni < 4; ++ni) bvs[ni] = bias[cob + wn + ni * 16 + mrow];
#pragma unroll
  for (int mi = 0; mi < 4; ++mi) {
#pragma unroll
    for (int rg = 0; rg < 4; ++rg) {
      int px = wm + mi * 16 + quad * 4 + rg;
      int hh = h0 + (px >> 6), wwp = px & 63;
#pragma unroll
      for (int ni = 0; ni < 4; ++ni) {
        int co = cob + wn + ni * 16 + mrow;
        float vv = fmaxf(acc[mi][ni][rg] * inv + bvs[ni], 0.f);
        if (F32OUT) {
          of[(((size_t)b * CO + co) * 64 + hh) * 64 + wwp] = vv;
        } else {
          oh[(((size_t)b * 64 + hh) * 64 + wwp) * CO + co] = (f16)(vv * 16.f);
        }
      }
    }
  }
}

// ---------------- scan weight frag prep: w[64][64][9] -> frag order ---------

__global__ void rf_wfrag(const float* __restrict__ w, f16* __restrict__ fh) {
  int gid = blockIdx.x * 256 + threadIdx.x;
  if (gid >= 4608) return;
  int lane = gid & 63;
  int rem = gid >> 6;
  int kc = rem & 1;
  int rem2 = rem >> 1;
  int t = rem2 % 9;
  int w4 = rem2 / 9;
  int co = w4 * 16 + (lane & 15);
  int cib = kc * 32 + (lane >> 4) * 8;
  f16x8 hb;
#pragma unroll
  for (int j = 0; j < 8; ++j)
    hb[j] = (f16)(256.f * w[((size_t)co * 64 + cib + j) * 9 + t]);
  *(f16x8*)&fh[(size_t)gid * 8] = hb;
}

// ---------------- MFMA recurrent scan (single fp16 carry) ------------------

__global__ __launch_bounds__(256, 1) void rf_mscan(
    const float* __restrict__ src, float* __restrict__ dst,
    const f16* __restrict__ fh, const float* __restrict__ bias, int dir) {
  __shared__ f16 ch[72 * 64];
  const int b = blockIdx.x;
  const int tid = threadIdx.x;
  const int wave = tid >> 6, lane = tid & 63;
  const int quad = lane >> 4, l15 = lane & 15;

  f16x8 Ah[9][2];
#pragma unroll
  for (int t = 0; t < 9; ++t)
#pragma unroll
    for (int kc = 0; kc < 2; ++kc)
      Ah[t][kc] = *(const f16x8*)&fh[(((wave * 9 + t) * 2 + kc) * 64 + lane) * 8];
  float bvs[4];
#pragma unroll
  for (int r = 0; r < 4; ++r) bvs[r] = bias[wave * 16 + quad * 4 + r];

  for (int s = tid; s < 2304; s += 256) ((unsigned*)ch)[s] = 0u;
  __syncthreads();

  const size_t sbase = (size_t)b * 64 * 4096;
  const int row0 = (dir > 0) ? 0 : 63;
  {
    int pos0 = tid & 63, cig = tid >> 6;
#pragma unroll
    for (int q = 0; q < 16; ++q) {
      int ci = cig * 16 + q;
      float v = src[sbase + (size_t)ci * 4096 + row0 * 64 + pos0];
      dst[sbase + (size_t)ci * 4096 + row0 * 64 + pos0] = v;
      int rowIdx = pos0 + 4;
      ch[rowIdx * 64 + (((ci >> 3) ^ (rowIdx & 7)) << 3) + (ci & 7)] = (f16)v;
    }
  }
  __syncthreads();

  const float inv = 1.0f / 256.0f;
  for (int s = 1; s < 64; ++s) {
    const int row = (dir > 0) ? s : 63 - s;
    float srow[4][4];
#pragma unroll
    for (int nt = 0; nt < 4; ++nt)
#pragma unroll
      for (int r = 0; r < 4; ++r)
        srow[nt][r] = src[sbase + (size_t)(wave * 16 + quad * 4 + r) * 4096 +
                          row * 64 + nt * 16 + l15];
    f32x4 acc[4];
#pragma unroll
    for (int nt = 0; nt < 4; ++nt) acc[nt] = (f32x4){0.f, 0.f, 0.f, 0.f};
#pragma unroll
    for (int t = 0; t < 9; ++t)
#pragma unroll
      for (int kc = 0; kc < 2; ++kc) {
#pragma unroll
        for (int nt = 0; nt < 4; ++nt) {
          int rowIdx = nt * 16 + l15 + t;
          int gr = kc * 4 + quad;
          f16x8 Bh = *(const f16x8*)&ch[rowIdx * 64 + ((gr ^ (rowIdx & 7)) << 3)];
          acc[nt] = __builtin_amdgcn_mfma_f32_16x16x32_f16(Ah[t][kc], Bh, acc[nt], 0, 0, 0);
        }
      }
    __syncthreads();
#pragma unroll
    for (int nt = 0; nt < 4; ++nt) {
      int pos = nt * 16 + l15;
      int rowIdx = pos + 4;
      f16x4 hv;
#pragma unroll
      for (int r = 0; r < 4; ++r) {
        float v = fmaxf(acc[nt][r] * inv + bvs[r], 0.f) + srow[nt][r];
        dst[sbase + (size_t)(wave * 16 + quad * 4 + r) * 4096 + row * 64 + pos] = v;
        hv[r] = (f16)v;
      }
      int ci0 = wave * 16 + quad * 4;
      *(f16x4*)&ch[rowIdx * 64 + (((ci0 >> 3) ^ (rowIdx & 7)) << 3) + (ci0 & 7)] = hv;
    }
    __syncthreads();
  }
}

// ---------------- transpose last two dims (64x64) per (b,c) ----------------

__global__ void rf_transpose(const float* __restrict__ src, float* __restrict__ dst) {
  int bc = blockIdx.x;  // 256
  __shared__ float tl[64][65];
  int tid = threadIdx.x;
  const float* sp = src + (size_t)bc * 4096;
  float* dp = dst + (size_t)bc * 4096;
  for (int s = tid; s < 4096; s += 256) {
    int h = s >> 6, w = s & 63;
    tl[w][h] = sp[s];
  }
  __syncthreads();
  for (int s = tid; s < 4096; s += 256) dp[s] = tl[s >> 6][s & 63];
}

// ---------------- final 1x1 conv + relu + 8x8 upsample ----------------

__global__ void rf_final(const float* __restrict__ t, const float* __restrict__ ow,
                         const float* __restrict__ ob, float* __restrict__ out) {
  int b = blockIdx.y;
  int s = blockIdx.x * 256 + threadIdx.x;  // 0..4095
  int w = s >> 6, h = s & 63;
  float acc = ob[0];
  for (int c = 0; c < 64; ++c)
    acc += ow[c] * t[(((size_t)b * 64 + c) * 64 + w) * 64 + h];
  acc = fmaxf(acc, 0.f);
  float4 vv = make_float4(acc, acc, acc, acc);
  for (int dy = 0; dy < 8; ++dy) {
    float* dp = out + ((size_t)b * 512 + h * 8 + dy) * 512 + w * 8;
    *(float4*)dp = vv;
    *(float4*)(dp + 4) = vv;
  }
}

// ---------------- launch ----------------

extern "C" void kernel_launch(void* const* d_in, const int* in_sizes, int n_in,
                              void* d_out, int out_size, void* d_ws, size_t ws_size,
                              hipStream_t stream) {
  const float* in    = (const float*)d_in[0];
  const float* wA    = (const float*)d_in[1];
  const float* bA    = (const float*)d_in[2];
  const float* wB    = (const float*)d_in[3];
  const float* wC    = (const float*)d_in[5];
  const float* bC    = (const float*)d_in[6];
  const float* gamma = (const float*)d_in[7];
  const float* bw1 = (const float*)d_in[8];  const float* bb1 = (const float*)d_in[9];
  const float* bw2 = (const float*)d_in[10]; const float* bb2 = (const float*)d_in[11];
  const float* bw3 = (const float*)d_in[12]; const float* bb3 = (const float*)d_in[13];
  const float* bw4 = (const float*)d_in[14]; const float* bb4 = (const float*)d_in[15];
  const float* bw5 = (const float*)d_in[16]; const float* bb5 = (const float*)d_in[17];
  const float* bw6 = (const float*)d_in[18]; const float* bb6 = (const float*)d_in[19];
  const float* du_w = (const float*)d_in[20]; const float* du_b = (const float*)d_in[21];
  const float* lr_w = (const float*)d_in[22]; const float* lr_b = (const float*)d_in[23];
  const float* ow   = (const float*)d_in[24]; const float* ob   = (const float*)d_in[25];
  float* out = (float*)d_out;
  float* ws = (float*)d_ws;

  // phase-1 (attention) buffers; offsets in f32 slots (f16 elems = 2x)
  f16* vH  = (f16*)(ws + 0);          // 16.8M f16 -> [0, 4194304)
  f16* xTh = (f16*)(ws + 4194304);    // [4194304, 8388608)
  f16* wCh = (f16*)(ws + 8388608);    // [8388608, 8912896)
  f16* yH  = (f16*)(ws + 16777216);   // [16777216, 20971520)
  // conv phase (F buffers = same sizes as old wsingle buffers)
  f16* w1h = (f16*)(ws + 0);          // [0, 2359296)
  f16* c1H = (f16*)(ws + 2359296);    // [2359296, 6553600)
  f16* w3h = (f16*)(ws + 6553600);    // [6553600, 7733248)
  f16* w2h = (f16*)(ws + 16777216);   // [16777216, 17956864)  (yH dead)
  f16* c2H = (f16*)(ws + 17956864);   // [17956864, 22151168)
  f16* w4h = (f16*)(ws + 22151168);   // [22151168, 22740992)
  f16* c4H = (f16*)(ws + 22740992);   // [22740992, 24838144)
  f16* c3H = c1H;
  f16* w5h = (f16*)(ws + 0);          // [0, 147456)       (w1 dead)
  f16* c5H = (f16*)(ws + 147456);     // [147456, 1196032)
  f16* w6h = (f16*)(ws + 1196032);    // [1196032, 1232896)
  float* tin = ws + 1232896;          // [1232896, 2281472)
  float* t0  = ws + 2281472;          // [2281472, 3330048)
  float* t1  = ws + 3330048;          // [3330048, 4378624)
  f16* duFh = (f16*)(ws + 4378624);   // [4378624, 4397056)  (c1/c3 dead)
  f16* lrFh = (f16*)(ws + 4397056);   // [4397056, 4415488)
  float* sm = ws + 33554432;
  float* A_  = sm;
  float* M_  = sm + 16384;
  float* iZ  = sm + 32768;
  float* u_  = sm + 49152;
  float* s_  = sm + 50176;
  float* c0_ = sm + 50304;
  float* fst = sm + 50308;
  float* zp  = sm + 50432;  // 64-float zero page for OOB DMA lanes

  rf_zero<<<1, 64, 0, stream>>>(zp);
  rf_s<<<1, 128, 0, stream>>>(wB, bA, s_, c0_);
  rf_u<<<4, 256, 0, stream>>>(wA, s_, u_);
  rf_fstat<<<4, 256, 0, stream>>>(in, fst);
  rf_A<<<dim3(16, 4), 256, 0, stream>>>(in, u_, c0_, fst, A_, M_);
  rf_Z<<<4096, 256, 0, stream>>>(in, A_, M_, iZ);
  rf_xsplit<<<dim3(64, 16, 4), 256, 0, stream>>>(in, xTh);
  rf_wC1<<<512, 256, 0, stream>>>(wC, wCh);
  rf_vgemmm<<<dim3(32, 8, 4), 256, 0, stream>>>(wCh, xTh, bC, vH);
  rf_attm<<<dim3(32, 4, 4), 256, 0, stream>>>(vH, A_, M_, iZ, in, gamma, yH);

  // fragment-ordered conv weights (sizes identical to old wsingle buffers)
  rf_wfragc<<<2304, 256, 0, stream>>>(bw1, w1h, 1024, 512);
  rf_wfragc<<<1152, 256, 0, stream>>>(bw3, w3h, 512, 512);
  rf_mconv<128, 128, false><<<dim3(128, 4), 256, 0, stream>>>(
      yH, w1h, bb1, zp, c1H, nullptr, 1024, 512);
  rf_wfragc<<<1152, 256, 0, stream>>>(bw2, w2h, 512, 512);
  rf_wfragc<<<576, 256, 0, stream>>>(bw4, w4h, 512, 256);
  rf_wfragc<<<144, 256, 0, stream>>>(bw5, w5h, 256, 128);
  rf_wfragc<<<36, 256, 0, stream>>>(bw6, w6h, 128, 64);
  rf_mconv<128, 128, false><<<dim3(128, 4), 256, 0, stream>>>(
      c1H, w2h, bb2, zp, c2H, nullptr, 512, 512);
  rf_mconv<128, 128, false><<<dim3(128, 4), 256, 0, stream>>>(
      c2H, w3h, bb3, zp, c3H, nullptr, 512, 512);
  rf_mconv<128, 128, false><<<dim3(128, 2), 256, 0, stream>>>(
      c3H, w4h, bb4, zp, c4H, nullptr, 512, 256);
  rf_wfrag<<<18, 256, 0, stream>>>(du_w, duFh);
  rf_wfrag<<<18, 256, 0, stream>>>(lr_w, lrFh);
  rf_mconv<128, 128, false><<<dim3(128, 1), 256, 0, stream>>>(
      c4H, w5h, bb5, zp, c5H, nullptr, 256, 128);
  rf_mconv<256, 64, true><<<dim3(64, 1), 256, 0, stream>>>(
      c5H, w6h, bb6, zp, nullptr, tin, 128, 64);

  rf_mscan<<<4, 256, 0, stream>>>(tin, t0, duFh, du_b, +1);
  rf_mscan<<<4, 256, 0, stream>>>(t0, t1, duFh, du_b, -1);
  rf_transpose<<<256, 256, 0, stream>>>(t1, t0);
  rf_mscan<<<4, 256, 0, stream>>>(t0, t1, lrFh, lr_b, +1);
  rf_mscan<<<4, 256, 0, stream>>>(t1, t0, lrFh, lr_b, -1);
  rf_final<<<dim3(16, 4), 256, 0, stream>>>(t0, ow, ob, out);
}

// Round 6
// 1679.746 us; speedup vs baseline: 1.1916x; 1.0017x over previous
//
#include <hip/hip_runtime.h>

// resFAN round 12 (R5 this session): conv VMEM-ordering fix + XCD swizzle.
// R4 counters: convs dominate (~6x198us), MfmaUtil 33%, HBM 8%.  Root cause
// theory: VMEM retires IN ORDER per wave -> current body issues stageA (7 HBM
// DMAs) first, so every tap's fb weight-load wait transitively drains the A
// DMAs (tap0 eats ~900cyc/k-iter), and weights round-robin over all XCDs'
// L2s -> fb misses at HBM latency.  Fix: (1) stageA moved AFTER all fb
// issues; (2) fb double-buffered 1 tap ahead (k-loop unrolled x2 for
// compile-time parity); (3) flat grid + XCD-pair-per-co-slice swizzle so
// weight slices stay L2-resident.
//
// Error budget unchanged: fp16 quant 2^-11, scales 16/256.

#define NPIX 4096

typedef _Float16 f16;
typedef _Float16 f16x8 __attribute__((ext_vector_type(8)));
typedef _Float16 f16x4 __attribute__((ext_vector_type(4)));
typedef float f32x4 __attribute__((ext_vector_type(4)));

__device__ inline void async16(const void* g, void* l) {
  __builtin_amdgcn_global_load_lds(
      (const __attribute__((address_space(1))) unsigned int*)g,
      (__attribute__((address_space(3))) unsigned int*)l, 16, 0, 0);
}

// ---------------- small prep kernels ----------------

__global__ void rf_zero(float* __restrict__ z) { z[threadIdx.x] = 0.f; }

__global__ void rf_s(const float* __restrict__ wB, const float* __restrict__ bA,
                     float* __restrict__ s_out, float* __restrict__ c0_out) {
  int c = threadIdx.x;  // 128 threads
  const float* row = wB + (size_t)c * 1024;
  float acc = 0.f;
  for (int i = 0; i < 1024; ++i) acc += row[i];
  s_out[c] = acc;
  __shared__ float sh[128];
  sh[c] = acc * bA[c];
  __syncthreads();
  for (int off = 64; off > 0; off >>= 1) {
    if (c < off) sh[c] += sh[c + off];
    __syncthreads();
  }
  if (c == 0) c0_out[0] = sh[0];
}

__global__ void rf_u(const float* __restrict__ wA, const float* __restrict__ s,
                     float* __restrict__ u) {
  int i = blockIdx.x * 256 + threadIdx.x;  // 1024 total
  float acc = 0.f;
  for (int c = 0; c < 128; ++c) acc += s[c] * wA[(size_t)c * 1024 + i];
  u[i] = acc;
}

__global__ void rf_fstat(const float* __restrict__ in, float* __restrict__ fstat) {
  int b = blockIdx.x;
  int t = threadIdx.x;
  const float* f = in + ((size_t)b * 1025 + 1024) * NPIX;
  float mx = -1e30f, mn = 1e30f;
  for (int j = t; j < NPIX; j += 256) {
    float v = f[j];
    mx = fmaxf(mx, v);
    mn = fminf(mn, v);
  }
  __shared__ float smx[256], smn[256];
  smx[t] = mx; smn[t] = mn;
  __syncthreads();
  for (int off = 128; off > 0; off >>= 1) {
    if (t < off) {
      smx[t] = fmaxf(smx[t], smx[t + off]);
      smn[t] = fminf(smn[t], smn[t + off]);
    }
    __syncthreads();
  }
  if (t == 0) { fstat[b] = smx[0]; fstat[4 + b] = smn[0]; }
}

__global__ __launch_bounds__(256) void rf_A(const float* __restrict__ in,
                                            const float* __restrict__ u,
                                            const float* __restrict__ c0p,
                                            const float* __restrict__ fst,
                                            float* __restrict__ A, float* __restrict__ M) {
  __shared__ float ul[1024];
  int b = blockIdx.y;
  int n = blockIdx.x * 256 + threadIdx.x;
  for (int s = threadIdx.x; s < 1024; s += 256) ul[s] = u[s];
  __syncthreads();
  const float* xp = in + (size_t)b * 1025 * NPIX + n;
  float acc = c0p[0];
#pragma unroll 8
  for (int i = 0; i < 1024; ++i) acc = fmaf(ul[i], xp[(size_t)i * NPIX], acc);
  A[b * NPIX + n] = acc;
  M[b * NPIX + n] = fmaxf(acc * fst[b], acc * fst[4 + b]);
}

__global__ void rf_Z(const float* __restrict__ in, const float* __restrict__ A,
                     const float* __restrict__ M, float* __restrict__ iZ) {
  int idx = blockIdx.x * 4 + (threadIdx.x >> 6);  // (b,n) pair, 16384 total
  int lane = threadIdx.x & 63;
  int b = idx >> 12;
  const float* f = in + ((size_t)b * 1025 + 1024) * NPIX;
  float a = A[idx], m = M[idx];
  float acc = 0.f;
#pragma unroll 4
  for (int it = 0; it < 64; ++it) acc += __expf(a * f[lane + it * 64] - m);
  for (int off = 32; off > 0; off >>= 1) acc += __shfl_down(acc, off, 64);
  if (lane == 0) iZ[idx] = 1.0f / acc;
}

// ---------------- x transpose: [b][ci][n] f32 -> [b][n][ci] f16, scale 16 ---

__global__ void rf_xsplit(const float* __restrict__ in, f16* __restrict__ xh) {
  __shared__ float tl[64][65];
  int nt = blockIdx.x, ct = blockIdx.y, b = blockIdx.z;
  int n0 = nt * 64, c0 = ct * 64;
  int tid = threadIdx.x;
  for (int s = tid; s < 4096; s += 256) {
    int r = s >> 6, c = s & 63;
    tl[r][c] = in[((size_t)b * 1025 + c0 + r) * NPIX + n0 + c];
  }
  __syncthreads();
  for (int s = tid; s < 512; s += 256) {
    int n = s >> 3, g = s & 7;
    f16x8 hb;
#pragma unroll
    for (int q = 0; q < 8; ++q) hb[q] = (f16)(16.f * tl[g * 8 + q][n]);
    size_t o = ((size_t)b * NPIX + n0 + n) * 1024 + c0 + g * 8;
    *(f16x8*)&xh[o] = hb;
  }
}

// ---------------- wC cast: [1024][1024] f32 -> f16, scale 256 --------------

__global__ void rf_wC1(const float* __restrict__ wC, f16* __restrict__ wh) {
  int base = (blockIdx.x * 256 + threadIdx.x) * 8;
  f16x8 hb;
#pragma unroll
  for (int q = 0; q < 8; ++q) hb[q] = (f16)(256.f * wC[base + q]);
  *(f16x8*)&wh[base] = hb;
}

// ---------------- MFMA v-GEMM (dbuf, single fp16): v = wC @ x + bC --------

__global__ __launch_bounds__(256, 2) void rf_vgemmm(
    const f16* __restrict__ wh, const f16* __restrict__ xh,
    const float* __restrict__ bC, f16* __restrict__ vH) {
  __shared__ f16 sA[2][4096], sB[2][4096];
  const int tid = threadIdx.x;
  const int nb = blockIdx.x * 128, cb = blockIdx.y * 128, b = blockIdx.z;
  const int pA = tid & 127;
  const int wv = tid >> 6, lane = tid & 63;
  const int mrow = lane & 15, quad = lane >> 4;
  const int wm = (wv & 1) * 64, wn = (wv >> 1) * 64;
  const size_t abase = (size_t)(cb + pA) * 1024;
  const size_t bbase = ((size_t)b * NPIX + nb + pA) * 1024;
  f32x4 acc[4][4];
#pragma unroll
  for (int i = 0; i < 4; ++i)
#pragma unroll
    for (int j = 0; j < 4; ++j) acc[i][j] = (f32x4){0.f, 0.f, 0.f, 0.f};

  auto stage = [&](int k0, int pb) {
#pragma unroll
    for (int s = 0; s < 2; ++s) {
      const int cc = ((tid + 256 * s) >> 7) & 3;
      const int lb = ((tid & ~63) + 256 * s) * 8;
      async16(wh + abase + k0 + cc * 8, &sA[pb][lb]);
      async16(xh + bbase + k0 + cc * 8, &sB[pb][lb]);
    }
  };
  stage(0, 0);
  int p = 0;
  for (int k0 = 0; k0 < 1024; k0 += 32) {
    __syncthreads();
    if (k0 + 32 < 1024) stage(k0 + 32, p ^ 1);
    f16x8 fa[4], fb[4];
#pragma unroll
    for (int mi = 0; mi < 4; ++mi)
      fa[mi] = *(const f16x8*)&sA[p][(quad * 128 + wm + mi * 16 + mrow) * 8];
#pragma unroll
    for (int ni = 0; ni < 4; ++ni)
      fb[ni] = *(const f16x8*)&sB[p][(quad * 128 + wn + ni * 16 + mrow) * 8];
#pragma unroll
    for (int mi = 0; mi < 4; ++mi)
#pragma unroll
      for (int ni = 0; ni < 4; ++ni)
        acc[mi][ni] = __builtin_amdgcn_mfma_f32_16x16x32_f16(fa[mi], fb[ni], acc[mi][ni], 0, 0, 0);
    p ^= 1;
  }
  const float inv = 1.0f / 4096.0f;
#pragma unroll
  for (int mi = 0; mi < 4; ++mi) {
#pragma unroll
    for (int rg = 0; rg < 4; ++rg) {
      int c = cb + wm + mi * 16 + quad * 4 + rg;
      float bv = bC[c];
#pragma unroll
      for (int ni = 0; ni < 4; ++ni) {
        int j = nb + wn + ni * 16 + mrow;
        vH[((size_t)b * 1024 + c) * NPIX + j] =
            (f16)(16.f * (acc[mi][ni][rg] * inv + bv));
      }
    }
  }
}

// ---------------- MFMA attention out-GEMM (counted-vmcnt pipeline) ---------

__global__ __launch_bounds__(256, 2) void rf_attm(
    const f16* __restrict__ vH,
    const float* __restrict__ Aarr, const float* __restrict__ Marr,
    const float* __restrict__ iZ, const float* __restrict__ in,
    const float* __restrict__ gptr, f16* __restrict__ yH) {
  __shared__ f16 sAh[3][8192];   // [buf][jgrp4][c256][8]  16KB each
  __shared__ f16 sPh[2][4096];   // [buf][kc4][i128][8]     8KB each
  __shared__ float fl[4096];     // f row, 16KB
  const int tid = threadIdx.x;
  const int ib = blockIdx.x * 128, cb = blockIdx.y * 256, b = blockIdx.z;
  const int wv = tid >> 6, lane = tid & 63;
  const int mrow = lane & 15, quad = lane >> 4;
  const int wm = wv * 64;                 // wave's 64-c slice of 256
  const int ni_ = tid & 127;
  const int kc0 = tid >> 7;               // 0..1
  const float av2 = Aarr[b * NPIX + ib + ni_] * 1.44269504f;
  const float mv2 = Marr[b * NPIX + ib + ni_] * 1.44269504f;
  const float* f = in + ((size_t)b * 1025 + 1024) * NPIX;
  const f16* vrow = vH + ((size_t)b * 1024 + cb + tid) * NPIX;

  f32x4 acc[4][8];
#pragma unroll
  for (int i = 0; i < 4; ++i)
#pragma unroll
    for (int j = 0; j < 8; ++j) acc[i][j] = (f32x4){0.f, 0.f, 0.f, 0.f};

  auto stage = [&](int j0, int pb) {
#pragma unroll
    for (int s = 0; s < 4; ++s)
      async16(vrow + j0 + s * 8, &sAh[pb][(s * 256 + tid) * 8]);
  };
  auto doP = [&](int j0, int pb) {
#pragma unroll
    for (int it = 0; it < 2; ++it) {
      const int kc = kc0 + 2 * it;
      const float4 fa4 = *(const float4*)&fl[j0 + kc * 8];
      const float4 fb4 = *(const float4*)&fl[j0 + kc * 8 + 4];
      const float fj[8] = {fa4.x, fa4.y, fa4.z, fa4.w, fb4.x, fb4.y, fb4.z, fb4.w};
      f16x8 ph;
#pragma unroll
      for (int q = 0; q < 8; ++q)
        ph[q] = (f16)exp2f(fmaf(av2, fj[q], -mv2));
      *(f16x8*)&sPh[pb][(kc * 128 + ni_) * 8] = ph;
    }
  };

  // prologue: f row -> LDS, A0, then P0 while A1 flies
#pragma unroll
  for (int s = 0; s < 4; ++s)
    async16(f + (tid + 256 * s) * 4, &fl[((tid & ~63) + 256 * s) * 4]);
  stage(0, 0);
  asm volatile("s_waitcnt vmcnt(0)" ::: "memory");
  __builtin_amdgcn_s_barrier();
  doP(0, 0);
  stage(32, 1);
  asm volatile("s_waitcnt lgkmcnt(0)" ::: "memory");
  __builtin_amdgcn_s_barrier();

  for (int k = 0; k < 126; ++k) {
    const int pa = k % 3;
    const int pp = k & 1;
    f16x8 fa[4], fb[8];
#pragma unroll
    for (int mi = 0; mi < 4; ++mi)
      fa[mi] = *(const f16x8*)&sAh[pa][(quad * 256 + wm + mi * 16 + mrow) * 8];
#pragma unroll
    for (int ni = 0; ni < 8; ++ni)
      fb[ni] = *(const f16x8*)&sPh[pp][(quad * 128 + ni * 16 + mrow) * 8];
    stage((k + 2) * 32, (k + 2) % 3);   // lands by end of step k+1
    doP((k + 1) * 32, pp ^ 1);          // lgkm-only, overlaps MFMA
#pragma unroll
    for (int mi = 0; mi < 4; ++mi)
#pragma unroll
      for (int ni = 0; ni < 8; ++ni)
        acc[mi][ni] = __builtin_amdgcn_mfma_f32_16x16x32_f16(fa[mi], fb[ni], acc[mi][ni], 0, 0, 0);
    asm volatile("s_waitcnt vmcnt(4) lgkmcnt(0)" ::: "memory");
    __builtin_amdgcn_s_barrier();
  }
  {  // k = 126: pa=0, pp=0; last doP, drain all DMAs
    f16x8 fa[4], fb[8];
#pragma unroll
    for (int mi = 0; mi < 4; ++mi)
      fa[mi] = *(const f16x8*)&sAh[0][(quad * 256 + wm + mi * 16 + mrow) * 8];
#pragma unroll
    for (int ni = 0; ni < 8; ++ni)
      fb[ni] = *(const f16x8*)&sPh[0][(quad * 128 + ni * 16 + mrow) * 8];
    doP(127 * 32, 1);
#pragma unroll
    for (int mi = 0; mi < 4; ++mi)
#pragma unroll
      for (int ni = 0; ni < 8; ++ni)
        acc[mi][ni] = __builtin_amdgcn_mfma_f32_16x16x32_f16(fa[mi], fb[ni], acc[mi][ni], 0, 0, 0);
    asm volatile("s_waitcnt vmcnt(0) lgkmcnt(0)" ::: "memory");
    __builtin_amdgcn_s_barrier();
  }
  {  // k = 127: pa=1, pp=1
    f16x8 fa[4], fb[8];
#pragma unroll
    for (int mi = 0; mi < 4; ++mi)
      fa[mi] = *(const f16x8*)&sAh[1][(quad * 256 + wm + mi * 16 + mrow) * 8];
#pragma unroll
    for (int ni = 0; ni < 8; ++ni)
      fb[ni] = *(const f16x8*)&sPh[1][(quad * 128 + ni * 16 + mrow) * 8];
#pragma unroll
    for (int mi = 0; mi < 4; ++mi)
#pragma unroll
      for (int ni = 0; ni < 8; ++ni)
        acc[mi][ni] = __builtin_amdgcn_mfma_f32_16x16x32_f16(fa[mi], fb[ni], acc[mi][ni], 0, 0, 0);
  }

  const float g = gptr[0];
  const float inv16 = 1.0f / 16.0f;
  float zvi[8];
#pragma unroll
  for (int ni = 0; ni < 8; ++ni)
    zvi[ni] = iZ[b * NPIX + ib + ni * 16 + mrow] * inv16;
#pragma unroll
  for (int mi = 0; mi < 4; ++mi) {
    const int cbase = cb + wm + mi * 16 + quad * 4;
#pragma unroll
    for (int ni = 0; ni < 8; ++ni) {
      const int i = ib + ni * 16 + mrow;
      f16x4 hv;
#pragma unroll
      for (int rg = 0; rg < 4; ++rg) {
        float xr = in[((size_t)b * 1025 + cbase + rg) * NPIX + i];
        hv[rg] = (f16)(16.f * (g * (acc[mi][ni][rg] * zvi[ni]) + xr));
      }
      *(f16x4*)&yH[((size_t)b * NPIX + i) * 1024 + cbase] = hv;
    }
  }
}

// ---------------- conv weight prep: [CO][CI][3][3] -> MFMA-fragment order --

__global__ void rf_wfragc(const float* __restrict__ w, f16* __restrict__ F,
                          int CI, int CO) {
  int gid = blockIdx.x * 256 + threadIdx.x;
  const int C16 = CO >> 4, KI = CI >> 5;
  const int total = 9 * KI * C16 * 64;
  if (gid >= total) return;
  int lane = gid & 63;
  int rest = gid >> 6;
  int c16 = rest % C16;
  int rest2 = rest / C16;
  int k = rest2 % KI;
  int t = rest2 / KI;
  int co = c16 * 16 + (lane & 15);
  int ci = k * 32 + (lane >> 4) * 8;
  f16x8 hb;
#pragma unroll
  for (int j = 0; j < 8; ++j)
    hb[j] = (f16)(256.0f * w[((size_t)co * CI + ci + j) * 9 + t]);
  *(f16x8*)&F[(size_t)gid * 8] = hb;
}

// ---------------- MFMA dilated 3x3 conv (halo dbuf A, prefetched reg B) ----
// Flat grid, XCD swizzle: co-slice pinned to an XCD group (weights stay
// L2-resident).  stageA issued AFTER all fb issues (VMEM retires in order:
// fb waits must not queue behind A DMAs).  fb double-buffered 1 tap ahead;
// k-loop unrolled x2 so buffer parity is compile-time (KI always even).

template <int BM, int BN, bool F32OUT>
__global__ __launch_bounds__(256, 2) void rf_mconv(
    const f16* __restrict__ xh, const f16* __restrict__ F,
    const float* __restrict__ bias, const float* __restrict__ zp,
    f16* __restrict__ oh, float* __restrict__ of, int CI, int CO, int NCB) {
  constexpr int ROWS = BM / 64;
  constexpr int TPI = 4096 / BM;
  constexpr int HROWS = ROWS + 4;               // +-2 row halo
  constexpr int COLP = 72;                      // 68 used + pad to 72
  constexpr int CHUNKS = HROWS * 4 * COLP;      // 16B chunks in halo tile
  constexpr int NSTG = (CHUNKS + 255) / 256;    // A stage instrs per thread
  __shared__ f16 sA[2][NSTG * 2048];
  const int tid = threadIdx.x;
  // XCD swizzle: bid%8 ~ XCD; R8 = XCDs per co-slice
  const int bid = blockIdx.x;
  const int R8 = 8 / NCB;
  const int xcd = bid & 7;
  const int cobi = xcd / R8;
  const int pxi = (bid >> 3) * R8 + (xcd % R8);
  const int cob = cobi * BN;
  const int b = pxi / TPI;
  const int h0 = (pxi - b * TPI) * ROWS;

  const int wv = tid >> 6, lane = tid & 63;
  const int mrow = lane & 15, quad = lane >> 4;
  const int wm = (BN == 128) ? (wv & 1) * 64 : wv * 64;
  const int wn = (BN == 128) ? (wv >> 1) * 64 : 0;
  const int r_out = wm >> 6;
  const int KI = CI >> 5;
  const int C16 = CO >> 4;
  const int cb16 = (cob + wn) >> 4;

  f32x4 acc[4][4];
#pragma unroll
  for (int i = 0; i < 4; ++i)
#pragma unroll
    for (int j = 0; j < 4; ++j) acc[i][j] = (f32x4){0.f, 0.f, 0.f, 0.f};

  // per-lane A staging sources (affine in k: +k*32 f16 when valid)
  const f16* abase[NSTG];
  unsigned vmask = 0;
#pragma unroll
  for (int s = 0; s < NSTG; ++s) {
    int idx = tid + 256 * s;
    int rowks = idx / COLP;
    int col = idx - rowks * COLP;
    int r = rowks >> 2, ks = rowks & 3;
    int srow = h0 + r - 2, scol = col - 2;
    bool ok = (idx < CHUNKS) && ((unsigned)srow < 64u) && ((unsigned)scol < 64u);
    abase[s] = ok ? xh + (((size_t)b * 64 + srow) * 64 + scol) * CI + ks * 8
                  : (const f16*)zp;
    if (ok) vmask |= (1u << s);
  }
  auto stageA = [&](int k, int pb) {
#pragma unroll
    for (int s = 0; s < NSTG; ++s) {
      const f16* sp = abase[s] + (((vmask >> s) & 1u) ? k * 32 : 0);
      async16(sp, &sA[pb][((tid & ~63) + 256 * s) * 8]);
    }
  };

  // per-lane B fragment base (fragment-ordered F)
  const f16* Fb = F + ((size_t)cb16 * 64 + lane) * 8;
  auto loadFB = [&](f16x8* dst, int t, int k) {
#pragma unroll
    for (int ni = 0; ni < 4; ++ni)
      dst[ni] = *(const f16x8*)(Fb + ((size_t)(t * KI + k) * C16 + ni) * 512);
  };

  stageA(0, 0);
  f16x8 fb0[4], fb1[4];
  loadFB(fb0, 0, 0);

  for (int k2 = 0; k2 < KI; k2 += 2) {
#pragma unroll
    for (int dk = 0; dk < 2; ++dk) {
      const int k = k2 + dk;
      __syncthreads();                  // A(k) drained & visible
#pragma unroll
      for (int t = 0; t < 9; ++t) {
        const int par = (t + dk) & 1;   // compile-time buffer parity
        f16x8* cur = par ? fb1 : fb0;
        f16x8* nxt = par ? fb0 : fb1;
        if (t < 8) loadFB(nxt, t + 1, k);
        else if (k + 1 < KI) loadFB(nxt, 0, k + 1);
        const int dh = (t / 3) * 2 - 2, dw = (t - (t / 3) * 3) * 2 - 2;
        f16x8 fa[4];
#pragma unroll
        for (int mi = 0; mi < 4; ++mi)
          fa[mi] = *(const f16x8*)&sA[dk][(((r_out + dh + 2) * 4 + quad) * COLP +
                                          mi * 16 + mrow + dw + 2) * 8];
#pragma unroll
        for (int mi = 0; mi < 4; ++mi)
#pragma unroll
          for (int ni = 0; ni < 4; ++ni)
            acc[mi][ni] = __builtin_amdgcn_mfma_f32_16x16x32_f16(fa[mi], cur[ni], acc[mi][ni], 0, 0, 0);
      }
      if (k + 1 < KI) stageA(k + 1, dk ^ 1);  // AFTER fb issues: fb never queues behind A
    }
  }

  const float inv = 1.0f / 4096.0f;
  float bvs[4];
#pragma unroll
  for (int ni = 0; ni < 4; ++ni) bvs[ni] = bias[cob + wn + ni * 16 + mrow];
#pragma unroll
  for (int mi = 0; mi < 4; ++mi) {
#pragma unroll
    for (int rg = 0; rg < 4; ++rg) {
      int px = wm + mi * 16 + quad * 4 + rg;
      int hh = h0 + (px >> 6), wwp = px & 63;
#pragma unroll
      for (int ni = 0; ni < 4; ++ni) {
        int co = cob + wn + ni * 16 + mrow;
        float vv = fmaxf(acc[mi][ni][rg] * inv + bvs[ni], 0.f);
        if (F32OUT) {
          of[(((size_t)b * CO + co) * 64 + hh) * 64 + wwp] = vv;
        } else {
          oh[(((size_t)b * 64 + hh) * 64 + wwp) * CO + co] = (f16)(vv * 16.f);
        }
      }
    }
  }
}

// ---------------- scan weight frag prep: w[64][64][9] -> frag order ---------

__global__ void rf_wfrag(const float* __restrict__ w, f16* __restrict__ fh) {
  int gid = blockIdx.x * 256 + threadIdx.x;
  if (gid >= 4608) return;
  int lane = gid & 63;
  int rem = gid >> 6;
  int kc = rem & 1;
  int rem2 = rem >> 1;
  int t = rem2 % 9;
  int w4 = rem2 / 9;
  int co = w4 * 16 + (lane & 15);
  int cib = kc * 32 + (lane >> 4) * 8;
  f16x8 hb;
#pragma unroll
  for (int j = 0; j < 8; ++j)
    hb[j] = (f16)(256.f * w[((size_t)co * 64 + cib + j) * 9 + t]);
  *(f16x8*)&fh[(size_t)gid * 8] = hb;
}

// ---------------- MFMA recurrent scan (single fp16 carry) ------------------

__global__ __launch_bounds__(256, 1) void rf_mscan(
    const float* __restrict__ src, float* __restrict__ dst,
    const f16* __restrict__ fh, const float* __restrict__ bias, int dir) {
  __shared__ f16 ch[72 * 64];
  const int b = blockIdx.x;
  const int tid = threadIdx.x;
  const int wave = tid >> 6, lane = tid & 63;
  const int quad = lane >> 4, l15 = lane & 15;

  f16x8 Ah[9][2];
#pragma unroll
  for (int t = 0; t < 9; ++t)
#pragma unroll
    for (int kc = 0; kc < 2; ++kc)
      Ah[t][kc] = *(const f16x8*)&fh[(((wave * 9 + t) * 2 + kc) * 64 + lane) * 8];
  float bvs[4];
#pragma unroll
  for (int r = 0; r < 4; ++r) bvs[r] = bias[wave * 16 + quad * 4 + r];

  for (int s = tid; s < 2304; s += 256) ((unsigned*)ch)[s] = 0u;
  __syncthreads();

  const size_t sbase = (size_t)b * 64 * 4096;
  const int row0 = (dir > 0) ? 0 : 63;
  {
    int pos0 = tid & 63, cig = tid >> 6;
#pragma unroll
    for (int q = 0; q < 16; ++q) {
      int ci = cig * 16 + q;
      float v = src[sbase + (size_t)ci * 4096 + row0 * 64 + pos0];
      dst[sbase + (size_t)ci * 4096 + row0 * 64 + pos0] = v;
      int rowIdx = pos0 + 4;
      ch[rowIdx * 64 + (((ci >> 3) ^ (rowIdx & 7)) << 3) + (ci & 7)] = (f16)v;
    }
  }
  __syncthreads();

  const float inv = 1.0f / 256.0f;
  for (int s = 1; s < 64; ++s) {
    const int row = (dir > 0) ? s : 63 - s;
    float srow[4][4];
#pragma unroll
    for (int nt = 0; nt < 4; ++nt)
#pragma unroll
      for (int r = 0; r < 4; ++r)
        srow[nt][r] = src[sbase + (size_t)(wave * 16 + quad * 4 + r) * 4096 +
                          row * 64 + nt * 16 + l15];
    f32x4 acc[4];
#pragma unroll
    for (int nt = 0; nt < 4; ++nt) acc[nt] = (f32x4){0.f, 0.f, 0.f, 0.f};
#pragma unroll
    for (int t = 0; t < 9; ++t)
#pragma unroll
      for (int kc = 0; kc < 2; ++kc) {
#pragma unroll
        for (int nt = 0; nt < 4; ++nt) {
          int rowIdx = nt * 16 + l15 + t;
          int gr = kc * 4 + quad;
          f16x8 Bh = *(const f16x8*)&ch[rowIdx * 64 + ((gr ^ (rowIdx & 7)) << 3)];
          acc[nt] = __builtin_amdgcn_mfma_f32_16x16x32_f16(Ah[t][kc], Bh, acc[nt], 0, 0, 0);
        }
      }
    __syncthreads();
#pragma unroll
    for (int nt = 0; nt < 4; ++nt) {
      int pos = nt * 16 + l15;
      int rowIdx = pos + 4;
      f16x4 hv;
#pragma unroll
      for (int r = 0; r < 4; ++r) {
        float v = fmaxf(acc[nt][r] * inv + bvs[r], 0.f) + srow[nt][r];
        dst[sbase + (size_t)(wave * 16 + quad * 4 + r) * 4096 + row * 64 + pos] = v;
        hv[r] = (f16)v;
      }
      int ci0 = wave * 16 + quad * 4;
      *(f16x4*)&ch[rowIdx * 64 + (((ci0 >> 3) ^ (rowIdx & 7)) << 3) + (ci0 & 7)] = hv;
    }
    __syncthreads();
  }
}

// ---------------- transpose last two dims (64x64) per (b,c) ----------------

__global__ void rf_transpose(const float* __restrict__ src, float* __restrict__ dst) {
  int bc = blockIdx.x;  // 256
  __shared__ float tl[64][65];
  int tid = threadIdx.x;
  const float* sp = src + (size_t)bc * 4096;
  float* dp = dst + (size_t)bc * 4096;
  for (int s = tid; s < 4096; s += 256) {
    int h = s >> 6, w = s & 63;
    tl[w][h] = sp[s];
  }
  __syncthreads();
  for (int s = tid; s < 4096; s += 256) dp[s] = tl[s >> 6][s & 63];
}

// ---------------- final 1x1 conv + relu + 8x8 upsample ----------------

__global__ void rf_final(const float* __restrict__ t, const float* __restrict__ ow,
                         const float* __restrict__ ob, float* __restrict__ out) {
  int b = blockIdx.y;
  int s = blockIdx.x * 256 + threadIdx.x;  // 0..4095
  int w = s >> 6, h = s & 63;
  float acc = ob[0];
  for (int c = 0; c < 64; ++c)
    acc += ow[c] * t[(((size_t)b * 64 + c) * 64 + w) * 64 + h];
  acc = fmaxf(acc, 0.f);
  float4 vv = make_float4(acc, acc, acc, acc);
  for (int dy = 0; dy < 8; ++dy) {
    float* dp = out + ((size_t)b * 512 + h * 8 + dy) * 512 + w * 8;
    *(float4*)dp = vv;
    *(float4*)(dp + 4) = vv;
  }
}

// ---------------- launch ----------------

extern "C" void kernel_launch(void* const* d_in, const int* in_sizes, int n_in,
                              void* d_out, int out_size, void* d_ws, size_t ws_size,
                              hipStream_t stream) {
  const float* in    = (const float*)d_in[0];
  const float* wA    = (const float*)d_in[1];
  const float* bA    = (const float*)d_in[2];
  const float* wB    = (const float*)d_in[3];
  const float* wC    = (const float*)d_in[5];
  const float* bC    = (const float*)d_in[6];
  const float* gamma = (const float*)d_in[7];
  const float* bw1 = (const float*)d_in[8];  const float* bb1 = (const float*)d_in[9];
  const float* bw2 = (const float*)d_in[10]; const float* bb2 = (const float*)d_in[11];
  const float* bw3 = (const float*)d_in[12]; const float* bb3 = (const float*)d_in[13];
  const float* bw4 = (const float*)d_in[14]; const float* bb4 = (const float*)d_in[15];
  const float* bw5 = (const float*)d_in[16]; const float* bb5 = (const float*)d_in[17];
  const float* bw6 = (const float*)d_in[18]; const float* bb6 = (const float*)d_in[19];
  const float* du_w = (const float*)d_in[20]; const float* du_b = (const float*)d_in[21];
  const float* lr_w = (const float*)d_in[22]; const float* lr_b = (const float*)d_in[23];
  const float* ow   = (const float*)d_in[24]; const float* ob   = (const float*)d_in[25];
  float* out = (float*)d_out;
  float* ws = (float*)d_ws;

  // phase-1 (attention) buffers; offsets in f32 slots (f16 elems = 2x)
  f16* vH  = (f16*)(ws + 0);          // 16.8M f16 -> [0, 4194304)
  f16* xTh = (f16*)(ws + 4194304);    // [4194304, 8388608)
  f16* wCh = (f16*)(ws + 8388608);    // [8388608, 8912896)
  f16* yH  = (f16*)(ws + 16777216);   // [16777216, 20971520)
  // conv phase (F buffers = same sizes as old wsingle buffers)
  f16* w1h = (f16*)(ws + 0);          // [0, 2359296)
  f16* c1H = (f16*)(ws + 2359296);    // [2359296, 6553600)
  f16* w3h = (f16*)(ws + 6553600);    // [6553600, 7733248)
  f16* w2h = (f16*)(ws + 16777216);   // [16777216, 17956864)  (yH dead)
  f16* c2H = (f16*)(ws + 17956864);   // [17956864, 22151168)
  f16* w4h = (f16*)(ws + 22151168);   // [22151168, 22740992)
  f16* c4H = (f16*)(ws + 22740992);   // [22740992, 24838144)
  f16* c3H = c1H;
  f16* w5h = (f16*)(ws + 0);          // [0, 147456)       (w1 dead)
  f16* c5H = (f16*)(ws + 147456);     // [147456, 1196032)
  f16* w6h = (f16*)(ws + 1196032);    // [1196032, 1232896)
  float* tin = ws + 1232896;          // [1232896, 2281472)
  float* t0  = ws + 2281472;          // [2281472, 3330048)
  float* t1  = ws + 3330048;          // [3330048, 4378624)
  f16* duFh = (f16*)(ws + 4378624);   // [4378624, 4397056)  (c1/c3 dead)
  f16* lrFh = (f16*)(ws + 4397056);   // [4397056, 4415488)
  float* sm = ws + 33554432;
  float* A_  = sm;
  float* M_  = sm + 16384;
  float* iZ  = sm + 32768;
  float* u_  = sm + 49152;
  float* s_  = sm + 50176;
  float* c0_ = sm + 50304;
  float* fst = sm + 50308;
  float* zp  = sm + 50432;  // 64-float zero page for OOB DMA lanes

  rf_zero<<<1, 64, 0, stream>>>(zp);
  rf_s<<<1, 128, 0, stream>>>(wB, bA, s_, c0_);
  rf_u<<<4, 256, 0, stream>>>(wA, s_, u_);
  rf_fstat<<<4, 256, 0, stream>>>(in, fst);
  rf_A<<<dim3(16, 4), 256, 0, stream>>>(in, u_, c0_, fst, A_, M_);
  rf_Z<<<4096, 256, 0, stream>>>(in, A_, M_, iZ);
  rf_xsplit<<<dim3(64, 16, 4), 256, 0, stream>>>(in, xTh);
  rf_wC1<<<512, 256, 0, stream>>>(wC, wCh);
  rf_vgemmm<<<dim3(32, 8, 4), 256, 0, stream>>>(wCh, xTh, bC, vH);
  rf_attm<<<dim3(32, 4, 4), 256, 0, stream>>>(vH, A_, M_, iZ, in, gamma, yH);

  // fragment-ordered conv weights (sizes identical to old wsingle buffers)
  rf_wfragc<<<2304, 256, 0, stream>>>(bw1, w1h, 1024, 512);
  rf_wfragc<<<1152, 256, 0, stream>>>(bw3, w3h, 512, 512);
  rf_mconv<128, 128, false><<<512, 256, 0, stream>>>(
      yH, w1h, bb1, zp, c1H, nullptr, 1024, 512, 4);
  rf_wfragc<<<1152, 256, 0, stream>>>(bw2, w2h, 512, 512);
  rf_wfragc<<<576, 256, 0, stream>>>(bw4, w4h, 512, 256);
  rf_wfragc<<<144, 256, 0, stream>>>(bw5, w5h, 256, 128);
  rf_wfragc<<<36, 256, 0, stream>>>(bw6, w6h, 128, 64);
  rf_mconv<128, 128, false><<<512, 256, 0, stream>>>(
      c1H, w2h, bb2, zp, c2H, nullptr, 512, 512, 4);
  rf_mconv<128, 128, false><<<512, 256, 0, stream>>>(
      c2H, w3h, bb3, zp, c3H, nullptr, 512, 512, 4);
  rf_mconv<128, 128, false><<<256, 256, 0, stream>>>(
      c3H, w4h, bb4, zp, c4H, nullptr, 512, 256, 2);
  rf_wfrag<<<18, 256, 0, stream>>>(du_w, duFh);
  rf_wfrag<<<18, 256, 0, stream>>>(lr_w, lrFh);
  rf_mconv<128, 128, false><<<128, 256, 0, stream>>>(
      c4H, w5h, bb5, zp, c5H, nullptr, 256, 128, 1);
  rf_mconv<256, 64, true><<<64, 256, 0, stream>>>(
      c5H, w6h, bb6, zp, nullptr, tin, 128, 64, 1);

  rf_mscan<<<4, 256, 0, stream>>>(tin, t0, duFh, du_b, +1);
  rf_mscan<<<4, 256, 0, stream>>>(t0, t1, duFh, du_b, -1);
  rf_transpose<<<256, 256, 0, stream>>>(t1, t0);
  rf_mscan<<<4, 256, 0, stream>>>(t0, t1, lrFh, lr_b, +1);
  rf_mscan<<<4, 256, 0, stream>>>(t1, t0, lrFh, lr_b, -1);
  rf_final<<<dim3(16, 4), 256, 0, stream>>>(t0, ow, ob, out);
}

// Round 7
// 1556.414 us; speedup vs baseline: 1.2860x; 1.0792x over previous
//
#include <hip/hip_runtime.h>

// resFAN round 13 (R6 this session): coalesced DMA layouts.
// R5 post-mortem: ordering/prefetch/swizzle all neutral, FETCH up.  Real
// bottleneck theory: L2 data-path waste.  stageA's lane stride is CI*2B=2KB
// (scattered) -> each 1KB DMA touches 64 cache lines (~8x overfetch on
// ~450MB A traffic); same pathology in attm vH staging (stride 8KB; 165MB
// FETCH vs 35MB ideal) and vgemm wh/xTh staging (2KB).  Fix: channel-group-8
// layouts so lanes read consecutive 16B: xTh/wCh [kg][.][8], vH [b][jg][c][8],
// yH/convs [b][cg][px][8].  Pure address permutation - LDS content, fragments
// and math unchanged.  XCD swizzle reverted (R5: +38MB FETCH, 0 time).
//
// Error budget unchanged: fp16 quant 2^-11, scales 16/256.

#define NPIX 4096

typedef _Float16 f16;
typedef _Float16 f16x8 __attribute__((ext_vector_type(8)));
typedef _Float16 f16x4 __attribute__((ext_vector_type(4)));
typedef float f32x4 __attribute__((ext_vector_type(4)));

__device__ inline void async16(const void* g, void* l) {
  __builtin_amdgcn_global_load_lds(
      (const __attribute__((address_space(1))) unsigned int*)g,
      (__attribute__((address_space(3))) unsigned int*)l, 16, 0, 0);
}

// ---------------- small prep kernels ----------------

__global__ void rf_zero(float* __restrict__ z) { z[threadIdx.x] = 0.f; }

__global__ void rf_s(const float* __restrict__ wB, const float* __restrict__ bA,
                     float* __restrict__ s_out, float* __restrict__ c0_out) {
  int c = threadIdx.x;  // 128 threads
  const float* row = wB + (size_t)c * 1024;
  float acc = 0.f;
  for (int i = 0; i < 1024; ++i) acc += row[i];
  s_out[c] = acc;
  __shared__ float sh[128];
  sh[c] = acc * bA[c];
  __syncthreads();
  for (int off = 64; off > 0; off >>= 1) {
    if (c < off) sh[c] += sh[c + off];
    __syncthreads();
  }
  if (c == 0) c0_out[0] = sh[0];
}

__global__ void rf_u(const float* __restrict__ wA, const float* __restrict__ s,
                     float* __restrict__ u) {
  int i = blockIdx.x * 256 + threadIdx.x;  // 1024 total
  float acc = 0.f;
  for (int c = 0; c < 128; ++c) acc += s[c] * wA[(size_t)c * 1024 + i];
  u[i] = acc;
}

__global__ void rf_fstat(const float* __restrict__ in, float* __restrict__ fstat) {
  int b = blockIdx.x;
  int t = threadIdx.x;
  const float* f = in + ((size_t)b * 1025 + 1024) * NPIX;
  float mx = -1e30f, mn = 1e30f;
  for (int j = t; j < NPIX; j += 256) {
    float v = f[j];
    mx = fmaxf(mx, v);
    mn = fminf(mn, v);
  }
  __shared__ float smx[256], smn[256];
  smx[t] = mx; smn[t] = mn;
  __syncthreads();
  for (int off = 128; off > 0; off >>= 1) {
    if (t < off) {
      smx[t] = fmaxf(smx[t], smx[t + off]);
      smn[t] = fminf(smn[t], smn[t + off]);
    }
    __syncthreads();
  }
  if (t == 0) { fstat[b] = smx[0]; fstat[4 + b] = smn[0]; }
}

__global__ __launch_bounds__(256) void rf_A(const float* __restrict__ in,
                                            const float* __restrict__ u,
                                            const float* __restrict__ c0p,
                                            const float* __restrict__ fst,
                                            float* __restrict__ A, float* __restrict__ M) {
  __shared__ float ul[1024];
  int b = blockIdx.y;
  int n = blockIdx.x * 256 + threadIdx.x;
  for (int s = threadIdx.x; s < 1024; s += 256) ul[s] = u[s];
  __syncthreads();
  const float* xp = in + (size_t)b * 1025 * NPIX + n;
  float acc = c0p[0];
#pragma unroll 8
  for (int i = 0; i < 1024; ++i) acc = fmaf(ul[i], xp[(size_t)i * NPIX], acc);
  A[b * NPIX + n] = acc;
  M[b * NPIX + n] = fmaxf(acc * fst[b], acc * fst[4 + b]);
}

__global__ void rf_Z(const float* __restrict__ in, const float* __restrict__ A,
                     const float* __restrict__ M, float* __restrict__ iZ) {
  int idx = blockIdx.x * 4 + (threadIdx.x >> 6);  // (b,n) pair, 16384 total
  int lane = threadIdx.x & 63;
  int b = idx >> 12;
  const float* f = in + ((size_t)b * 1025 + 1024) * NPIX;
  float a = A[idx], m = M[idx];
  float acc = 0.f;
#pragma unroll 4
  for (int it = 0; it < 64; ++it) acc += __expf(a * f[lane + it * 64] - m);
  for (int off = 32; off > 0; off >>= 1) acc += __shfl_down(acc, off, 64);
  if (lane == 0) iZ[idx] = 1.0f / acc;
}

// ------- x transpose: [b][ci][n] f32 -> xTh[b][kg128][n][8] f16, scale 16 --

__global__ void rf_xsplit(const float* __restrict__ in, f16* __restrict__ xh) {
  __shared__ float tl[64][65];
  int nt = blockIdx.x, ct = blockIdx.y, b = blockIdx.z;
  int n0 = nt * 64, c0 = ct * 64;
  int tid = threadIdx.x;
  for (int s = tid; s < 4096; s += 256) {
    int r = s >> 6, c = s & 63;
    tl[r][c] = in[((size_t)b * 1025 + c0 + r) * NPIX + n0 + c];
  }
  __syncthreads();
  for (int s = tid; s < 512; s += 256) {
    int n = s >> 3, g = s & 7;
    f16x8 hb;
#pragma unroll
    for (int q = 0; q < 8; ++q) hb[q] = (f16)(16.f * tl[g * 8 + q][n]);
    size_t o = (((size_t)b * 128 + (c0 >> 3) + g) * 4096 + n0 + n) * 8;
    *(f16x8*)&xh[o] = hb;
  }
}

// ------- wC cast: [1024][1024] f32 -> wCh[ig128][c][8] f16, scale 256 ------

__global__ void rf_wC1(const float* __restrict__ wC, f16* __restrict__ wh) {
  int base = (blockIdx.x * 256 + threadIdx.x) * 8;
  int c = base >> 10, i0 = base & 1023;
  f16x8 hb;
#pragma unroll
  for (int q = 0; q < 8; ++q) hb[q] = (f16)(256.f * wC[base + q]);
  *(f16x8*)&wh[(((size_t)(i0 >> 3)) * 1024 + c) * 8] = hb;
}

// ---------------- MFMA v-GEMM (dbuf, single fp16): v = wC @ x + bC --------
// wh [kg][c][8], xTh [b][kg][n][8]: DMA lanes stride 16B (coalesced).
// Output vH [b][jg512][c][8].

__global__ __launch_bounds__(256, 2) void rf_vgemmm(
    const f16* __restrict__ wh, const f16* __restrict__ xh,
    const float* __restrict__ bC, f16* __restrict__ vH) {
  __shared__ f16 sA[2][4096], sB[2][4096];
  const int tid = threadIdx.x;
  const int nb = blockIdx.x * 128, cb = blockIdx.y * 128, b = blockIdx.z;
  const int pA = tid & 127;
  const int wv = tid >> 6, lane = tid & 63;
  const int mrow = lane & 15, quad = lane >> 4;
  const int wm = (wv & 1) * 64, wn = (wv >> 1) * 64;
  f32x4 acc[4][4];
#pragma unroll
  for (int i = 0; i < 4; ++i)
#pragma unroll
    for (int j = 0; j < 4; ++j) acc[i][j] = (f32x4){0.f, 0.f, 0.f, 0.f};

  auto stage = [&](int k0, int pb) {
    const int kg = k0 >> 3;
#pragma unroll
    for (int s = 0; s < 2; ++s) {
      const int cc = ((tid + 256 * s) >> 7) & 3;
      const int lb = ((tid & ~63) + 256 * s) * 8;
      async16(wh + ((size_t)(kg + cc) * 1024 + cb + pA) * 8, &sA[pb][lb]);
      async16(xh + (((size_t)b * 128 + kg + cc) * 4096 + nb + pA) * 8, &sB[pb][lb]);
    }
  };
  stage(0, 0);
  int p = 0;
  for (int k0 = 0; k0 < 1024; k0 += 32) {
    __syncthreads();
    if (k0 + 32 < 1024) stage(k0 + 32, p ^ 1);
    f16x8 fa[4], fb[4];
#pragma unroll
    for (int mi = 0; mi < 4; ++mi)
      fa[mi] = *(const f16x8*)&sA[p][(quad * 128 + wm + mi * 16 + mrow) * 8];
#pragma unroll
    for (int ni = 0; ni < 4; ++ni)
      fb[ni] = *(const f16x8*)&sB[p][(quad * 128 + wn + ni * 16 + mrow) * 8];
#pragma unroll
    for (int mi = 0; mi < 4; ++mi)
#pragma unroll
      for (int ni = 0; ni < 4; ++ni)
        acc[mi][ni] = __builtin_amdgcn_mfma_f32_16x16x32_f16(fa[mi], fb[ni], acc[mi][ni], 0, 0, 0);
    p ^= 1;
  }
  const float inv = 1.0f / 4096.0f;
#pragma unroll
  for (int mi = 0; mi < 4; ++mi) {
#pragma unroll
    for (int rg = 0; rg < 4; ++rg) {
      int c = cb + wm + mi * 16 + quad * 4 + rg;
      float bv = bC[c];
#pragma unroll
      for (int ni = 0; ni < 4; ++ni) {
        int j = nb + wn + ni * 16 + mrow;
        vH[(((size_t)b * 512 + (j >> 3)) * 1024 + c) * 8 + (j & 7)] =
            (f16)(16.f * (acc[mi][ni][rg] * inv + bv));
      }
    }
  }
}

// ---------------- MFMA attention out-GEMM (counted-vmcnt pipeline) ---------
// vH [b][jg][c][8]: DMA lanes stride 16B.  Output yH [b][cg128][n][8].

__global__ __launch_bounds__(256, 2) void rf_attm(
    const f16* __restrict__ vH,
    const float* __restrict__ Aarr, const float* __restrict__ Marr,
    const float* __restrict__ iZ, const float* __restrict__ in,
    const float* __restrict__ gptr, f16* __restrict__ yH) {
  __shared__ f16 sAh[3][8192];   // [buf][jgrp4][c256][8]  16KB each
  __shared__ f16 sPh[2][4096];   // [buf][kc4][i128][8]     8KB each
  __shared__ float fl[4096];     // f row, 16KB
  const int tid = threadIdx.x;
  const int ib = blockIdx.x * 128, cb = blockIdx.y * 256, b = blockIdx.z;
  const int wv = tid >> 6, lane = tid & 63;
  const int mrow = lane & 15, quad = lane >> 4;
  const int wm = wv * 64;                 // wave's 64-c slice of 256
  const int ni_ = tid & 127;
  const int kc0 = tid >> 7;               // 0..1
  const float av2 = Aarr[b * NPIX + ib + ni_] * 1.44269504f;
  const float mv2 = Marr[b * NPIX + ib + ni_] * 1.44269504f;
  const float* f = in + ((size_t)b * 1025 + 1024) * NPIX;
  const f16* vbase = vH + (size_t)b * 4194304 + ((size_t)cb + tid) * 8;

  f32x4 acc[4][8];
#pragma unroll
  for (int i = 0; i < 4; ++i)
#pragma unroll
    for (int j = 0; j < 8; ++j) acc[i][j] = (f32x4){0.f, 0.f, 0.f, 0.f};

  auto stage = [&](int j0, int pb) {
    const int jg = j0 >> 3;
#pragma unroll
    for (int s = 0; s < 4; ++s)
      async16(vbase + (size_t)(jg + s) * 8192, &sAh[pb][(s * 256 + tid) * 8]);
  };
  auto doP = [&](int j0, int pb) {
#pragma unroll
    for (int it = 0; it < 2; ++it) {
      const int kc = kc0 + 2 * it;
      const float4 fa4 = *(const float4*)&fl[j0 + kc * 8];
      const float4 fb4 = *(const float4*)&fl[j0 + kc * 8 + 4];
      const float fj[8] = {fa4.x, fa4.y, fa4.z, fa4.w, fb4.x, fb4.y, fb4.z, fb4.w};
      f16x8 ph;
#pragma unroll
      for (int q = 0; q < 8; ++q)
        ph[q] = (f16)exp2f(fmaf(av2, fj[q], -mv2));
      *(f16x8*)&sPh[pb][(kc * 128 + ni_) * 8] = ph;
    }
  };

  // prologue: f row -> LDS, A0, then P0 while A1 flies
#pragma unroll
  for (int s = 0; s < 4; ++s)
    async16(f + (tid + 256 * s) * 4, &fl[((tid & ~63) + 256 * s) * 4]);
  stage(0, 0);
  asm volatile("s_waitcnt vmcnt(0)" ::: "memory");
  __builtin_amdgcn_s_barrier();
  doP(0, 0);
  stage(32, 1);
  asm volatile("s_waitcnt lgkmcnt(0)" ::: "memory");
  __builtin_amdgcn_s_barrier();

  for (int k = 0; k < 126; ++k) {
    const int pa = k % 3;
    const int pp = k & 1;
    f16x8 fa[4], fb[8];
#pragma unroll
    for (int mi = 0; mi < 4; ++mi)
      fa[mi] = *(const f16x8*)&sAh[pa][(quad * 256 + wm + mi * 16 + mrow) * 8];
#pragma unroll
    for (int ni = 0; ni < 8; ++ni)
      fb[ni] = *(const f16x8*)&sPh[pp][(quad * 128 + ni * 16 + mrow) * 8];
    stage((k + 2) * 32, (k + 2) % 3);   // lands by end of step k+1
    doP((k + 1) * 32, pp ^ 1);          // lgkm-only, overlaps MFMA
#pragma unroll
    for (int mi = 0; mi < 4; ++mi)
#pragma unroll
      for (int ni = 0; ni < 8; ++ni)
        acc[mi][ni] = __builtin_amdgcn_mfma_f32_16x16x32_f16(fa[mi], fb[ni], acc[mi][ni], 0, 0, 0);
    asm volatile("s_waitcnt vmcnt(4) lgkmcnt(0)" ::: "memory");
    __builtin_amdgcn_s_barrier();
  }
  {  // k = 126: pa=0, pp=0; last doP, drain all DMAs
    f16x8 fa[4], fb[8];
#pragma unroll
    for (int mi = 0; mi < 4; ++mi)
      fa[mi] = *(const f16x8*)&sAh[0][(quad * 256 + wm + mi * 16 + mrow) * 8];
#pragma unroll
    for (int ni = 0; ni < 8; ++ni)
      fb[ni] = *(const f16x8*)&sPh[0][(quad * 128 + ni * 16 + mrow) * 8];
    doP(127 * 32, 1);
#pragma unroll
    for (int mi = 0; mi < 4; ++mi)
#pragma unroll
      for (int ni = 0; ni < 8; ++ni)
        acc[mi][ni] = __builtin_amdgcn_mfma_f32_16x16x32_f16(fa[mi], fb[ni], acc[mi][ni], 0, 0, 0);
    asm volatile("s_waitcnt vmcnt(0) lgkmcnt(0)" ::: "memory");
    __builtin_amdgcn_s_barrier();
  }
  {  // k = 127: pa=1, pp=1
    f16x8 fa[4], fb[8];
#pragma unroll
    for (int mi = 0; mi < 4; ++mi)
      fa[mi] = *(const f16x8*)&sAh[1][(quad * 256 + wm + mi * 16 + mrow) * 8];
#pragma unroll
    for (int ni = 0; ni < 8; ++ni)
      fb[ni] = *(const f16x8*)&sPh[1][(quad * 128 + ni * 16 + mrow) * 8];
#pragma unroll
    for (int mi = 0; mi < 4; ++mi)
#pragma unroll
      for (int ni = 0; ni < 8; ++ni)
        acc[mi][ni] = __builtin_amdgcn_mfma_f32_16x16x32_f16(fa[mi], fb[ni], acc[mi][ni], 0, 0, 0);
  }

  const float g = gptr[0];
  const float inv16 = 1.0f / 16.0f;
  float zvi[8];
#pragma unroll
  for (int ni = 0; ni < 8; ++ni)
    zvi[ni] = iZ[b * NPIX + ib + ni * 16 + mrow] * inv16;
#pragma unroll
  for (int mi = 0; mi < 4; ++mi) {
    const int cbase = cb + wm + mi * 16 + quad * 4;
#pragma unroll
    for (int ni = 0; ni < 8; ++ni) {
      const int i = ib + ni * 16 + mrow;
      f16x4 hv;
#pragma unroll
      for (int rg = 0; rg < 4; ++rg) {
        float xr = in[((size_t)b * 1025 + cbase + rg) * NPIX + i];
        hv[rg] = (f16)(16.f * (g * (acc[mi][ni][rg] * zvi[ni]) + xr));
      }
      *(f16x4*)&yH[(((size_t)b * 128 + (cbase >> 3)) * 4096 + i) * 8 + (cbase & 7)] = hv;
    }
  }
}

// ---------------- conv weight prep: [CO][CI][3][3] -> MFMA-fragment order --

__global__ void rf_wfragc(const float* __restrict__ w, f16* __restrict__ F,
                          int CI, int CO) {
  int gid = blockIdx.x * 256 + threadIdx.x;
  const int C16 = CO >> 4, KI = CI >> 5;
  const int total = 9 * KI * C16 * 64;
  if (gid >= total) return;
  int lane = gid & 63;
  int rest = gid >> 6;
  int c16 = rest % C16;
  int rest2 = rest / C16;
  int k = rest2 % KI;
  int t = rest2 / KI;
  int co = c16 * 16 + (lane & 15);
  int ci = k * 32 + (lane >> 4) * 8;
  f16x8 hb;
#pragma unroll
  for (int j = 0; j < 8; ++j)
    hb[j] = (f16)(256.0f * w[((size_t)co * CI + ci + j) * 9 + t]);
  *(f16x8*)&F[(size_t)gid * 8] = hb;
}

// ---------------- MFMA dilated 3x3 conv (halo dbuf A, register B) ----------
// x layout [b][cg CI/8][px 4096][8]: stageA lanes (consecutive col) read
// consecutive 16B -> coalesced DMA (was 2KB stride = 8x granule overfetch).
// Output oh same grouped-8 layout.

template <int BM, int BN, bool F32OUT>
__global__ __launch_bounds__(256, 2) void rf_mconv(
    const f16* __restrict__ xh, const f16* __restrict__ F,
    const float* __restrict__ bias, const float* __restrict__ zp,
    f16* __restrict__ oh, float* __restrict__ of, int CI, int CO) {
  constexpr int ROWS = BM / 64;
  constexpr int TPI = 4096 / BM;
  constexpr int HROWS = ROWS + 4;               // +-2 row halo
  constexpr int COLP = 72;                      // 68 used + pad to 72
  constexpr int CHUNKS = HROWS * 4 * COLP;      // 16B chunks in halo tile
  constexpr int NSTG = (CHUNKS + 255) / 256;    // A stage instrs per thread
  __shared__ f16 sA[2][NSTG * 2048];
  const int tid = threadIdx.x;
  const int blkpx = blockIdx.x;
  const int cob = blockIdx.y * BN;
  const int b = blkpx / TPI;
  const int h0 = (blkpx - b * TPI) * ROWS;

  const int wv = tid >> 6, lane = tid & 63;
  const int mrow = lane & 15, quad = lane >> 4;
  const int wm = (BN == 128) ? (wv & 1) * 64 : wv * 64;
  const int wn = (BN == 128) ? (wv >> 1) * 64 : 0;
  const int r_out = wm >> 6;
  const int KI = CI >> 5;
  const int C16 = CO >> 4;
  const int cb16 = (cob + wn) >> 4;

  f32x4 acc[4][4];
#pragma unroll
  for (int i = 0; i < 4; ++i)
#pragma unroll
    for (int j = 0; j < 4; ++j) acc[i][j] = (f32x4){0.f, 0.f, 0.f, 0.f};

  // per-lane A staging sources; advance per k = 4 groups = 131072 f16
  const f16* abase[NSTG];
  unsigned vmask = 0;
#pragma unroll
  for (int s = 0; s < NSTG; ++s) {
    int idx = tid + 256 * s;
    int rowks = idx / COLP;
    int col = idx - rowks * COLP;
    int r = rowks >> 2, ks = rowks & 3;
    int srow = h0 + r - 2, scol = col - 2;
    bool ok = (idx < CHUNKS) && ((unsigned)srow < 64u) && ((unsigned)scol < 64u);
    abase[s] = ok ? xh + (((size_t)b * (CI >> 3) + ks) * 4096 + srow * 64 + scol) * 8
                  : (const f16*)zp;
    if (ok) vmask |= (1u << s);
  }
  auto stageA = [&](int k, int pb) {
#pragma unroll
    for (int s = 0; s < NSTG; ++s) {
      const f16* sp = abase[s] + (((vmask >> s) & 1u) ? k * 131072 : 0);
      async16(sp, &sA[pb][((tid & ~63) + 256 * s) * 8]);
    }
  };

  // per-lane B fragment base (fragment-ordered F, already coalesced)
  const f16* Fb = F + ((size_t)cb16 * 64 + lane) * 8;
  auto loadFB = [&](f16x8* dst, int t, int k) {
#pragma unroll
    for (int ni = 0; ni < 4; ++ni)
      dst[ni] = *(const f16x8*)(Fb + ((size_t)(t * KI + k) * C16 + ni) * 512);
  };

  stageA(0, 0);
  f16x8 fb0[4], fb1[4];
  loadFB(fb0, 0, 0);

  for (int k2 = 0; k2 < KI; k2 += 2) {
#pragma unroll
    for (int dk = 0; dk < 2; ++dk) {
      const int k = k2 + dk;
      __syncthreads();                  // A(k) drained & visible
#pragma unroll
      for (int t = 0; t < 9; ++t) {
        const int par = (t + dk) & 1;   // compile-time buffer parity
        f16x8* cur = par ? fb1 : fb0;
        f16x8* nxt = par ? fb0 : fb1;
        if (t < 8) loadFB(nxt, t + 1, k);
        else if (k + 1 < KI) loadFB(nxt, 0, k + 1);
        const int dh = (t / 3) * 2 - 2, dw = (t - (t / 3) * 3) * 2 - 2;
        f16x8 fa[4];
#pragma unroll
        for (int mi = 0; mi < 4; ++mi)
          fa[mi] = *(const f16x8*)&sA[dk][(((r_out + dh + 2) * 4 + quad) * COLP +
                                          mi * 16 + mrow + dw + 2) * 8];
#pragma unroll
        for (int mi = 0; mi < 4; ++mi)
#pragma unroll
          for (int ni = 0; ni < 4; ++ni)
            acc[mi][ni] = __builtin_amdgcn_mfma_f32_16x16x32_f16(fa[mi], cur[ni], acc[mi][ni], 0, 0, 0);
      }
      if (k + 1 < KI) stageA(k + 1, dk ^ 1);
    }
  }

  const float inv = 1.0f / 4096.0f;
  float bvs[4];
#pragma unroll
  for (int ni = 0; ni < 4; ++ni) bvs[ni] = bias[cob + wn + ni * 16 + mrow];
#pragma unroll
  for (int mi = 0; mi < 4; ++mi) {
#pragma unroll
    for (int rg = 0; rg < 4; ++rg) {
      int px = wm + mi * 16 + quad * 4 + rg;
      int hh = h0 + (px >> 6), wwp = px & 63;
#pragma unroll
      for (int ni = 0; ni < 4; ++ni) {
        int co = cob + wn + ni * 16 + mrow;
        float vv = fmaxf(acc[mi][ni][rg] * inv + bvs[ni], 0.f);
        if (F32OUT) {
          of[(((size_t)b * CO + co) * 64 + hh) * 64 + wwp] = vv;
        } else {
          oh[(((size_t)b * (CO >> 3) + (co >> 3)) * 4096 + hh * 64 + wwp) * 8 + (co & 7)] =
              (f16)(vv * 16.f);
        }
      }
    }
  }
}

// ---------------- scan weight frag prep: w[64][64][9] -> frag order ---------

__global__ void rf_wfrag(const float* __restrict__ w, f16* __restrict__ fh) {
  int gid = blockIdx.x * 256 + threadIdx.x;
  if (gid >= 4608) return;
  int lane = gid & 63;
  int rem = gid >> 6;
  int kc = rem & 1;
  int rem2 = rem >> 1;
  int t = rem2 % 9;
  int w4 = rem2 / 9;
  int co = w4 * 16 + (lane & 15);
  int cib = kc * 32 + (lane >> 4) * 8;
  f16x8 hb;
#pragma unroll
  for (int j = 0; j < 8; ++j)
    hb[j] = (f16)(256.f * w[((size_t)co * 64 + cib + j) * 9 + t]);
  *(f16x8*)&fh[(size_t)gid * 8] = hb;
}

// ---------------- MFMA recurrent scan (single fp16 carry) ------------------

__global__ __launch_bounds__(256, 1) void rf_mscan(
    const float* __restrict__ src, float* __restrict__ dst,
    const f16* __restrict__ fh, const float* __restrict__ bias, int dir) {
  __shared__ f16 ch[72 * 64];
  const int b = blockIdx.x;
  const int tid = threadIdx.x;
  const int wave = tid >> 6, lane = tid & 63;
  const int quad = lane >> 4, l15 = lane & 15;

  f16x8 Ah[9][2];
#pragma unroll
  for (int t = 0; t < 9; ++t)
#pragma unroll
    for (int kc = 0; kc < 2; ++kc)
      Ah[t][kc] = *(const f16x8*)&fh[(((wave * 9 + t) * 2 + kc) * 64 + lane) * 8];
  float bvs[4];
#pragma unroll
  for (int r = 0; r < 4; ++r) bvs[r] = bias[wave * 16 + quad * 4 + r];

  for (int s = tid; s < 2304; s += 256) ((unsigned*)ch)[s] = 0u;
  __syncthreads();

  const size_t sbase = (size_t)b * 64 * 4096;
  const int row0 = (dir > 0) ? 0 : 63;
  {
    int pos0 = tid & 63, cig = tid >> 6;
#pragma unroll
    for (int q = 0; q < 16; ++q) {
      int ci = cig * 16 + q;
      float v = src[sbase + (size_t)ci * 4096 + row0 * 64 + pos0];
      dst[sbase + (size_t)ci * 4096 + row0 * 64 + pos0] = v;
      int rowIdx = pos0 + 4;
      ch[rowIdx * 64 + (((ci >> 3) ^ (rowIdx & 7)) << 3) + (ci & 7)] = (f16)v;
    }
  }
  __syncthreads();

  const float inv = 1.0f / 256.0f;
  for (int s = 1; s < 64; ++s) {
    const int row = (dir > 0) ? s : 63 - s;
    float srow[4][4];
#pragma unroll
    for (int nt = 0; nt < 4; ++nt)
#pragma unroll
      for (int r = 0; r < 4; ++r)
        srow[nt][r] = src[sbase + (size_t)(wave * 16 + quad * 4 + r) * 4096 +
                          row * 64 + nt * 16 + l15];
    f32x4 acc[4];
#pragma unroll
    for (int nt = 0; nt < 4; ++nt) acc[nt] = (f32x4){0.f, 0.f, 0.f, 0.f};
#pragma unroll
    for (int t = 0; t < 9; ++t)
#pragma unroll
      for (int kc = 0; kc < 2; ++kc) {
#pragma unroll
        for (int nt = 0; nt < 4; ++nt) {
          int rowIdx = nt * 16 + l15 + t;
          int gr = kc * 4 + quad;
          f16x8 Bh = *(const f16x8*)&ch[rowIdx * 64 + ((gr ^ (rowIdx & 7)) << 3)];
          acc[nt] = __builtin_amdgcn_mfma_f32_16x16x32_f16(Ah[t][kc], Bh, acc[nt], 0, 0, 0);
        }
      }
    __syncthreads();
#pragma unroll
    for (int nt = 0; nt < 4; ++nt) {
      int pos = nt * 16 + l15;
      int rowIdx = pos + 4;
      f16x4 hv;
#pragma unroll
      for (int r = 0; r < 4; ++r) {
        float v = fmaxf(acc[nt][r] * inv + bvs[r], 0.f) + srow[nt][r];
        dst[sbase + (size_t)(wave * 16 + quad * 4 + r) * 4096 + row * 64 + pos] = v;
        hv[r] = (f16)v;
      }
      int ci0 = wave * 16 + quad * 4;
      *(f16x4*)&ch[rowIdx * 64 + (((ci0 >> 3) ^ (rowIdx & 7)) << 3) + (ci0 & 7)] = hv;
    }
    __syncthreads();
  }
}

// ---------------- transpose last two dims (64x64) per (b,c) ----------------

__global__ void rf_transpose(const float* __restrict__ src, float* __restrict__ dst) {
  int bc = blockIdx.x;  // 256
  __shared__ float tl[64][65];
  int tid = threadIdx.x;
  const float* sp = src + (size_t)bc * 4096;
  float* dp = dst + (size_t)bc * 4096;
  for (int s = tid; s < 4096; s += 256) {
    int h = s >> 6, w = s & 63;
    tl[w][h] = sp[s];
  }
  __syncthreads();
  for (int s = tid; s < 4096; s += 256) dp[s] = tl[s >> 6][s & 63];
}

// ---------------- final 1x1 conv + relu + 8x8 upsample ----------------

__global__ void rf_final(const float* __restrict__ t, const float* __restrict__ ow,
                         const float* __restrict__ ob, float* __restrict__ out) {
  int b = blockIdx.y;
  int s = blockIdx.x * 256 + threadIdx.x;  // 0..4095
  int w = s >> 6, h = s & 63;
  float acc = ob[0];
  for (int c = 0; c < 64; ++c)
    acc += ow[c] * t[(((size_t)b * 64 + c) * 64 + w) * 64 + h];
  acc = fmaxf(acc, 0.f);
  float4 vv = make_float4(acc, acc, acc, acc);
  for (int dy = 0; dy < 8; ++dy) {
    float* dp = out + ((size_t)b * 512 + h * 8 + dy) * 512 + w * 8;
    *(float4*)dp = vv;
    *(float4*)(dp + 4) = vv;
  }
}

// ---------------- launch ----------------

extern "C" void kernel_launch(void* const* d_in, const int* in_sizes, int n_in,
                              void* d_out, int out_size, void* d_ws, size_t ws_size,
                              hipStream_t stream) {
  const float* in    = (const float*)d_in[0];
  const float* wA    = (const float*)d_in[1];
  const float* bA    = (const float*)d_in[2];
  const float* wB    = (const float*)d_in[3];
  const float* wC    = (const float*)d_in[5];
  const float* bC    = (const float*)d_in[6];
  const float* gamma = (const float*)d_in[7];
  const float* bw1 = (const float*)d_in[8];  const float* bb1 = (const float*)d_in[9];
  const float* bw2 = (const float*)d_in[10]; const float* bb2 = (const float*)d_in[11];
  const float* bw3 = (const float*)d_in[12]; const float* bb3 = (const float*)d_in[13];
  const float* bw4 = (const float*)d_in[14]; const float* bb4 = (const float*)d_in[15];
  const float* bw5 = (const float*)d_in[16]; const float* bb5 = (const float*)d_in[17];
  const float* bw6 = (const float*)d_in[18]; const float* bb6 = (const float*)d_in[19];
  const float* du_w = (const float*)d_in[20]; const float* du_b = (const float*)d_in[21];
  const float* lr_w = (const float*)d_in[22]; const float* lr_b = (const float*)d_in[23];
  const float* ow   = (const float*)d_in[24]; const float* ob   = (const float*)d_in[25];
  float* out = (float*)d_out;
  float* ws = (float*)d_ws;

  // phase-1 (attention) buffers; offsets in f32 slots (f16 elems = 2x)
  f16* vH  = (f16*)(ws + 0);          // 16.8M f16 -> [0, 4194304)
  f16* xTh = (f16*)(ws + 4194304);    // [4194304, 8388608)
  f16* wCh = (f16*)(ws + 8388608);    // [8388608, 8912896)
  f16* yH  = (f16*)(ws + 16777216);   // [16777216, 20971520)
  // conv phase (F buffers = same sizes as old wsingle buffers)
  f16* w1h = (f16*)(ws + 0);          // [0, 2359296)
  f16* c1H = (f16*)(ws + 2359296);    // [2359296, 6553600)
  f16* w3h = (f16*)(ws + 6553600);    // [6553600, 7733248)
  f16* w2h = (f16*)(ws + 16777216);   // [16777216, 17956864)  (yH dead)
  f16* c2H = (f16*)(ws + 17956864);   // [17956864, 22151168)
  f16* w4h = (f16*)(ws + 22151168);   // [22151168, 22740992)
  f16* c4H = (f16*)(ws + 22740992);   // [22740992, 24838144)
  f16* c3H = c1H;
  f16* w5h = (f16*)(ws + 0);          // [0, 147456)       (w1 dead)
  f16* c5H = (f16*)(ws + 147456);     // [147456, 1196032)
  f16* w6h = (f16*)(ws + 1196032);    // [1196032, 1232896)
  float* tin = ws + 1232896;          // [1232896, 2281472)
  float* t0  = ws + 2281472;          // [2281472, 3330048)
  float* t1  = ws + 3330048;          // [3330048, 4378624)
  f16* duFh = (f16*)(ws + 4378624);   // [4378624, 4397056)  (c1/c3 dead)
  f16* lrFh = (f16*)(ws + 4397056);   // [4397056, 4415488)
  float* sm = ws + 33554432;
  float* A_  = sm;
  float* M_  = sm + 16384;
  float* iZ  = sm + 32768;
  float* u_  = sm + 49152;
  float* s_  = sm + 50176;
  float* c0_ = sm + 50304;
  float* fst = sm + 50308;
  float* zp  = sm + 50432;  // 64-float zero page for OOB DMA lanes

  rf_zero<<<1, 64, 0, stream>>>(zp);
  rf_s<<<1, 128, 0, stream>>>(wB, bA, s_, c0_);
  rf_u<<<4, 256, 0, stream>>>(wA, s_, u_);
  rf_fstat<<<4, 256, 0, stream>>>(in, fst);
  rf_A<<<dim3(16, 4), 256, 0, stream>>>(in, u_, c0_, fst, A_, M_);
  rf_Z<<<4096, 256, 0, stream>>>(in, A_, M_, iZ);
  rf_xsplit<<<dim3(64, 16, 4), 256, 0, stream>>>(in, xTh);
  rf_wC1<<<512, 256, 0, stream>>>(wC, wCh);
  rf_vgemmm<<<dim3(32, 8, 4), 256, 0, stream>>>(wCh, xTh, bC, vH);
  rf_attm<<<dim3(32, 4, 4), 256, 0, stream>>>(vH, A_, M_, iZ, in, gamma, yH);

  // fragment-ordered conv weights (sizes identical to old wsingle buffers)
  rf_wfragc<<<2304, 256, 0, stream>>>(bw1, w1h, 1024, 512);
  rf_wfragc<<<1152, 256, 0, stream>>>(bw3, w3h, 512, 512);
  rf_mconv<128, 128, false><<<dim3(128, 4), 256, 0, stream>>>(
      yH, w1h, bb1, zp, c1H, nullptr, 1024, 512);
  rf_wfragc<<<1152, 256, 0, stream>>>(bw2, w2h, 512, 512);
  rf_wfragc<<<576, 256, 0, stream>>>(bw4, w4h, 512, 256);
  rf_wfragc<<<144, 256, 0, stream>>>(bw5, w5h, 256, 128);
  rf_wfragc<<<36, 256, 0, stream>>>(bw6, w6h, 128, 64);
  rf_mconv<128, 128, false><<<dim3(128, 4), 256, 0, stream>>>(
      c1H, w2h, bb2, zp, c2H, nullptr, 512, 512);
  rf_mconv<128, 128, false><<<dim3(128, 4), 256, 0, stream>>>(
      c2H, w3h, bb3, zp, c3H, nullptr, 512, 512);
  rf_mconv<128, 128, false><<<dim3(128, 2), 256, 0, stream>>>(
      c3H, w4h, bb4, zp, c4H, nullptr, 512, 256);
  rf_wfrag<<<18, 256, 0, stream>>>(du_w, duFh);
  rf_wfrag<<<18, 256, 0, stream>>>(lr_w, lrFh);
  rf_mconv<128, 128, false><<<dim3(128, 1), 256, 0, stream>>>(
      c4H, w5h, bb5, zp, c5H, nullptr, 256, 128);
  rf_mconv<256, 64, true><<<dim3(64, 1), 256, 0, stream>>>(
      c5H, w6h, bb6, zp, nullptr, tin, 128, 64);

  rf_mscan<<<4, 256, 0, stream>>>(tin, t0, duFh, du_b, +1);
  rf_mscan<<<4, 256, 0, stream>>>(t0, t1, duFh, du_b, -1);
  rf_transpose<<<256, 256, 0, stream>>>(t1, t0);
  rf_mscan<<<4, 256, 0, stream>>>(t0, t1, lrFh, lr_b, +1);
  rf_mscan<<<4, 256, 0, stream>>>(t1, t0, lrFh, lr_b, -1);
  rf_final<<<dim3(16, 4), 256, 0, stream>>>(t0, ow, ob, out);
}

// Round 8
// 1464.986 us; speedup vs baseline: 1.3663x; 1.0624x over previous
//
#include <hip/hip_runtime.h>

// resFAN round 14 (R7 this session): mscan single-barrier + srow prefetch.
// R6 post-mortem: coalesced layouts -123us (convs off top-5); attm tops at
// 183us.  Budget arithmetic leaves ~500us for the 4 rf_mscan passes: 4 blocks
// on 256 CUs, 64 serial rows x 2 barriers each, with per-row srow global
// reads (200-900cyc) INSIDE the barrier critical path.  Fix: (1) carry row
// double-buffered ch[2][] -> WAR barrier dropped (1 barrier/row); (2) srow(s+1)
// register-prefetched during row s MFMA -> global latency hidden; (3) halo
// zeroed once for both buffers.  attm untouched (next: tile restructure).
//
// Error budget unchanged: fp16 quant 2^-11, scales 16/256.

#define NPIX 4096

typedef _Float16 f16;
typedef _Float16 f16x8 __attribute__((ext_vector_type(8)));
typedef _Float16 f16x4 __attribute__((ext_vector_type(4)));
typedef float f32x4 __attribute__((ext_vector_type(4)));

__device__ inline void async16(const void* g, void* l) {
  __builtin_amdgcn_global_load_lds(
      (const __attribute__((address_space(1))) unsigned int*)g,
      (__attribute__((address_space(3))) unsigned int*)l, 16, 0, 0);
}

// ---------------- small prep kernels ----------------

__global__ void rf_zero(float* __restrict__ z) { z[threadIdx.x] = 0.f; }

__global__ void rf_s(const float* __restrict__ wB, const float* __restrict__ bA,
                     float* __restrict__ s_out, float* __restrict__ c0_out) {
  int c = threadIdx.x;  // 128 threads
  const float* row = wB + (size_t)c * 1024;
  float acc = 0.f;
  for (int i = 0; i < 1024; ++i) acc += row[i];
  s_out[c] = acc;
  __shared__ float sh[128];
  sh[c] = acc * bA[c];
  __syncthreads();
  for (int off = 64; off > 0; off >>= 1) {
    if (c < off) sh[c] += sh[c + off];
    __syncthreads();
  }
  if (c == 0) c0_out[0] = sh[0];
}

__global__ void rf_u(const float* __restrict__ wA, const float* __restrict__ s,
                     float* __restrict__ u) {
  int i = blockIdx.x * 256 + threadIdx.x;  // 1024 total
  float acc = 0.f;
  for (int c = 0; c < 128; ++c) acc += s[c] * wA[(size_t)c * 1024 + i];
  u[i] = acc;
}

__global__ void rf_fstat(const float* __restrict__ in, float* __restrict__ fstat) {
  int b = blockIdx.x;
  int t = threadIdx.x;
  const float* f = in + ((size_t)b * 1025 + 1024) * NPIX;
  float mx = -1e30f, mn = 1e30f;
  for (int j = t; j < NPIX; j += 256) {
    float v = f[j];
    mx = fmaxf(mx, v);
    mn = fminf(mn, v);
  }
  __shared__ float smx[256], smn[256];
  smx[t] = mx; smn[t] = mn;
  __syncthreads();
  for (int off = 128; off > 0; off >>= 1) {
    if (t < off) {
      smx[t] = fmaxf(smx[t], smx[t + off]);
      smn[t] = fminf(smn[t], smn[t + off]);
    }
    __syncthreads();
  }
  if (t == 0) { fstat[b] = smx[0]; fstat[4 + b] = smn[0]; }
}

__global__ __launch_bounds__(256) void rf_A(const float* __restrict__ in,
                                            const float* __restrict__ u,
                                            const float* __restrict__ c0p,
                                            const float* __restrict__ fst,
                                            float* __restrict__ A, float* __restrict__ M) {
  __shared__ float ul[1024];
  int b = blockIdx.y;
  int n = blockIdx.x * 256 + threadIdx.x;
  for (int s = threadIdx.x; s < 1024; s += 256) ul[s] = u[s];
  __syncthreads();
  const float* xp = in + (size_t)b * 1025 * NPIX + n;
  float acc = c0p[0];
#pragma unroll 8
  for (int i = 0; i < 1024; ++i) acc = fmaf(ul[i], xp[(size_t)i * NPIX], acc);
  A[b * NPIX + n] = acc;
  M[b * NPIX + n] = fmaxf(acc * fst[b], acc * fst[4 + b]);
}

__global__ void rf_Z(const float* __restrict__ in, const float* __restrict__ A,
                     const float* __restrict__ M, float* __restrict__ iZ) {
  int idx = blockIdx.x * 4 + (threadIdx.x >> 6);  // (b,n) pair, 16384 total
  int lane = threadIdx.x & 63;
  int b = idx >> 12;
  const float* f = in + ((size_t)b * 1025 + 1024) * NPIX;
  float a = A[idx], m = M[idx];
  float acc = 0.f;
#pragma unroll 4
  for (int it = 0; it < 64; ++it) acc += __expf(a * f[lane + it * 64] - m);
  for (int off = 32; off > 0; off >>= 1) acc += __shfl_down(acc, off, 64);
  if (lane == 0) iZ[idx] = 1.0f / acc;
}

// ------- x transpose: [b][ci][n] f32 -> xTh[b][kg128][n][8] f16, scale 16 --

__global__ void rf_xsplit(const float* __restrict__ in, f16* __restrict__ xh) {
  __shared__ float tl[64][65];
  int nt = blockIdx.x, ct = blockIdx.y, b = blockIdx.z;
  int n0 = nt * 64, c0 = ct * 64;
  int tid = threadIdx.x;
  for (int s = tid; s < 4096; s += 256) {
    int r = s >> 6, c = s & 63;
    tl[r][c] = in[((size_t)b * 1025 + c0 + r) * NPIX + n0 + c];
  }
  __syncthreads();
  for (int s = tid; s < 512; s += 256) {
    int n = s >> 3, g = s & 7;
    f16x8 hb;
#pragma unroll
    for (int q = 0; q < 8; ++q) hb[q] = (f16)(16.f * tl[g * 8 + q][n]);
    size_t o = (((size_t)b * 128 + (c0 >> 3) + g) * 4096 + n0 + n) * 8;
    *(f16x8*)&xh[o] = hb;
  }
}

// ------- wC cast: [1024][1024] f32 -> wCh[ig128][c][8] f16, scale 256 ------

__global__ void rf_wC1(const float* __restrict__ wC, f16* __restrict__ wh) {
  int base = (blockIdx.x * 256 + threadIdx.x) * 8;
  int c = base >> 10, i0 = base & 1023;
  f16x8 hb;
#pragma unroll
  for (int q = 0; q < 8; ++q) hb[q] = (f16)(256.f * wC[base + q]);
  *(f16x8*)&wh[(((size_t)(i0 >> 3)) * 1024 + c) * 8] = hb;
}

// ---------------- MFMA v-GEMM (dbuf, single fp16): v = wC @ x + bC --------

__global__ __launch_bounds__(256, 2) void rf_vgemmm(
    const f16* __restrict__ wh, const f16* __restrict__ xh,
    const float* __restrict__ bC, f16* __restrict__ vH) {
  __shared__ f16 sA[2][4096], sB[2][4096];
  const int tid = threadIdx.x;
  const int nb = blockIdx.x * 128, cb = blockIdx.y * 128, b = blockIdx.z;
  const int pA = tid & 127;
  const int wv = tid >> 6, lane = tid & 63;
  const int mrow = lane & 15, quad = lane >> 4;
  const int wm = (wv & 1) * 64, wn = (wv >> 1) * 64;
  f32x4 acc[4][4];
#pragma unroll
  for (int i = 0; i < 4; ++i)
#pragma unroll
    for (int j = 0; j < 4; ++j) acc[i][j] = (f32x4){0.f, 0.f, 0.f, 0.f};

  auto stage = [&](int k0, int pb) {
    const int kg = k0 >> 3;
#pragma unroll
    for (int s = 0; s < 2; ++s) {
      const int cc = ((tid + 256 * s) >> 7) & 3;
      const int lb = ((tid & ~63) + 256 * s) * 8;
      async16(wh + ((size_t)(kg + cc) * 1024 + cb + pA) * 8, &sA[pb][lb]);
      async16(xh + (((size_t)b * 128 + kg + cc) * 4096 + nb + pA) * 8, &sB[pb][lb]);
    }
  };
  stage(0, 0);
  int p = 0;
  for (int k0 = 0; k0 < 1024; k0 += 32) {
    __syncthreads();
    if (k0 + 32 < 1024) stage(k0 + 32, p ^ 1);
    f16x8 fa[4], fb[4];
#pragma unroll
    for (int mi = 0; mi < 4; ++mi)
      fa[mi] = *(const f16x8*)&sA[p][(quad * 128 + wm + mi * 16 + mrow) * 8];
#pragma unroll
    for (int ni = 0; ni < 4; ++ni)
      fb[ni] = *(const f16x8*)&sB[p][(quad * 128 + wn + ni * 16 + mrow) * 8];
#pragma unroll
    for (int mi = 0; mi < 4; ++mi)
#pragma unroll
      for (int ni = 0; ni < 4; ++ni)
        acc[mi][ni] = __builtin_amdgcn_mfma_f32_16x16x32_f16(fa[mi], fb[ni], acc[mi][ni], 0, 0, 0);
    p ^= 1;
  }
  const float inv = 1.0f / 4096.0f;
#pragma unroll
  for (int mi = 0; mi < 4; ++mi) {
#pragma unroll
    for (int rg = 0; rg < 4; ++rg) {
      int c = cb + wm + mi * 16 + quad * 4 + rg;
      float bv = bC[c];
#pragma unroll
      for (int ni = 0; ni < 4; ++ni) {
        int j = nb + wn + ni * 16 + mrow;
        vH[(((size_t)b * 512 + (j >> 3)) * 1024 + c) * 8 + (j & 7)] =
            (f16)(16.f * (acc[mi][ni][rg] * inv + bv));
      }
    }
  }
}

// ---------------- MFMA attention out-GEMM (counted-vmcnt pipeline) ---------

__global__ __launch_bounds__(256, 2) void rf_attm(
    const f16* __restrict__ vH,
    const float* __restrict__ Aarr, const float* __restrict__ Marr,
    const float* __restrict__ iZ, const float* __restrict__ in,
    const float* __restrict__ gptr, f16* __restrict__ yH) {
  __shared__ f16 sAh[3][8192];   // [buf][jgrp4][c256][8]  16KB each
  __shared__ f16 sPh[2][4096];   // [buf][kc4][i128][8]     8KB each
  __shared__ float fl[4096];     // f row, 16KB
  const int tid = threadIdx.x;
  const int ib = blockIdx.x * 128, cb = blockIdx.y * 256, b = blockIdx.z;
  const int wv = tid >> 6, lane = tid & 63;
  const int mrow = lane & 15, quad = lane >> 4;
  const int wm = wv * 64;                 // wave's 64-c slice of 256
  const int ni_ = tid & 127;
  const int kc0 = tid >> 7;               // 0..1
  const float av2 = Aarr[b * NPIX + ib + ni_] * 1.44269504f;
  const float mv2 = Marr[b * NPIX + ib + ni_] * 1.44269504f;
  const float* f = in + ((size_t)b * 1025 + 1024) * NPIX;
  const f16* vbase = vH + (size_t)b * 4194304 + ((size_t)cb + tid) * 8;

  f32x4 acc[4][8];
#pragma unroll
  for (int i = 0; i < 4; ++i)
#pragma unroll
    for (int j = 0; j < 8; ++j) acc[i][j] = (f32x4){0.f, 0.f, 0.f, 0.f};

  auto stage = [&](int j0, int pb) {
    const int jg = j0 >> 3;
#pragma unroll
    for (int s = 0; s < 4; ++s)
      async16(vbase + (size_t)(jg + s) * 8192, &sAh[pb][(s * 256 + tid) * 8]);
  };
  auto doP = [&](int j0, int pb) {
#pragma unroll
    for (int it = 0; it < 2; ++it) {
      const int kc = kc0 + 2 * it;
      const float4 fa4 = *(const float4*)&fl[j0 + kc * 8];
      const float4 fb4 = *(const float4*)&fl[j0 + kc * 8 + 4];
      const float fj[8] = {fa4.x, fa4.y, fa4.z, fa4.w, fb4.x, fb4.y, fb4.z, fb4.w};
      f16x8 ph;
#pragma unroll
      for (int q = 0; q < 8; ++q)
        ph[q] = (f16)exp2f(fmaf(av2, fj[q], -mv2));
      *(f16x8*)&sPh[pb][(kc * 128 + ni_) * 8] = ph;
    }
  };

  // prologue: f row -> LDS, A0, then P0 while A1 flies
#pragma unroll
  for (int s = 0; s < 4; ++s)
    async16(f + (tid + 256 * s) * 4, &fl[((tid & ~63) + 256 * s) * 4]);
  stage(0, 0);
  asm volatile("s_waitcnt vmcnt(0)" ::: "memory");
  __builtin_amdgcn_s_barrier();
  doP(0, 0);
  stage(32, 1);
  asm volatile("s_waitcnt lgkmcnt(0)" ::: "memory");
  __builtin_amdgcn_s_barrier();

  for (int k = 0; k < 126; ++k) {
    const int pa = k % 3;
    const int pp = k & 1;
    f16x8 fa[4], fb[8];
#pragma unroll
    for (int mi = 0; mi < 4; ++mi)
      fa[mi] = *(const f16x8*)&sAh[pa][(quad * 256 + wm + mi * 16 + mrow) * 8];
#pragma unroll
    for (int ni = 0; ni < 8; ++ni)
      fb[ni] = *(const f16x8*)&sPh[pp][(quad * 128 + ni * 16 + mrow) * 8];
    stage((k + 2) * 32, (k + 2) % 3);   // lands by end of step k+1
    doP((k + 1) * 32, pp ^ 1);          // lgkm-only, overlaps MFMA
#pragma unroll
    for (int mi = 0; mi < 4; ++mi)
#pragma unroll
      for (int ni = 0; ni < 8; ++ni)
        acc[mi][ni] = __builtin_amdgcn_mfma_f32_16x16x32_f16(fa[mi], fb[ni], acc[mi][ni], 0, 0, 0);
    asm volatile("s_waitcnt vmcnt(4) lgkmcnt(0)" ::: "memory");
    __builtin_amdgcn_s_barrier();
  }
  {  // k = 126: pa=0, pp=0; last doP, drain all DMAs
    f16x8 fa[4], fb[8];
#pragma unroll
    for (int mi = 0; mi < 4; ++mi)
      fa[mi] = *(const f16x8*)&sAh[0][(quad * 256 + wm + mi * 16 + mrow) * 8];
#pragma unroll
    for (int ni = 0; ni < 8; ++ni)
      fb[ni] = *(const f16x8*)&sPh[0][(quad * 128 + ni * 16 + mrow) * 8];
    doP(127 * 32, 1);
#pragma unroll
    for (int mi = 0; mi < 4; ++mi)
#pragma unroll
      for (int ni = 0; ni < 8; ++ni)
        acc[mi][ni] = __builtin_amdgcn_mfma_f32_16x16x32_f16(fa[mi], fb[ni], acc[mi][ni], 0, 0, 0);
    asm volatile("s_waitcnt vmcnt(0) lgkmcnt(0)" ::: "memory");
    __builtin_amdgcn_s_barrier();
  }
  {  // k = 127: pa=1, pp=1
    f16x8 fa[4], fb[8];
#pragma unroll
    for (int mi = 0; mi < 4; ++mi)
      fa[mi] = *(const f16x8*)&sAh[1][(quad * 256 + wm + mi * 16 + mrow) * 8];
#pragma unroll
    for (int ni = 0; ni < 8; ++ni)
      fb[ni] = *(const f16x8*)&sPh[1][(quad * 128 + ni * 16 + mrow) * 8];
#pragma unroll
    for (int mi = 0; mi < 4; ++mi)
#pragma unroll
      for (int ni = 0; ni < 8; ++ni)
        acc[mi][ni] = __builtin_amdgcn_mfma_f32_16x16x32_f16(fa[mi], fb[ni], acc[mi][ni], 0, 0, 0);
  }

  const float g = gptr[0];
  const float inv16 = 1.0f / 16.0f;
  float zvi[8];
#pragma unroll
  for (int ni = 0; ni < 8; ++ni)
    zvi[ni] = iZ[b * NPIX + ib + ni * 16 + mrow] * inv16;
#pragma unroll
  for (int mi = 0; mi < 4; ++mi) {
    const int cbase = cb + wm + mi * 16 + quad * 4;
#pragma unroll
    for (int ni = 0; ni < 8; ++ni) {
      const int i = ib + ni * 16 + mrow;
      f16x4 hv;
#pragma unroll
      for (int rg = 0; rg < 4; ++rg) {
        float xr = in[((size_t)b * 1025 + cbase + rg) * NPIX + i];
        hv[rg] = (f16)(16.f * (g * (acc[mi][ni][rg] * zvi[ni]) + xr));
      }
      *(f16x4*)&yH[(((size_t)b * 128 + (cbase >> 3)) * 4096 + i) * 8 + (cbase & 7)] = hv;
    }
  }
}

// ---------------- conv weight prep: [CO][CI][3][3] -> MFMA-fragment order --

__global__ void rf_wfragc(const float* __restrict__ w, f16* __restrict__ F,
                          int CI, int CO) {
  int gid = blockIdx.x * 256 + threadIdx.x;
  const int C16 = CO >> 4, KI = CI >> 5;
  const int total = 9 * KI * C16 * 64;
  if (gid >= total) return;
  int lane = gid & 63;
  int rest = gid >> 6;
  int c16 = rest % C16;
  int rest2 = rest / C16;
  int k = rest2 % KI;
  int t = rest2 / KI;
  int co = c16 * 16 + (lane & 15);
  int ci = k * 32 + (lane >> 4) * 8;
  f16x8 hb;
#pragma unroll
  for (int j = 0; j < 8; ++j)
    hb[j] = (f16)(256.0f * w[((size_t)co * CI + ci + j) * 9 + t]);
  *(f16x8*)&F[(size_t)gid * 8] = hb;
}

// ---------------- MFMA dilated 3x3 conv (halo dbuf A, register B) ----------

template <int BM, int BN, bool F32OUT>
__global__ __launch_bounds__(256, 2) void rf_mconv(
    const f16* __restrict__ xh, const f16* __restrict__ F,
    const float* __restrict__ bias, const float* __restrict__ zp,
    f16* __restrict__ oh, float* __restrict__ of, int CI, int CO) {
  constexpr int ROWS = BM / 64;
  constexpr int TPI = 4096 / BM;
  constexpr int HROWS = ROWS + 4;               // +-2 row halo
  constexpr int COLP = 72;                      // 68 used + pad to 72
  constexpr int CHUNKS = HROWS * 4 * COLP;      // 16B chunks in halo tile
  constexpr int NSTG = (CHUNKS + 255) / 256;    // A stage instrs per thread
  __shared__ f16 sA[2][NSTG * 2048];
  const int tid = threadIdx.x;
  const int blkpx = blockIdx.x;
  const int cob = blockIdx.y * BN;
  const int b = blkpx / TPI;
  const int h0 = (blkpx - b * TPI) * ROWS;

  const int wv = tid >> 6, lane = tid & 63;
  const int mrow = lane & 15, quad = lane >> 4;
  const int wm = (BN == 128) ? (wv & 1) * 64 : wv * 64;
  const int wn = (BN == 128) ? (wv >> 1) * 64 : 0;
  const int r_out = wm >> 6;
  const int KI = CI >> 5;
  const int C16 = CO >> 4;
  const int cb16 = (cob + wn) >> 4;

  f32x4 acc[4][4];
#pragma unroll
  for (int i = 0; i < 4; ++i)
#pragma unroll
    for (int j = 0; j < 4; ++j) acc[i][j] = (f32x4){0.f, 0.f, 0.f, 0.f};

  // per-lane A staging sources; advance per k = 4 groups = 131072 f16
  const f16* abase[NSTG];
  unsigned vmask = 0;
#pragma unroll
  for (int s = 0; s < NSTG; ++s) {
    int idx = tid + 256 * s;
    int rowks = idx / COLP;
    int col = idx - rowks * COLP;
    int r = rowks >> 2, ks = rowks & 3;
    int srow = h0 + r - 2, scol = col - 2;
    bool ok = (idx < CHUNKS) && ((unsigned)srow < 64u) && ((unsigned)scol < 64u);
    abase[s] = ok ? xh + (((size_t)b * (CI >> 3) + ks) * 4096 + srow * 64 + scol) * 8
                  : (const f16*)zp;
    if (ok) vmask |= (1u << s);
  }
  auto stageA = [&](int k, int pb) {
#pragma unroll
    for (int s = 0; s < NSTG; ++s) {
      const f16* sp = abase[s] + (((vmask >> s) & 1u) ? k * 131072 : 0);
      async16(sp, &sA[pb][((tid & ~63) + 256 * s) * 8]);
    }
  };

  // per-lane B fragment base (fragment-ordered F, already coalesced)
  const f16* Fb = F + ((size_t)cb16 * 64 + lane) * 8;
  auto loadFB = [&](f16x8* dst, int t, int k) {
#pragma unroll
    for (int ni = 0; ni < 4; ++ni)
      dst[ni] = *(const f16x8*)(Fb + ((size_t)(t * KI + k) * C16 + ni) * 512);
  };

  stageA(0, 0);
  f16x8 fb0[4], fb1[4];
  loadFB(fb0, 0, 0);

  for (int k2 = 0; k2 < KI; k2 += 2) {
#pragma unroll
    for (int dk = 0; dk < 2; ++dk) {
      const int k = k2 + dk;
      __syncthreads();                  // A(k) drained & visible
#pragma unroll
      for (int t = 0; t < 9; ++t) {
        const int par = (t + dk) & 1;   // compile-time buffer parity
        f16x8* cur = par ? fb1 : fb0;
        f16x8* nxt = par ? fb0 : fb1;
        if (t < 8) loadFB(nxt, t + 1, k);
        else if (k + 1 < KI) loadFB(nxt, 0, k + 1);
        const int dh = (t / 3) * 2 - 2, dw = (t - (t / 3) * 3) * 2 - 2;
        f16x8 fa[4];
#pragma unroll
        for (int mi = 0; mi < 4; ++mi)
          fa[mi] = *(const f16x8*)&sA[dk][(((r_out + dh + 2) * 4 + quad) * COLP +
                                          mi * 16 + mrow + dw + 2) * 8];
#pragma unroll
        for (int mi = 0; mi < 4; ++mi)
#pragma unroll
          for (int ni = 0; ni < 4; ++ni)
            acc[mi][ni] = __builtin_amdgcn_mfma_f32_16x16x32_f16(fa[mi], cur[ni], acc[mi][ni], 0, 0, 0);
      }
      if (k + 1 < KI) stageA(k + 1, dk ^ 1);
    }
  }

  const float inv = 1.0f / 4096.0f;
  float bvs[4];
#pragma unroll
  for (int ni = 0; ni < 4; ++ni) bvs[ni] = bias[cob + wn + ni * 16 + mrow];
#pragma unroll
  for (int mi = 0; mi < 4; ++mi) {
#pragma unroll
    for (int rg = 0; rg < 4; ++rg) {
      int px = wm + mi * 16 + quad * 4 + rg;
      int hh = h0 + (px >> 6), wwp = px & 63;
#pragma unroll
      for (int ni = 0; ni < 4; ++ni) {
        int co = cob + wn + ni * 16 + mrow;
        float vv = fmaxf(acc[mi][ni][rg] * inv + bvs[ni], 0.f);
        if (F32OUT) {
          of[(((size_t)b * CO + co) * 64 + hh) * 64 + wwp] = vv;
        } else {
          oh[(((size_t)b * (CO >> 3) + (co >> 3)) * 4096 + hh * 64 + wwp) * 8 + (co & 7)] =
              (f16)(vv * 16.f);
        }
      }
    }
  }
}

// ---------------- scan weight frag prep: w[64][64][9] -> frag order ---------

__global__ void rf_wfrag(const float* __restrict__ w, f16* __restrict__ fh) {
  int gid = blockIdx.x * 256 + threadIdx.x;
  if (gid >= 4608) return;
  int lane = gid & 63;
  int rem = gid >> 6;
  int kc = rem & 1;
  int rem2 = rem >> 1;
  int t = rem2 % 9;
  int w4 = rem2 / 9;
  int co = w4 * 16 + (lane & 15);
  int cib = kc * 32 + (lane >> 4) * 8;
  f16x8 hb;
#pragma unroll
  for (int j = 0; j < 8; ++j)
    hb[j] = (f16)(256.f * w[((size_t)co * 64 + cib + j) * 9 + t]);
  *(f16x8*)&fh[(size_t)gid * 8] = hb;
}

// ---------------- MFMA recurrent scan (dbuf carry, srow prefetch) ----------
// ch double-buffered: MFMA reads ch[(s-1)&1], writes go to ch[s&1] -> ONE
// barrier per row (WAR eliminated).  srow(s+1) register-prefetched during
// row s MFMA so global latency hides under the accumulation chains.

__global__ __launch_bounds__(256, 1) void rf_mscan(
    const float* __restrict__ src, float* __restrict__ dst,
    const f16* __restrict__ fh, const float* __restrict__ bias, int dir) {
  __shared__ f16 ch[2][72 * 64];
  const int b = blockIdx.x;
  const int tid = threadIdx.x;
  const int wave = tid >> 6, lane = tid & 63;
  const int quad = lane >> 4, l15 = lane & 15;

  f16x8 Ah[9][2];
#pragma unroll
  for (int t = 0; t < 9; ++t)
#pragma unroll
    for (int kc = 0; kc < 2; ++kc)
      Ah[t][kc] = *(const f16x8*)&fh[(((wave * 9 + t) * 2 + kc) * 64 + lane) * 8];
  float bvs[4];
#pragma unroll
  for (int r = 0; r < 4; ++r) bvs[r] = bias[wave * 16 + quad * 4 + r];

  for (int s = tid; s < 4608; s += 256) ((unsigned*)ch)[s] = 0u;  // both bufs
  __syncthreads();

  const size_t sbase = (size_t)b * 64 * 4096;
  const int row0 = (dir > 0) ? 0 : 63;
  {
    int pos0 = tid & 63, cig = tid >> 6;
#pragma unroll
    for (int q = 0; q < 16; ++q) {
      int ci = cig * 16 + q;
      float v = src[sbase + (size_t)ci * 4096 + row0 * 64 + pos0];
      dst[sbase + (size_t)ci * 4096 + row0 * 64 + pos0] = v;
      int rowIdx = pos0 + 4;
      ch[0][rowIdx * 64 + (((ci >> 3) ^ (rowIdx & 7)) << 3) + (ci & 7)] = (f16)v;
    }
  }
  // prefetch srow for s=1
  float srN[4][4];
  {
    const int rown = (dir > 0) ? 1 : 62;
#pragma unroll
    for (int nt = 0; nt < 4; ++nt)
#pragma unroll
      for (int r = 0; r < 4; ++r)
        srN[nt][r] = src[sbase + (size_t)(wave * 16 + quad * 4 + r) * 4096 +
                         rown * 64 + nt * 16 + l15];
  }
  __syncthreads();

  const float inv = 1.0f / 256.0f;
  for (int s = 1; s < 64; ++s) {
    const int row = (dir > 0) ? s : 63 - s;
    const f16* chp = ch[(s - 1) & 1];
    f16* chw = ch[s & 1];
    float srow[4][4];
#pragma unroll
    for (int nt = 0; nt < 4; ++nt)
#pragma unroll
      for (int r = 0; r < 4; ++r) srow[nt][r] = srN[nt][r];
    if (s < 63) {
      const int rown = (dir > 0) ? s + 1 : 63 - (s + 1);
#pragma unroll
      for (int nt = 0; nt < 4; ++nt)
#pragma unroll
        for (int r = 0; r < 4; ++r)
          srN[nt][r] = src[sbase + (size_t)(wave * 16 + quad * 4 + r) * 4096 +
                           rown * 64 + nt * 16 + l15];
    }
    f32x4 acc[4];
#pragma unroll
    for (int nt = 0; nt < 4; ++nt) acc[nt] = (f32x4){0.f, 0.f, 0.f, 0.f};
#pragma unroll
    for (int t = 0; t < 9; ++t)
#pragma unroll
      for (int kc = 0; kc < 2; ++kc) {
#pragma unroll
        for (int nt = 0; nt < 4; ++nt) {
          int rowIdx = nt * 16 + l15 + t;
          int gr = kc * 4 + quad;
          f16x8 Bh = *(const f16x8*)&chp[rowIdx * 64 + ((gr ^ (rowIdx & 7)) << 3)];
          acc[nt] = __builtin_amdgcn_mfma_f32_16x16x32_f16(Ah[t][kc], Bh, acc[nt], 0, 0, 0);
        }
      }
    // no WAR barrier: writes go to the other buffer
#pragma unroll
    for (int nt = 0; nt < 4; ++nt) {
      int pos = nt * 16 + l15;
      int rowIdx = pos + 4;
      f16x4 hv;
#pragma unroll
      for (int r = 0; r < 4; ++r) {
        float v = fmaxf(acc[nt][r] * inv + bvs[r], 0.f) + srow[nt][r];
        dst[sbase + (size_t)(wave * 16 + quad * 4 + r) * 4096 + row * 64 + pos] = v;
        hv[r] = (f16)v;
      }
      int ci0 = wave * 16 + quad * 4;
      *(f16x4*)&chw[rowIdx * 64 + (((ci0 >> 3) ^ (rowIdx & 7)) << 3) + (ci0 & 7)] = hv;
    }
    __syncthreads();   // ch[s&1] visible for next row's reads
  }
}

// ---------------- transpose last two dims (64x64) per (b,c) ----------------

__global__ void rf_transpose(const float* __restrict__ src, float* __restrict__ dst) {
  int bc = blockIdx.x;  // 256
  __shared__ float tl[64][65];
  int tid = threadIdx.x;
  const float* sp = src + (size_t)bc * 4096;
  float* dp = dst + (size_t)bc * 4096;
  for (int s = tid; s < 4096; s += 256) {
    int h = s >> 6, w = s & 63;
    tl[w][h] = sp[s];
  }
  __syncthreads();
  for (int s = tid; s < 4096; s += 256) dp[s] = tl[s >> 6][s & 63];
}

// ---------------- final 1x1 conv + relu + 8x8 upsample ----------------

__global__ void rf_final(const float* __restrict__ t, const float* __restrict__ ow,
                         const float* __restrict__ ob, float* __restrict__ out) {
  int b = blockIdx.y;
  int s = blockIdx.x * 256 + threadIdx.x;  // 0..4095
  int w = s >> 6, h = s & 63;
  float acc = ob[0];
  for (int c = 0; c < 64; ++c)
    acc += ow[c] * t[(((size_t)b * 64 + c) * 64 + w) * 64 + h];
  acc = fmaxf(acc, 0.f);
  float4 vv = make_float4(acc, acc, acc, acc);
  for (int dy = 0; dy < 8; ++dy) {
    float* dp = out + ((size_t)b * 512 + h * 8 + dy) * 512 + w * 8;
    *(float4*)dp = vv;
    *(float4*)(dp + 4) = vv;
  }
}

// ---------------- launch ----------------

extern "C" void kernel_launch(void* const* d_in, const int* in_sizes, int n_in,
                              void* d_out, int out_size, void* d_ws, size_t ws_size,
                              hipStream_t stream) {
  const float* in    = (const float*)d_in[0];
  const float* wA    = (const float*)d_in[1];
  const float* bA    = (const float*)d_in[2];
  const float* wB    = (const float*)d_in[3];
  const float* wC    = (const float*)d_in[5];
  const float* bC    = (const float*)d_in[6];
  const float* gamma = (const float*)d_in[7];
  const float* bw1 = (const float*)d_in[8];  const float* bb1 = (const float*)d_in[9];
  const float* bw2 = (const float*)d_in[10]; const float* bb2 = (const float*)d_in[11];
  const float* bw3 = (const float*)d_in[12]; const float* bb3 = (const float*)d_in[13];
  const float* bw4 = (const float*)d_in[14]; const float* bb4 = (const float*)d_in[15];
  const float* bw5 = (const float*)d_in[16]; const float* bb5 = (const float*)d_in[17];
  const float* bw6 = (const float*)d_in[18]; const float* bb6 = (const float*)d_in[19];
  const float* du_w = (const float*)d_in[20]; const float* du_b = (const float*)d_in[21];
  const float* lr_w = (const float*)d_in[22]; const float* lr_b = (const float*)d_in[23];
  const float* ow   = (const float*)d_in[24]; const float* ob   = (const float*)d_in[25];
  float* out = (float*)d_out;
  float* ws = (float*)d_ws;

  // phase-1 (attention) buffers; offsets in f32 slots (f16 elems = 2x)
  f16* vH  = (f16*)(ws + 0);          // 16.8M f16 -> [0, 4194304)
  f16* xTh = (f16*)(ws + 4194304);    // [4194304, 8388608)
  f16* wCh = (f16*)(ws + 8388608);    // [8388608, 8912896)
  f16* yH  = (f16*)(ws + 16777216);   // [16777216, 20971520)
  // conv phase (F buffers = same sizes as old wsingle buffers)
  f16* w1h = (f16*)(ws + 0);          // [0, 2359296)
  f16* c1H = (f16*)(ws + 2359296);    // [2359296, 6553600)
  f16* w3h = (f16*)(ws + 6553600);    // [6553600, 7733248)
  f16* w2h = (f16*)(ws + 16777216);   // [16777216, 17956864)  (yH dead)
  f16* c2H = (f16*)(ws + 17956864);   // [17956864, 22151168)
  f16* w4h = (f16*)(ws + 22151168);   // [22151168, 22740992)
  f16* c4H = (f16*)(ws + 22740992);   // [22740992, 24838144)
  f16* c3H = c1H;
  f16* w5h = (f16*)(ws + 0);          // [0, 147456)       (w1 dead)
  f16* c5H = (f16*)(ws + 147456);     // [147456, 1196032)
  f16* w6h = (f16*)(ws + 1196032);    // [1196032, 1232896)
  float* tin = ws + 1232896;          // [1232896, 2281472)
  float* t0  = ws + 2281472;          // [2281472, 3330048)
  float* t1  = ws + 3330048;          // [3330048, 4378624)
  f16* duFh = (f16*)(ws + 4378624);   // [4378624, 4397056)  (c1/c3 dead)
  f16* lrFh = (f16*)(ws + 4397056);   // [4397056, 4415488)
  float* sm = ws + 33554432;
  float* A_  = sm;
  float* M_  = sm + 16384;
  float* iZ  = sm + 32768;
  float* u_  = sm + 49152;
  float* s_  = sm + 50176;
  float* c0_ = sm + 50304;
  float* fst = sm + 50308;
  float* zp  = sm + 50432;  // 64-float zero page for OOB DMA lanes

  rf_zero<<<1, 64, 0, stream>>>(zp);
  rf_s<<<1, 128, 0, stream>>>(wB, bA, s_, c0_);
  rf_u<<<4, 256, 0, stream>>>(wA, s_, u_);
  rf_fstat<<<4, 256, 0, stream>>>(in, fst);
  rf_A<<<dim3(16, 4), 256, 0, stream>>>(in, u_, c0_, fst, A_, M_);
  rf_Z<<<4096, 256, 0, stream>>>(in, A_, M_, iZ);
  rf_xsplit<<<dim3(64, 16, 4), 256, 0, stream>>>(in, xTh);
  rf_wC1<<<512, 256, 0, stream>>>(wC, wCh);
  rf_vgemmm<<<dim3(32, 8, 4), 256, 0, stream>>>(wCh, xTh, bC, vH);
  rf_attm<<<dim3(32, 4, 4), 256, 0, stream>>>(vH, A_, M_, iZ, in, gamma, yH);

  // fragment-ordered conv weights (sizes identical to old wsingle buffers)
  rf_wfragc<<<2304, 256, 0, stream>>>(bw1, w1h, 1024, 512);
  rf_wfragc<<<1152, 256, 0, stream>>>(bw3, w3h, 512, 512);
  rf_mconv<128, 128, false><<<dim3(128, 4), 256, 0, stream>>>(
      yH, w1h, bb1, zp, c1H, nullptr, 1024, 512);
  rf_wfragc<<<1152, 256, 0, stream>>>(bw2, w2h, 512, 512);
  rf_wfragc<<<576, 256, 0, stream>>>(bw4, w4h, 512, 256);
  rf_wfragc<<<144, 256, 0, stream>>>(bw5, w5h, 256, 128);
  rf_wfragc<<<36, 256, 0, stream>>>(bw6, w6h, 128, 64);
  rf_mconv<128, 128, false><<<dim3(128, 4), 256, 0, stream>>>(
      c1H, w2h, bb2, zp, c2H, nullptr, 512, 512);
  rf_mconv<128, 128, false><<<dim3(128, 4), 256, 0, stream>>>(
      c2H, w3h, bb3, zp, c3H, nullptr, 512, 512);
  rf_mconv<128, 128, false><<<dim3(128, 2), 256, 0, stream>>>(
      c3H, w4h, bb4, zp, c4H, nullptr, 512, 256);
  rf_wfrag<<<18, 256, 0, stream>>>(du_w, duFh);
  rf_wfrag<<<18, 256, 0, stream>>>(lr_w, lrFh);
  rf_mconv<128, 128, false><<<dim3(128, 1), 256, 0, stream>>>(
      c4H, w5h, bb5, zp, c5H, nullptr, 256, 128);
  rf_mconv<256, 64, true><<<dim3(64, 1), 256, 0, stream>>>(
      c5H, w6h, bb6, zp, nullptr, tin, 128, 64);

  rf_mscan<<<4, 256, 0, stream>>>(tin, t0, duFh, du_b, +1);
  rf_mscan<<<4, 256, 0, stream>>>(t0, t1, duFh, du_b, -1);
  rf_transpose<<<256, 256, 0, stream>>>(t1, t0);
  rf_mscan<<<4, 256, 0, stream>>>(t0, t1, lrFh, lr_b, +1);
  rf_mscan<<<4, 256, 0, stream>>>(t1, t0, lrFh, lr_b, -1);
  rf_final<<<dim3(16, 4), 256, 0, stream>>>(t0, ow, ob, out);
}

// Round 9
// 1426.434 us; speedup vs baseline: 1.4032x; 1.0270x over previous
//
#include <hip/hip_runtime.h>

// resFAN round 15 (R8 this session): attm 512-thread / 512-c blocks.
// R7 post-mortem: mscan fix -91us; attm tops at 179us with VALUBusy 52% /
// MfmaUtil 34% -> P-tile exp dominates, still computed 4x redundantly (once
// per cb-block).  Fix: 8-wave 512-thread blocks covering 512 c (grid y 4->2):
// P redundancy 4x->2x, per-thread doP halves (8 exp, kc0=tid>>7 single shot),
// sAh [3][4*512*8]=96KB, total LDS 128KB = 1 block/CU, 256 blocks = 1 round.
// Same counted-vmcnt(4) pipeline, same per-wave tile and epilogue.
//
// Error budget unchanged: fp16 quant 2^-11, scales 16/256.

#define NPIX 4096

typedef _Float16 f16;
typedef _Float16 f16x8 __attribute__((ext_vector_type(8)));
typedef _Float16 f16x4 __attribute__((ext_vector_type(4)));
typedef float f32x4 __attribute__((ext_vector_type(4)));

__device__ inline void async16(const void* g, void* l) {
  __builtin_amdgcn_global_load_lds(
      (const __attribute__((address_space(1))) unsigned int*)g,
      (__attribute__((address_space(3))) unsigned int*)l, 16, 0, 0);
}

// ---------------- small prep kernels ----------------

__global__ void rf_zero(float* __restrict__ z) { z[threadIdx.x] = 0.f; }

__global__ void rf_s(const float* __restrict__ wB, const float* __restrict__ bA,
                     float* __restrict__ s_out, float* __restrict__ c0_out) {
  int c = threadIdx.x;  // 128 threads
  const float* row = wB + (size_t)c * 1024;
  float acc = 0.f;
  for (int i = 0; i < 1024; ++i) acc += row[i];
  s_out[c] = acc;
  __shared__ float sh[128];
  sh[c] = acc * bA[c];
  __syncthreads();
  for (int off = 64; off > 0; off >>= 1) {
    if (c < off) sh[c] += sh[c + off];
    __syncthreads();
  }
  if (c == 0) c0_out[0] = sh[0];
}

__global__ void rf_u(const float* __restrict__ wA, const float* __restrict__ s,
                     float* __restrict__ u) {
  int i = blockIdx.x * 256 + threadIdx.x;  // 1024 total
  float acc = 0.f;
  for (int c = 0; c < 128; ++c) acc += s[c] * wA[(size_t)c * 1024 + i];
  u[i] = acc;
}

__global__ void rf_fstat(const float* __restrict__ in, float* __restrict__ fstat) {
  int b = blockIdx.x;
  int t = threadIdx.x;
  const float* f = in + ((size_t)b * 1025 + 1024) * NPIX;
  float mx = -1e30f, mn = 1e30f;
  for (int j = t; j < NPIX; j += 256) {
    float v = f[j];
    mx = fmaxf(mx, v);
    mn = fminf(mn, v);
  }
  __shared__ float smx[256], smn[256];
  smx[t] = mx; smn[t] = mn;
  __syncthreads();
  for (int off = 128; off > 0; off >>= 1) {
    if (t < off) {
      smx[t] = fmaxf(smx[t], smx[t + off]);
      smn[t] = fminf(smn[t], smn[t + off]);
    }
    __syncthreads();
  }
  if (t == 0) { fstat[b] = smx[0]; fstat[4 + b] = smn[0]; }
}

__global__ __launch_bounds__(256) void rf_A(const float* __restrict__ in,
                                            const float* __restrict__ u,
                                            const float* __restrict__ c0p,
                                            const float* __restrict__ fst,
                                            float* __restrict__ A, float* __restrict__ M) {
  __shared__ float ul[1024];
  int b = blockIdx.y;
  int n = blockIdx.x * 256 + threadIdx.x;
  for (int s = threadIdx.x; s < 1024; s += 256) ul[s] = u[s];
  __syncthreads();
  const float* xp = in + (size_t)b * 1025 * NPIX + n;
  float acc = c0p[0];
#pragma unroll 8
  for (int i = 0; i < 1024; ++i) acc = fmaf(ul[i], xp[(size_t)i * NPIX], acc);
  A[b * NPIX + n] = acc;
  M[b * NPIX + n] = fmaxf(acc * fst[b], acc * fst[4 + b]);
}

__global__ void rf_Z(const float* __restrict__ in, const float* __restrict__ A,
                     const float* __restrict__ M, float* __restrict__ iZ) {
  int idx = blockIdx.x * 4 + (threadIdx.x >> 6);  // (b,n) pair, 16384 total
  int lane = threadIdx.x & 63;
  int b = idx >> 12;
  const float* f = in + ((size_t)b * 1025 + 1024) * NPIX;
  float a = A[idx], m = M[idx];
  float acc = 0.f;
#pragma unroll 4
  for (int it = 0; it < 64; ++it) acc += __expf(a * f[lane + it * 64] - m);
  for (int off = 32; off > 0; off >>= 1) acc += __shfl_down(acc, off, 64);
  if (lane == 0) iZ[idx] = 1.0f / acc;
}

// ------- x transpose: [b][ci][n] f32 -> xTh[b][kg128][n][8] f16, scale 16 --

__global__ void rf_xsplit(const float* __restrict__ in, f16* __restrict__ xh) {
  __shared__ float tl[64][65];
  int nt = blockIdx.x, ct = blockIdx.y, b = blockIdx.z;
  int n0 = nt * 64, c0 = ct * 64;
  int tid = threadIdx.x;
  for (int s = tid; s < 4096; s += 256) {
    int r = s >> 6, c = s & 63;
    tl[r][c] = in[((size_t)b * 1025 + c0 + r) * NPIX + n0 + c];
  }
  __syncthreads();
  for (int s = tid; s < 512; s += 256) {
    int n = s >> 3, g = s & 7;
    f16x8 hb;
#pragma unroll
    for (int q = 0; q < 8; ++q) hb[q] = (f16)(16.f * tl[g * 8 + q][n]);
    size_t o = (((size_t)b * 128 + (c0 >> 3) + g) * 4096 + n0 + n) * 8;
    *(f16x8*)&xh[o] = hb;
  }
}

// ------- wC cast: [1024][1024] f32 -> wCh[ig128][c][8] f16, scale 256 ------

__global__ void rf_wC1(const float* __restrict__ wC, f16* __restrict__ wh) {
  int base = (blockIdx.x * 256 + threadIdx.x) * 8;
  int c = base >> 10, i0 = base & 1023;
  f16x8 hb;
#pragma unroll
  for (int q = 0; q < 8; ++q) hb[q] = (f16)(256.f * wC[base + q]);
  *(f16x8*)&wh[(((size_t)(i0 >> 3)) * 1024 + c) * 8] = hb;
}

// ---------------- MFMA v-GEMM (dbuf, single fp16): v = wC @ x + bC --------

__global__ __launch_bounds__(256, 2) void rf_vgemmm(
    const f16* __restrict__ wh, const f16* __restrict__ xh,
    const float* __restrict__ bC, f16* __restrict__ vH) {
  __shared__ f16 sA[2][4096], sB[2][4096];
  const int tid = threadIdx.x;
  const int nb = blockIdx.x * 128, cb = blockIdx.y * 128, b = blockIdx.z;
  const int pA = tid & 127;
  const int wv = tid >> 6, lane = tid & 63;
  const int mrow = lane & 15, quad = lane >> 4;
  const int wm = (wv & 1) * 64, wn = (wv >> 1) * 64;
  f32x4 acc[4][4];
#pragma unroll
  for (int i = 0; i < 4; ++i)
#pragma unroll
    for (int j = 0; j < 4; ++j) acc[i][j] = (f32x4){0.f, 0.f, 0.f, 0.f};

  auto stage = [&](int k0, int pb) {
    const int kg = k0 >> 3;
#pragma unroll
    for (int s = 0; s < 2; ++s) {
      const int cc = ((tid + 256 * s) >> 7) & 3;
      const int lb = ((tid & ~63) + 256 * s) * 8;
      async16(wh + ((size_t)(kg + cc) * 1024 + cb + pA) * 8, &sA[pb][lb]);
      async16(xh + (((size_t)b * 128 + kg + cc) * 4096 + nb + pA) * 8, &sB[pb][lb]);
    }
  };
  stage(0, 0);
  int p = 0;
  for (int k0 = 0; k0 < 1024; k0 += 32) {
    __syncthreads();
    if (k0 + 32 < 1024) stage(k0 + 32, p ^ 1);
    f16x8 fa[4], fb[4];
#pragma unroll
    for (int mi = 0; mi < 4; ++mi)
      fa[mi] = *(const f16x8*)&sA[p][(quad * 128 + wm + mi * 16 + mrow) * 8];
#pragma unroll
    for (int ni = 0; ni < 4; ++ni)
      fb[ni] = *(const f16x8*)&sB[p][(quad * 128 + wn + ni * 16 + mrow) * 8];
#pragma unroll
    for (int mi = 0; mi < 4; ++mi)
#pragma unroll
      for (int ni = 0; ni < 4; ++ni)
        acc[mi][ni] = __builtin_amdgcn_mfma_f32_16x16x32_f16(fa[mi], fb[ni], acc[mi][ni], 0, 0, 0);
    p ^= 1;
  }
  const float inv = 1.0f / 4096.0f;
#pragma unroll
  for (int mi = 0; mi < 4; ++mi) {
#pragma unroll
    for (int rg = 0; rg < 4; ++rg) {
      int c = cb + wm + mi * 16 + quad * 4 + rg;
      float bv = bC[c];
#pragma unroll
      for (int ni = 0; ni < 4; ++ni) {
        int j = nb + wn + ni * 16 + mrow;
        vH[(((size_t)b * 512 + (j >> 3)) * 1024 + c) * 8 + (j & 7)] =
            (f16)(16.f * (acc[mi][ni][rg] * inv + bv));
      }
    }
  }
}

// ---------------- MFMA attention out-GEMM (8-wave, 512-c blocks) -----------
// P redundancy 2x (grid y=2).  Per-thread doP: 8 exp (kc0 = tid>>7).
// LDS: sAh 3x32KB + sPh 2x8KB + fl 16KB = 128KB -> 1 block/CU, 256 blocks.

__global__ __launch_bounds__(512, 1) void rf_attm(
    const f16* __restrict__ vH,
    const float* __restrict__ Aarr, const float* __restrict__ Marr,
    const float* __restrict__ iZ, const float* __restrict__ in,
    const float* __restrict__ gptr, f16* __restrict__ yH) {
  __shared__ f16 sAh[3][16384];  // [buf][jgrp4][c512][8]  32KB each
  __shared__ f16 sPh[2][4096];   // [buf][kc4][i128][8]     8KB each
  __shared__ float fl[4096];     // f row, 16KB
  const int tid = threadIdx.x;
  const int ib = blockIdx.x * 128, cb = blockIdx.y * 512, b = blockIdx.z;
  const int wv = tid >> 6, lane = tid & 63;
  const int mrow = lane & 15, quad = lane >> 4;
  const int wm = wv * 64;                 // wave's 64-c slice of 512
  const int ni_ = tid & 127;
  const int kc0 = tid >> 7;               // 0..3
  const float av2 = Aarr[b * NPIX + ib + ni_] * 1.44269504f;
  const float mv2 = Marr[b * NPIX + ib + ni_] * 1.44269504f;
  const float* f = in + ((size_t)b * 1025 + 1024) * NPIX;
  const f16* vbase = vH + (size_t)b * 4194304 + ((size_t)cb + tid) * 8;

  f32x4 acc[4][8];
#pragma unroll
  for (int i = 0; i < 4; ++i)
#pragma unroll
    for (int j = 0; j < 8; ++j) acc[i][j] = (f32x4){0.f, 0.f, 0.f, 0.f};

  auto stage = [&](int j0, int pb) {
    const int jg = j0 >> 3;
#pragma unroll
    for (int s = 0; s < 4; ++s)
      async16(vbase + (size_t)(jg + s) * 8192, &sAh[pb][(s * 512 + tid) * 8]);
  };
  auto doP = [&](int j0, int pb) {
    const float4 fa4 = *(const float4*)&fl[j0 + kc0 * 8];
    const float4 fb4 = *(const float4*)&fl[j0 + kc0 * 8 + 4];
    const float fj[8] = {fa4.x, fa4.y, fa4.z, fa4.w, fb4.x, fb4.y, fb4.z, fb4.w};
    f16x8 ph;
#pragma unroll
    for (int q = 0; q < 8; ++q)
      ph[q] = (f16)exp2f(fmaf(av2, fj[q], -mv2));
    *(f16x8*)&sPh[pb][(kc0 * 128 + ni_) * 8] = ph;
  };

  // prologue: f row -> LDS (2 chunks/thread), A0, then P0 while A1 flies
#pragma unroll
  for (int s = 0; s < 2; ++s)
    async16(f + (tid + 512 * s) * 4, &fl[(tid + 512 * s) * 4]);
  stage(0, 0);
  asm volatile("s_waitcnt vmcnt(0)" ::: "memory");
  __builtin_amdgcn_s_barrier();
  doP(0, 0);
  stage(32, 1);
  asm volatile("s_waitcnt lgkmcnt(0)" ::: "memory");
  __builtin_amdgcn_s_barrier();

  for (int k = 0; k < 126; ++k) {
    const int pa = k % 3;
    const int pp = k & 1;
    f16x8 fa[4], fb[8];
#pragma unroll
    for (int mi = 0; mi < 4; ++mi)
      fa[mi] = *(const f16x8*)&sAh[pa][(quad * 512 + wm + mi * 16 + mrow) * 8];
#pragma unroll
    for (int ni = 0; ni < 8; ++ni)
      fb[ni] = *(const f16x8*)&sPh[pp][(quad * 128 + ni * 16 + mrow) * 8];
    stage((k + 2) * 32, (k + 2) % 3);   // lands by end of step k+1
    doP((k + 1) * 32, pp ^ 1);          // lgkm-only, overlaps MFMA
#pragma unroll
    for (int mi = 0; mi < 4; ++mi)
#pragma unroll
      for (int ni = 0; ni < 8; ++ni)
        acc[mi][ni] = __builtin_amdgcn_mfma_f32_16x16x32_f16(fa[mi], fb[ni], acc[mi][ni], 0, 0, 0);
    asm volatile("s_waitcnt vmcnt(4) lgkmcnt(0)" ::: "memory");
    __builtin_amdgcn_s_barrier();
  }
  {  // k = 126: pa=0, pp=0; last doP, drain all DMAs
    f16x8 fa[4], fb[8];
#pragma unroll
    for (int mi = 0; mi < 4; ++mi)
      fa[mi] = *(const f16x8*)&sAh[0][(quad * 512 + wm + mi * 16 + mrow) * 8];
#pragma unroll
    for (int ni = 0; ni < 8; ++ni)
      fb[ni] = *(const f16x8*)&sPh[0][(quad * 128 + ni * 16 + mrow) * 8];
    doP(127 * 32, 1);
#pragma unroll
    for (int mi = 0; mi < 4; ++mi)
#pragma unroll
      for (int ni = 0; ni < 8; ++ni)
        acc[mi][ni] = __builtin_amdgcn_mfma_f32_16x16x32_f16(fa[mi], fb[ni], acc[mi][ni], 0, 0, 0);
    asm volatile("s_waitcnt vmcnt(0) lgkmcnt(0)" ::: "memory");
    __builtin_amdgcn_s_barrier();
  }
  {  // k = 127: pa=1, pp=1
    f16x8 fa[4], fb[8];
#pragma unroll
    for (int mi = 0; mi < 4; ++mi)
      fa[mi] = *(const f16x8*)&sAh[1][(quad * 512 + wm + mi * 16 + mrow) * 8];
#pragma unroll
    for (int ni = 0; ni < 8; ++ni)
      fb[ni] = *(const f16x8*)&sPh[1][(quad * 128 + ni * 16 + mrow) * 8];
#pragma unroll
    for (int mi = 0; mi < 4; ++mi)
#pragma unroll
      for (int ni = 0; ni < 8; ++ni)
        acc[mi][ni] = __builtin_amdgcn_mfma_f32_16x16x32_f16(fa[mi], fb[ni], acc[mi][ni], 0, 0, 0);
  }

  const float g = gptr[0];
  const float inv16 = 1.0f / 16.0f;
  float zvi[8];
#pragma unroll
  for (int ni = 0; ni < 8; ++ni)
    zvi[ni] = iZ[b * NPIX + ib + ni * 16 + mrow] * inv16;
#pragma unroll
  for (int mi = 0; mi < 4; ++mi) {
    const int cbase = cb + wm + mi * 16 + quad * 4;
#pragma unroll
    for (int ni = 0; ni < 8; ++ni) {
      const int i = ib + ni * 16 + mrow;
      f16x4 hv;
#pragma unroll
      for (int rg = 0; rg < 4; ++rg) {
        float xr = in[((size_t)b * 1025 + cbase + rg) * NPIX + i];
        hv[rg] = (f16)(16.f * (g * (acc[mi][ni][rg] * zvi[ni]) + xr));
      }
      *(f16x4*)&yH[(((size_t)b * 128 + (cbase >> 3)) * 4096 + i) * 8 + (cbase & 7)] = hv;
    }
  }
}

// ---------------- conv weight prep: [CO][CI][3][3] -> MFMA-fragment order --

__global__ void rf_wfragc(const float* __restrict__ w, f16* __restrict__ F,
                          int CI, int CO) {
  int gid = blockIdx.x * 256 + threadIdx.x;
  const int C16 = CO >> 4, KI = CI >> 5;
  const int total = 9 * KI * C16 * 64;
  if (gid >= total) return;
  int lane = gid & 63;
  int rest = gid >> 6;
  int c16 = rest % C16;
  int rest2 = rest / C16;
  int k = rest2 % KI;
  int t = rest2 / KI;
  int co = c16 * 16 + (lane & 15);
  int ci = k * 32 + (lane >> 4) * 8;
  f16x8 hb;
#pragma unroll
  for (int j = 0; j < 8; ++j)
    hb[j] = (f16)(256.0f * w[((size_t)co * CI + ci + j) * 9 + t]);
  *(f16x8*)&F[(size_t)gid * 8] = hb;
}

// ---------------- MFMA dilated 3x3 conv (halo dbuf A, register B) ----------

template <int BM, int BN, bool F32OUT>
__global__ __launch_bounds__(256, 2) void rf_mconv(
    const f16* __restrict__ xh, const f16* __restrict__ F,
    const float* __restrict__ bias, const float* __restrict__ zp,
    f16* __restrict__ oh, float* __restrict__ of, int CI, int CO) {
  constexpr int ROWS = BM / 64;
  constexpr int TPI = 4096 / BM;
  constexpr int HROWS = ROWS + 4;               // +-2 row halo
  constexpr int COLP = 72;                      // 68 used + pad to 72
  constexpr int CHUNKS = HROWS * 4 * COLP;      // 16B chunks in halo tile
  constexpr int NSTG = (CHUNKS + 255) / 256;    // A stage instrs per thread
  __shared__ f16 sA[2][NSTG * 2048];
  const int tid = threadIdx.x;
  const int blkpx = blockIdx.x;
  const int cob = blockIdx.y * BN;
  const int b = blkpx / TPI;
  const int h0 = (blkpx - b * TPI) * ROWS;

  const int wv = tid >> 6, lane = tid & 63;
  const int mrow = lane & 15, quad = lane >> 4;
  const int wm = (BN == 128) ? (wv & 1) * 64 : wv * 64;
  const int wn = (BN == 128) ? (wv >> 1) * 64 : 0;
  const int r_out = wm >> 6;
  const int KI = CI >> 5;
  const int C16 = CO >> 4;
  const int cb16 = (cob + wn) >> 4;

  f32x4 acc[4][4];
#pragma unroll
  for (int i = 0; i < 4; ++i)
#pragma unroll
    for (int j = 0; j < 4; ++j) acc[i][j] = (f32x4){0.f, 0.f, 0.f, 0.f};

  // per-lane A staging sources; advance per k = 4 groups = 131072 f16
  const f16* abase[NSTG];
  unsigned vmask = 0;
#pragma unroll
  for (int s = 0; s < NSTG; ++s) {
    int idx = tid + 256 * s;
    int rowks = idx / COLP;
    int col = idx - rowks * COLP;
    int r = rowks >> 2, ks = rowks & 3;
    int srow = h0 + r - 2, scol = col - 2;
    bool ok = (idx < CHUNKS) && ((unsigned)srow < 64u) && ((unsigned)scol < 64u);
    abase[s] = ok ? xh + (((size_t)b * (CI >> 3) + ks) * 4096 + srow * 64 + scol) * 8
                  : (const f16*)zp;
    if (ok) vmask |= (1u << s);
  }
  auto stageA = [&](int k, int pb) {
#pragma unroll
    for (int s = 0; s < NSTG; ++s) {
      const f16* sp = abase[s] + (((vmask >> s) & 1u) ? k * 131072 : 0);
      async16(sp, &sA[pb][((tid & ~63) + 256 * s) * 8]);
    }
  };

  // per-lane B fragment base (fragment-ordered F, already coalesced)
  const f16* Fb = F + ((size_t)cb16 * 64 + lane) * 8;
  auto loadFB = [&](f16x8* dst, int t, int k) {
#pragma unroll
    for (int ni = 0; ni < 4; ++ni)
      dst[ni] = *(const f16x8*)(Fb + ((size_t)(t * KI + k) * C16 + ni) * 512);
  };

  stageA(0, 0);
  f16x8 fb0[4], fb1[4];
  loadFB(fb0, 0, 0);

  for (int k2 = 0; k2 < KI; k2 += 2) {
#pragma unroll
    for (int dk = 0; dk < 2; ++dk) {
      const int k = k2 + dk;
      __syncthreads();                  // A(k) drained & visible
#pragma unroll
      for (int t = 0; t < 9; ++t) {
        const int par = (t + dk) & 1;   // compile-time buffer parity
        f16x8* cur = par ? fb1 : fb0;
        f16x8* nxt = par ? fb0 : fb1;
        if (t < 8) loadFB(nxt, t + 1, k);
        else if (k + 1 < KI) loadFB(nxt, 0, k + 1);
        const int dh = (t / 3) * 2 - 2, dw = (t - (t / 3) * 3) * 2 - 2;
        f16x8 fa[4];
#pragma unroll
        for (int mi = 0; mi < 4; ++mi)
          fa[mi] = *(const f16x8*)&sA[dk][(((r_out + dh + 2) * 4 + quad) * COLP +
                                          mi * 16 + mrow + dw + 2) * 8];
#pragma unroll
        for (int mi = 0; mi < 4; ++mi)
#pragma unroll
          for (int ni = 0; ni < 4; ++ni)
            acc[mi][ni] = __builtin_amdgcn_mfma_f32_16x16x32_f16(fa[mi], cur[ni], acc[mi][ni], 0, 0, 0);
      }
      if (k + 1 < KI) stageA(k + 1, dk ^ 1);
    }
  }

  const float inv = 1.0f / 4096.0f;
  float bvs[4];
#pragma unroll
  for (int ni = 0; ni < 4; ++ni) bvs[ni] = bias[cob + wn + ni * 16 + mrow];
#pragma unroll
  for (int mi = 0; mi < 4; ++mi) {
#pragma unroll
    for (int rg = 0; rg < 4; ++rg) {
      int px = wm + mi * 16 + quad * 4 + rg;
      int hh = h0 + (px >> 6), wwp = px & 63;
#pragma unroll
      for (int ni = 0; ni < 4; ++ni) {
        int co = cob + wn + ni * 16 + mrow;
        float vv = fmaxf(acc[mi][ni][rg] * inv + bvs[ni], 0.f);
        if (F32OUT) {
          of[(((size_t)b * CO + co) * 64 + hh) * 64 + wwp] = vv;
        } else {
          oh[(((size_t)b * (CO >> 3) + (co >> 3)) * 4096 + hh * 64 + wwp) * 8 + (co & 7)] =
              (f16)(vv * 16.f);
        }
      }
    }
  }
}

// ---------------- scan weight frag prep: w[64][64][9] -> frag order ---------

__global__ void rf_wfrag(const float* __restrict__ w, f16* __restrict__ fh) {
  int gid = blockIdx.x * 256 + threadIdx.x;
  if (gid >= 4608) return;
  int lane = gid & 63;
  int rem = gid >> 6;
  int kc = rem & 1;
  int rem2 = rem >> 1;
  int t = rem2 % 9;
  int w4 = rem2 / 9;
  int co = w4 * 16 + (lane & 15);
  int cib = kc * 32 + (lane >> 4) * 8;
  f16x8 hb;
#pragma unroll
  for (int j = 0; j < 8; ++j)
    hb[j] = (f16)(256.f * w[((size_t)co * 64 + cib + j) * 9 + t]);
  *(f16x8*)&fh[(size_t)gid * 8] = hb;
}

// ---------------- MFMA recurrent scan (dbuf carry, srow prefetch) ----------

__global__ __launch_bounds__(256, 1) void rf_mscan(
    const float* __restrict__ src, float* __restrict__ dst,
    const f16* __restrict__ fh, const float* __restrict__ bias, int dir) {
  __shared__ f16 ch[2][72 * 64];
  const int b = blockIdx.x;
  const int tid = threadIdx.x;
  const int wave = tid >> 6, lane = tid & 63;
  const int quad = lane >> 4, l15 = lane & 15;

  f16x8 Ah[9][2];
#pragma unroll
  for (int t = 0; t < 9; ++t)
#pragma unroll
    for (int kc = 0; kc < 2; ++kc)
      Ah[t][kc] = *(const f16x8*)&fh[(((wave * 9 + t) * 2 + kc) * 64 + lane) * 8];
  float bvs[4];
#pragma unroll
  for (int r = 0; r < 4; ++r) bvs[r] = bias[wave * 16 + quad * 4 + r];

  for (int s = tid; s < 4608; s += 256) ((unsigned*)ch)[s] = 0u;  // both bufs
  __syncthreads();

  const size_t sbase = (size_t)b * 64 * 4096;
  const int row0 = (dir > 0) ? 0 : 63;
  {
    int pos0 = tid & 63, cig = tid >> 6;
#pragma unroll
    for (int q = 0; q < 16; ++q) {
      int ci = cig * 16 + q;
      float v = src[sbase + (size_t)ci * 4096 + row0 * 64 + pos0];
      dst[sbase + (size_t)ci * 4096 + row0 * 64 + pos0] = v;
      int rowIdx = pos0 + 4;
      ch[0][rowIdx * 64 + (((ci >> 3) ^ (rowIdx & 7)) << 3) + (ci & 7)] = (f16)v;
    }
  }
  // prefetch srow for s=1
  float srN[4][4];
  {
    const int rown = (dir > 0) ? 1 : 62;
#pragma unroll
    for (int nt = 0; nt < 4; ++nt)
#pragma unroll
      for (int r = 0; r < 4; ++r)
        srN[nt][r] = src[sbase + (size_t)(wave * 16 + quad * 4 + r) * 4096 +
                         rown * 64 + nt * 16 + l15];
  }
  __syncthreads();

  const float inv = 1.0f / 256.0f;
  for (int s = 1; s < 64; ++s) {
    const int row = (dir > 0) ? s : 63 - s;
    const f16* chp = ch[(s - 1) & 1];
    f16* chw = ch[s & 1];
    float srow[4][4];
#pragma unroll
    for (int nt = 0; nt < 4; ++nt)
#pragma unroll
      for (int r = 0; r < 4; ++r) srow[nt][r] = srN[nt][r];
    if (s < 63) {
      const int rown = (dir > 0) ? s + 1 : 63 - (s + 1);
#pragma unroll
      for (int nt = 0; nt < 4; ++nt)
#pragma unroll
        for (int r = 0; r < 4; ++r)
          srN[nt][r] = src[sbase + (size_t)(wave * 16 + quad * 4 + r) * 4096 +
                           rown * 64 + nt * 16 + l15];
    }
    f32x4 acc[4];
#pragma unroll
    for (int nt = 0; nt < 4; ++nt) acc[nt] = (f32x4){0.f, 0.f, 0.f, 0.f};
#pragma unroll
    for (int t = 0; t < 9; ++t)
#pragma unroll
      for (int kc = 0; kc < 2; ++kc) {
#pragma unroll
        for (int nt = 0; nt < 4; ++nt) {
          int rowIdx = nt * 16 + l15 + t;
          int gr = kc * 4 + quad;
          f16x8 Bh = *(const f16x8*)&chp[rowIdx * 64 + ((gr ^ (rowIdx & 7)) << 3)];
          acc[nt] = __builtin_amdgcn_mfma_f32_16x16x32_f16(Ah[t][kc], Bh, acc[nt], 0, 0, 0);
        }
      }
    // no WAR barrier: writes go to the other buffer
#pragma unroll
    for (int nt = 0; nt < 4; ++nt) {
      int pos = nt * 16 + l15;
      int rowIdx = pos + 4;
      f16x4 hv;
#pragma unroll
      for (int r = 0; r < 4; ++r) {
        float v = fmaxf(acc[nt][r] * inv + bvs[r], 0.f) + srow[nt][r];
        dst[sbase + (size_t)(wave * 16 + quad * 4 + r) * 4096 + row * 64 + pos] = v;
        hv[r] = (f16)v;
      }
      int ci0 = wave * 16 + quad * 4;
      *(f16x4*)&chw[rowIdx * 64 + (((ci0 >> 3) ^ (rowIdx & 7)) << 3) + (ci0 & 7)] = hv;
    }
    __syncthreads();   // ch[s&1] visible for next row's reads
  }
}

// ---------------- transpose last two dims (64x64) per (b,c) ----------------

__global__ void rf_transpose(const float* __restrict__ src, float* __restrict__ dst) {
  int bc = blockIdx.x;  // 256
  __shared__ float tl[64][65];
  int tid = threadIdx.x;
  const float* sp = src + (size_t)bc * 4096;
  float* dp = dst + (size_t)bc * 4096;
  for (int s = tid; s < 4096; s += 256) {
    int h = s >> 6, w = s & 63;
    tl[w][h] = sp[s];
  }
  __syncthreads();
  for (int s = tid; s < 4096; s += 256) dp[s] = tl[s >> 6][s & 63];
}

// ---------------- final 1x1 conv + relu + 8x8 upsample ----------------

__global__ void rf_final(const float* __restrict__ t, const float* __restrict__ ow,
                         const float* __restrict__ ob, float* __restrict__ out) {
  int b = blockIdx.y;
  int s = blockIdx.x * 256 + threadIdx.x;  // 0..4095
  int w = s >> 6, h = s & 63;
  float acc = ob[0];
  for (int c = 0; c < 64; ++c)
    acc += ow[c] * t[(((size_t)b * 64 + c) * 64 + w) * 64 + h];
  acc = fmaxf(acc, 0.f);
  float4 vv = make_float4(acc, acc, acc, acc);
  for (int dy = 0; dy < 8; ++dy) {
    float* dp = out + ((size_t)b * 512 + h * 8 + dy) * 512 + w * 8;
    *(float4*)dp = vv;
    *(float4*)(dp + 4) = vv;
  }
}

// ---------------- launch ----------------

extern "C" void kernel_launch(void* const* d_in, const int* in_sizes, int n_in,
                              void* d_out, int out_size, void* d_ws, size_t ws_size,
                              hipStream_t stream) {
  const float* in    = (const float*)d_in[0];
  const float* wA    = (const float*)d_in[1];
  const float* bA    = (const float*)d_in[2];
  const float* wB    = (const float*)d_in[3];
  const float* wC    = (const float*)d_in[5];
  const float* bC    = (const float*)d_in[6];
  const float* gamma = (const float*)d_in[7];
  const float* bw1 = (const float*)d_in[8];  const float* bb1 = (const float*)d_in[9];
  const float* bw2 = (const float*)d_in[10]; const float* bb2 = (const float*)d_in[11];
  const float* bw3 = (const float*)d_in[12]; const float* bb3 = (const float*)d_in[13];
  const float* bw4 = (const float*)d_in[14]; const float* bb4 = (const float*)d_in[15];
  const float* bw5 = (const float*)d_in[16]; const float* bb5 = (const float*)d_in[17];
  const float* bw6 = (const float*)d_in[18]; const float* bb6 = (const float*)d_in[19];
  const float* du_w = (const float*)d_in[20]; const float* du_b = (const float*)d_in[21];
  const float* lr_w = (const float*)d_in[22]; const float* lr_b = (const float*)d_in[23];
  const float* ow   = (const float*)d_in[24]; const float* ob   = (const float*)d_in[25];
  float* out = (float*)d_out;
  float* ws = (float*)d_ws;

  // phase-1 (attention) buffers; offsets in f32 slots (f16 elems = 2x)
  f16* vH  = (f16*)(ws + 0);          // 16.8M f16 -> [0, 4194304)
  f16* xTh = (f16*)(ws + 4194304);    // [4194304, 8388608)
  f16* wCh = (f16*)(ws + 8388608);    // [8388608, 8912896)
  f16* yH  = (f16*)(ws + 16777216);   // [16777216, 20971520)
  // conv phase (F buffers = same sizes as old wsingle buffers)
  f16* w1h = (f16*)(ws + 0);          // [0, 2359296)
  f16* c1H = (f16*)(ws + 2359296);    // [2359296, 6553600)
  f16* w3h = (f16*)(ws + 6553600);    // [6553600, 7733248)
  f16* w2h = (f16*)(ws + 16777216);   // [16777216, 17956864)  (yH dead)
  f16* c2H = (f16*)(ws + 17956864);   // [17956864, 22151168)
  f16* w4h = (f16*)(ws + 22151168);   // [22151168, 22740992)
  f16* c4H = (f16*)(ws + 22740992);   // [22740992, 24838144)
  f16* c3H = c1H;
  f16* w5h = (f16*)(ws + 0);          // [0, 147456)       (w1 dead)
  f16* c5H = (f16*)(ws + 147456);     // [147456, 1196032)
  f16* w6h = (f16*)(ws + 1196032);    // [1196032, 1232896)
  float* tin = ws + 1232896;          // [1232896, 2281472)
  float* t0  = ws + 2281472;          // [2281472, 3330048)
  float* t1  = ws + 3330048;          // [3330048, 4378624)
  f16* duFh = (f16*)(ws + 4378624);   // [4378624, 4397056)  (c1/c3 dead)
  f16* lrFh = (f16*)(ws + 4397056);   // [4397056, 4415488)
  float* sm = ws + 33554432;
  float* A_  = sm;
  float* M_  = sm + 16384;
  float* iZ  = sm + 32768;
  float* u_  = sm + 49152;
  float* s_  = sm + 50176;
  float* c0_ = sm + 50304;
  float* fst = sm + 50308;
  float* zp  = sm + 50432;  // 64-float zero page for OOB DMA lanes

  rf_zero<<<1, 64, 0, stream>>>(zp);
  rf_s<<<1, 128, 0, stream>>>(wB, bA, s_, c0_);
  rf_u<<<4, 256, 0, stream>>>(wA, s_, u_);
  rf_fstat<<<4, 256, 0, stream>>>(in, fst);
  rf_A<<<dim3(16, 4), 256, 0, stream>>>(in, u_, c0_, fst, A_, M_);
  rf_Z<<<4096, 256, 0, stream>>>(in, A_, M_, iZ);
  rf_xsplit<<<dim3(64, 16, 4), 256, 0, stream>>>(in, xTh);
  rf_wC1<<<512, 256, 0, stream>>>(wC, wCh);
  rf_vgemmm<<<dim3(32, 8, 4), 256, 0, stream>>>(wCh, xTh, bC, vH);
  rf_attm<<<dim3(32, 2, 4), 512, 0, stream>>>(vH, A_, M_, iZ, in, gamma, yH);

  // fragment-ordered conv weights (sizes identical to old wsingle buffers)
  rf_wfragc<<<2304, 256, 0, stream>>>(bw1, w1h, 1024, 512);
  rf_wfragc<<<1152, 256, 0, stream>>>(bw3, w3h, 512, 512);
  rf_mconv<128, 128, false><<<dim3(128, 4), 256, 0, stream>>>(
      yH, w1h, bb1, zp, c1H, nullptr, 1024, 512);
  rf_wfragc<<<1152, 256, 0, stream>>>(bw2, w2h, 512, 512);
  rf_wfragc<<<576, 256, 0, stream>>>(bw4, w4h, 512, 256);
  rf_wfragc<<<144, 256, 0, stream>>>(bw5, w5h, 256, 128);
  rf_wfragc<<<36, 256, 0, stream>>>(bw6, w6h, 128, 64);
  rf_mconv<128, 128, false><<<dim3(128, 4), 256, 0, stream>>>(
      c1H, w2h, bb2, zp, c2H, nullptr, 512, 512);
  rf_mconv<128, 128, false><<<dim3(128, 4), 256, 0, stream>>>(
      c2H, w3h, bb3, zp, c3H, nullptr, 512, 512);
  rf_mconv<128, 128, false><<<dim3(128, 2), 256, 0, stream>>>(
      c3H, w4h, bb4, zp, c4H, nullptr, 512, 256);
  rf_wfrag<<<18, 256, 0, stream>>>(du_w, duFh);
  rf_wfrag<<<18, 256, 0, stream>>>(lr_w, lrFh);
  rf_mconv<128, 128, false><<<dim3(128, 1), 256, 0, stream>>>(
      c4H, w5h, bb5, zp, c5H, nullptr, 256, 128);
  rf_mconv<256, 64, true><<<dim3(64, 1), 256, 0, stream>>>(
      c5H, w6h, bb6, zp, nullptr, tin, 128, 64);

  rf_mscan<<<4, 256, 0, stream>>>(tin, t0, duFh, du_b, +1);
  rf_mscan<<<4, 256, 0, stream>>>(t0, t1, duFh, du_b, -1);
  rf_transpose<<<256, 256, 0, stream>>>(t1, t0);
  rf_mscan<<<4, 256, 0, stream>>>(t0, t1, lrFh, lr_b, +1);
  rf_mscan<<<4, 256, 0, stream>>>(t1, t0, lrFh, lr_b, -1);
  rf_final<<<dim3(16, 4), 256, 0, stream>>>(t0, ow, ob, out);
}